// Round 8
// baseline (499.655 us; speedup 1.0000x reference)
//
#include <hip/hip_runtime.h>
#include <hip/hip_bf16.h>

#define NN 10000
#define EE 160000
#define DD 128
#define HH 4
#define CC 32
#define FFF 512
#define LL 2
#define RELV 100
#define EPS 1e-6f
#define GATE_BIAS 3.0f
#define BM 64
#define NT 16

typedef __bf16 bf16x8 __attribute__((ext_vector_type(8)));
typedef float f32x4 __attribute__((ext_vector_type(4)));
typedef float f32x16 __attribute__((ext_vector_type(16)));

#define MFMA(a,b,c)   __builtin_amdgcn_mfma_f32_16x16x32_bf16((a),(b),(c),0,0,0)
#define MFMA32(a,b,c) __builtin_amdgcn_mfma_f32_32x32x16_bf16((a),(b),(c),0,0,0)

__device__ __forceinline__ int swzK(int e, int b){ return e*256 + (b ^ ((e&7)<<4)); }   // [64][128] bf16
__device__ __forceinline__ int swz128(int e, int b){ return e*256 + (b ^ ((e&7)<<4)); } // [16][128] bf16
__device__ __forceinline__ int swz512(int e, int b){ return e*1024 + (b ^ ((e&7)<<4)); }// [16][512] bf16

// v9: 256-thr blocks (2 nodes each) + edge-histogram fused in (hist pre-zeroed via memset)
__global__ __launch_bounds__(256) void k_gx(
    const int* __restrict__ node_ids, const float* __restrict__ node_emb,
    float* __restrict__ x, ushort* __restrict__ xb,
    const int* __restrict__ dst, int* __restrict__ hist){
  int b = blockIdx.x, t = threadIdx.x;
  int n = b*2 + (t>>7);
  int c = t & 127;
  float v = node_emb[(long)node_ids[n]*DD + c];
  x[(long)n*DD + c] = v;
  __hip_bfloat16 h = __float2bfloat16(v);
  xb[(long)n*DD + c] = *(ushort*)&h;
  if (t < 32){
    int e = b*32 + t;
    atomicAdd(&hist[dst[e]], 1);
  }
}

// W[?][instride] fp32 -> MFMA32 fragment order bf16 (device helper)
__device__ __forceinline__ void wprep_one(
    const float* __restrict__ in, ushort* __restrict__ out, int tid, int IN, int instride){
  int lane = tid & 63;
  int grp  = tid >> 6;
  int nkb  = IN >> 4;
  int kb   = grp % nkb;
  int cb   = grp / nkb;
  int col  = cb*32 + (lane & 31);
  int k0   = kb*16 + (lane >> 5)*8;
  const float* p = in + (long)col*instride + k0;
  bf16x8 h;
  #pragma unroll
  for (int j=0;j<8;++j) h[j] = (__bf16)p[j];
  *(bf16x8*)(out + (long)tid*8) = h;
}

// fused per-layer weight prep (Gwb,Bwb,Kwb,Vwb wprep + A1b subcast), one launch/layer.
__global__ __launch_bounds__(256) void k_prep(
    const float* __restrict__ relG_w, const float* __restrict__ relB_w,
    const float* __restrict__ k_w, const float* __restrict__ v_w,
    const float* __restrict__ relA_w,
    ushort* __restrict__ Gwb, ushort* __restrict__ Bwb,
    ushort* __restrict__ Kwb, ushort* __restrict__ Vwb, ushort* __restrict__ A1b){
  int tid = blockIdx.x*256 + threadIdx.x;
  if (tid < DD*FFF/8){
    wprep_one(relG_w, Gwb, tid, FFF, FFF);
    wprep_one(relB_w, Bwb, tid, FFF, FFF);
  }
  if (tid < DD*DD/8){
    wprep_one(k_w, Kwb, tid, DD, 256);
    wprep_one(v_w, Vwb, tid, DD, DD);
  }
  {
    int o = tid / DD, i = tid % DD;
    __hip_bfloat16 h = __float2bfloat16(relA_w[(long)o*256 + i]);
    A1b[tid] = *(ushort*)&h;
  }
}

// the 4 plain casts (Qw,Ow,Wi,Wo both layers) in one launch. grid 512 x 256.
__global__ __launch_bounds__(256) void k_f2b4(
    const float* __restrict__ q_w, const float* __restrict__ o_w,
    const float* __restrict__ wi_w, const float* __restrict__ wo_w,
    ushort* __restrict__ Qwb, ushort* __restrict__ Owb,
    ushort* __restrict__ Wib, ushort* __restrict__ Wob){
  long i = (long)blockIdx.x*256 + threadIdx.x;
  const long nV = (long)LL*DD*DD;
  if (i < nV){
    __hip_bfloat16 h1 = __float2bfloat16(q_w[i]); Qwb[i] = *(ushort*)&h1;
    __hip_bfloat16 h2 = __float2bfloat16(o_w[i]); Owb[i] = *(ushort*)&h2;
  }
  {
    __hip_bfloat16 h3 = __float2bfloat16(wi_w[i]); Wib[i] = *(ushort*)&h3;
    __hip_bfloat16 h4 = __float2bfloat16(wo_w[i]); Wob[i] = *(ushort*)&h4;
  }
}

// per-relation precompute: EA2[rel][f] = bf16(emb@Aw2^T + Ab), EK[rel][o] = emb@Kw2^T (fp32)
__global__ __launch_bounds__(256) void k_ea(
    const float* __restrict__ edge_emb, const float* __restrict__ relA_w,
    const float* __restrict__ relA_b, const float* __restrict__ k_w,
    ushort* __restrict__ EA2b, float* __restrict__ EKf){
  int rel = blockIdx.x, t = threadIdx.x;
  __shared__ float emb[128];
  if (t < 128) emb[t] = edge_emb[(long)rel*DD + t];
  __syncthreads();
  for (int f=t; f<FFF; f+=256){
    const float* wr = relA_w + (long)f*256 + 128;
    float s = relA_b[f];
    for (int i=0;i<128;++i) s += emb[i]*wr[i];
    __hip_bfloat16 h = __float2bfloat16(s);
    EA2b[(long)rel*FFF + f] = *(ushort*)&h;
  }
  if (t < 128){
    const float* wr = k_w + (long)t*256 + 128;
    float s = 0.f;
    for (int i=0;i<128;++i) s += emb[i]*wr[i];
    EKf[(long)rel*DD + t] = s;
  }
}

// exclusive prefix of hist[NN] -> cursor[NN]; single block, 256 threads
__global__ __launch_bounds__(256) void k_scan(const int* __restrict__ hist, int* __restrict__ cursor){
  __shared__ int tsum[256];
  const int t = threadIdx.x;
  const int PER = (NN + 255) / 256;   // 40
  const int base = t*PER;
  int s = 0;
  for (int i=0;i<PER;++i){ int idx = base+i; if (idx < NN) s += hist[idx]; }
  tsum[t] = s;
  __syncthreads();
  if (t == 0){
    int run = 0;
    for (int i=0;i<256;++i){ int v = tsum[i]; tsum[i] = run; run += v; }
  }
  __syncthreads();
  int run = tsum[t];
  for (int i=0;i<PER;++i){
    int idx = base+i;
    if (idx < NN){ int v = hist[idx]; cursor[idx] = run; run += v; }
  }
}
__global__ __launch_bounds__(256) void k_scatter(const int* __restrict__ dst,
    int* __restrict__ cursor, int* __restrict__ perm){
  int e = blockIdx.x*256 + threadIdx.x;
  if (e < EE){
    int p = atomicAdd(&cursor[dst[e]], 1);
    perm[p] = e;
  }
}

// fused LN+q-proj AND XA = x@Aw1^T; also zeroes agg/denom for its 16 nodes.
__global__ __launch_bounds__(256) void k_lnq_xa(
    const float* __restrict__ x, const float* __restrict__ lnw, const float* __restrict__ lnb,
    const ushort* __restrict__ qwb, const ushort* __restrict__ a1b,
    float* __restrict__ q, ushort* __restrict__ XAb,
    float* __restrict__ agg, float* __restrict__ denom){
  __shared__ __align__(16) unsigned char HB[NT*256];    // LN'd x (bf16)
  __shared__ __align__(16) unsigned char HR[NT*256];    // raw x (bf16)
  const int n0 = blockIdx.x*NT;
  const int t = threadIdx.x;
  const int e = t>>4, s = t&15;
  const int w = t>>6, l = t&63, lr = l&15, lg = l>>4;
  {
    float4 z4 = {0.f,0.f,0.f,0.f};
    float* ap = agg + (long)n0*DD + t*8;
    *(float4*)ap = z4; *(float4*)(ap+4) = z4;
    if (t < NT*HH) denom[n0*HH + t] = 0.f;
  }
  {
    const float* xp = x + (long)(n0+e)*DD + s*8;
    float xv[8];
    *(float4*)&xv[0] = *(const float4*)xp;
    *(float4*)&xv[4] = *(const float4*)(xp+4);
    float sm = 0.f;
    #pragma unroll
    for (int i=0;i<8;++i) sm += xv[i];
    sm += __shfl_xor(sm,1); sm += __shfl_xor(sm,2);
    sm += __shfl_xor(sm,4); sm += __shfl_xor(sm,8);
    float mu = sm*(1.f/DD);
    float sq = 0.f;
    #pragma unroll
    for (int i=0;i<8;++i){ float d = xv[i]-mu; sq += d*d; }
    sq += __shfl_xor(sq,1); sq += __shfl_xor(sq,2);
    sq += __shfl_xor(sq,4); sq += __shfl_xor(sq,8);
    float rstd = rsqrtf(sq*(1.f/DD) + EPS);
    float4 w0 = *(const float4*)(lnw + s*8), w1 = *(const float4*)(lnw + s*8 + 4);
    float4 b0 = *(const float4*)(lnb + s*8), b1 = *(const float4*)(lnb + s*8 + 4);
    float wv[8] = {w0.x,w0.y,w0.z,w0.w,w1.x,w1.y,w1.z,w1.w};
    float bv[8] = {b0.x,b0.y,b0.z,b0.w,b1.x,b1.y,b1.z,b1.w};
    bf16x8 hb, hr;
    #pragma unroll
    for (int i=0;i<8;++i){
      hb[i] = (__bf16)((xv[i]-mu)*rstd*wv[i] + bv[i]);
      hr[i] = (__bf16)xv[i];
    }
    *(bf16x8*)(HB + swz128(e, s*16)) = hb;
    *(bf16x8*)(HR + swz128(e, s*16)) = hr;
  }
  __syncthreads();
  // q projection (K=128) from HB
  {
    const int o0 = w*32;
    f32x4 z = {0.f,0.f,0.f,0.f};
    f32x4 acc[2] = {z,z};
    #pragma unroll
    for (int k4=0;k4<4;++k4){
      bf16x8 a = *(const bf16x8*)(HB + swz128(lr, k4*64 + lg*16));
      #pragma unroll
      for (int nt=0;nt<2;++nt){
        bf16x8 b = *(const bf16x8*)(qwb + (long)(o0+nt*16+lr)*128 + k4*32 + lg*8);
        acc[nt] = MFMA(a, b, acc[nt]);
      }
    }
    #pragma unroll
    for (int nt=0;nt<2;++nt)
      #pragma unroll
      for (int r=0;r<4;++r)
        q[(long)(n0 + lg*4 + r)*DD + o0 + nt*16 + lr] = acc[nt][r];
  }
  // XA (512 out, K=128) from HR
  {
    const int f0w = w*128;
    f32x4 z = {0.f,0.f,0.f,0.f};
    f32x4 acc[8] = {z,z,z,z,z,z,z,z};
    #pragma unroll
    for (int k4=0;k4<4;++k4){
      bf16x8 a = *(const bf16x8*)(HR + swz128(lr, k4*64 + lg*16));
      #pragma unroll
      for (int nt=0;nt<8;++nt){
        bf16x8 b = *(const bf16x8*)(a1b + (long)(f0w+nt*16+lr)*128 + k4*32 + lg*8);
        acc[nt] = MFMA(a, b, acc[nt]);
      }
    }
    #pragma unroll
    for (int nt=0;nt<8;++nt)
      #pragma unroll
      for (int r=0;r<4;++r){
        __hip_bfloat16 h = __float2bfloat16(acc[nt][r]);
        XAb[(long)(n0+lg*4+r)*FFF + f0w+nt*16+lr] = *(ushort*)&h;
      }
  }
}

// --- fused edge kernel (dst-sorted) ---
// v7: in-register blend, dbuf INTB, (R,C) wave tiling (513 -> 472).
// v9: register diet for 3 blocks/CU: weights loaded 4-at-a-time, one matrix per pass
//     (GEMM-phase live set ~20 regs vs 36-64); __launch_bounds__(512,6) pins combined
//     (arch+acc) <= ~85 -> 6 waves/SIMD -> 3 blocks/CU (was 2). LDS 51200*3 fits 160K.
//     WATCH: if WRITE_SIZE blows up (spills, v2 lesson) revert to (512,4).
__global__ __launch_bounds__(512,6) void k_edge(
    const ushort* __restrict__ xb, const ushort* __restrict__ XAb,
    const ushort* __restrict__ EAb, const float* __restrict__ EKf,
    const float* __restrict__ q,
    const int* __restrict__ src, const int* __restrict__ dst, const int* __restrict__ eids,
    const int* __restrict__ perm,
    const ushort* __restrict__ Gwb, const float* __restrict__ Gb,
    const ushort* __restrict__ Bwb, const float* __restrict__ Bb,
    const ushort* __restrict__ Kwb, const ushort* __restrict__ Vwb,
    float* __restrict__ agg, float* __restrict__ denom)
{
  __shared__ __align__(16) unsigned char KVB[BM*256];      // 16KB kv2 bf16 [64][128] swz; later AGB rows 0..31 (fp32 linear)
  __shared__ __align__(16) unsigned char INTB[2][BM*256];  // 32KB celu chunk dbuf; INTB[0] later AGB rows 32..63
  __shared__ float EXL[BM][HH];                            // 1KB
  __shared__ int srcl[BM], dstl[BM], eidl[BM];

  const int e0 = blockIdx.x * BM;
  const int t  = threadIdx.x;
  const int w  = t >> 6;
  const int l  = t & 63;
  const int c32 = l & 31;
  const int hi  = l >> 5;
  const int R = w >> 2;          // row-group (edges 32R..32R+32)
  const int C = w & 3;           // col-quarter / head
  const int oc = C*32 + c32;

  if (t < BM){
    int pe = perm[e0+t];
    srcl[t] = src[pe]; dstl[t] = dst[pe]; eidl[t] = eids[pe];
  }
  __syncthreads();

  // stage kv_j = xb[src] into KVB (first read is at blend -- chunk syncs cover the hazard)
  {
    const uint4* xbu = (const uint4*)xb;
    #pragma unroll
    for (int it=0; it<2; ++it){
      int g = it*512 + t;
      int e = g >> 4, qq = g & 15;
      *(uint4*)(KVB + swzK(e, qq*16)) = xbu[(long)srcl[e]*16 + qq];
    }
  }

  f32x16 gbG, gbB;
  {
    float bg = Gb[oc] + GATE_BIAS;
    float bb = Bb[oc];
    #pragma unroll
    for (int i=0;i<16;++i){ gbG[i] = bg; gbB[i] = bb; }
  }

  // prologue: issue chunk-0 gather
  bf16x8 xa8[2], ea8[2];
  #pragma unroll
  for (int it=0; it<2; ++it){
    int g = it*512 + t;
    int e = g >> 4, c8 = g & 15;
    xa8[it] = *(const bf16x8*)(XAb + (long)srcl[e]*FFF + c8*8);
    ea8[it] = *(const bf16x8*)(EAb + (long)eidl[e]*FFF + c8*8);
  }

  // 4 chunks of 128 FF-cols; INTB double-buffered: ONE barrier per chunk.
  #pragma unroll
  for (int ch=0; ch<4; ++ch){
    bf16x8 o[2];
    #pragma unroll
    for (int it=0; it<2; ++it){
      #pragma unroll
      for (int j=0;j<8;++j){
        float s = (float)xa8[it][j] + (float)ea8[it][j];
        o[it][j] = (__bf16)((s > 0.f) ? s : (__expf(s) - 1.f));
      }
    }
    unsigned char* INTp = INTB[ch & 1];
    #pragma unroll
    for (int it=0; it<2; ++it){
      int g = it*512 + t;
      int e = g >> 4, c8 = g & 15;
      *(bf16x8*)(INTp + swzK(e, c8*16)) = o[it];
    }
    __syncthreads();   // INT[p] visible; GEMM(ch-2) readers of this buffer finished >=1 sync ago
    if (ch < 3){
      #pragma unroll
      for (int it=0; it<2; ++it){
        int g = it*512 + t;
        int e = g >> 4, c8 = g & 15;
        xa8[it] = *(const bf16x8*)(XAb + (long)srcl[e]*FFF + (ch+1)*128 + c8*8);
        ea8[it] = *(const bf16x8*)(EAb + (long)eidl[e]*FFF + (ch+1)*128 + c8*8);
      }
    }
    // gate GEMM: weights 4-at-a-time (register diet)
    {
      const ushort* Wg = Gwb + ((long)(C*32 + ch*8)*64 + l)*8;
      #pragma unroll
      for (int h2=0; h2<2; ++h2){
        bf16x8 wf[4];
        #pragma unroll
        for (int i=0;i<4;++i) wf[i] = *(const bf16x8*)(Wg + (long)(h2*4+i)*512);
        #pragma unroll
        for (int i=0;i<4;++i){
          bf16x8 a = *(const bf16x8*)(INTp + swzK(R*32 + c32, (h2*4+i)*32 + hi*16));
          gbG = MFMA32(a, wf[i], gbG);
        }
      }
    }
    // badd GEMM
    {
      const ushort* Wb = Bwb + ((long)(C*32 + ch*8)*64 + l)*8;
      #pragma unroll
      for (int h2=0; h2<2; ++h2){
        bf16x8 wf[4];
        #pragma unroll
        for (int i=0;i<4;++i) wf[i] = *(const bf16x8*)(Wb + (long)(h2*4+i)*512);
        #pragma unroll
        for (int i=0;i<4;++i){
          bf16x8 a = *(const bf16x8*)(INTp + swzK(R*32 + c32, (h2*4+i)*32 + hi*16));
          gbB = MFMA32(a, wf[i], gbB);
        }
      }
    }
  }

  // in-register blend: kv2 = badd + sigmoid(gate)*(kv - badd), write back to KVB
  #pragma unroll
  for (int r=0;r<16;++r){
    int row = (r&3) + 8*(r>>2) + 4*hi;
    int gr = R*32 + row;
    float g  = 1.f/(1.f + __expf(-gbG[r]));
    float kv = (float)*(const __bf16*)(KVB + swzK(gr, oc*2));
    float k2 = gbB[r] + g*(kv - gbB[r]);
    *(__bf16*)(KVB + swzK(gr, oc*2)) = (__bf16)k2;
  }
  __syncthreads();   // kv2 ready in KVB

  // K and V GEMMs: wave (R,C) computes K[32R..][32C..] and V[32R..][32C..], K=128
  f32x16 ka, va;
  #pragma unroll
  for (int i=0;i<16;++i){ ka[i] = 0.f; va[i] = 0.f; }
  {
    const ushort* Wk = Kwb + ((long)(C*8)*64 + l)*8;
    #pragma unroll
    for (int h2=0; h2<2; ++h2){
      bf16x8 wf[4];
      #pragma unroll
      for (int i=0;i<4;++i) wf[i] = *(const bf16x8*)(Wk + (long)(h2*4+i)*512);
      #pragma unroll
      for (int i=0;i<4;++i){
        bf16x8 a = *(const bf16x8*)(KVB + swzK(R*32 + c32, (h2*4+i)*32 + hi*16));
        ka = MFMA32(a, wf[i], ka);
      }
    }
  }
  {
    const ushort* Wv = Vwb + ((long)(C*8)*64 + l)*8;
    #pragma unroll
    for (int h2=0; h2<2; ++h2){
      bf16x8 wf[4];
      #pragma unroll
      for (int i=0;i<4;++i) wf[i] = *(const bf16x8*)(Wv + (long)(h2*4+i)*512);
      #pragma unroll
      for (int i=0;i<4;++i){
        bf16x8 a = *(const bf16x8*)(KVB + swzK(R*32 + c32, (h2*4+i)*32 + hi*16));
        va = MFMA32(a, wf[i], va);
      }
    }
  }
  __syncthreads();   // all KVB reads done; KVB + INTB[0] become fp32 AGB[64][128] (linear)

  // V -> AGB overlay (rows 0..31 -> KVB, 32..63 -> INTB[0])
  #pragma unroll
  for (int r=0;r<16;++r){
    int row = (r&3) + 8*(r>>2) + 4*hi;
    int gr = R*32 + row;
    unsigned char* ab = (gr < 32) ? KVB : INTB[0];
    *(float*)(ab + ((gr & 31)*128 + oc)*4) = va[r];
  }
  // score: k += EK[eid]; dot with q[dst] over head C's 32 cols; EXL = exp
  #pragma unroll
  for (int r=0;r<16;++r){
    int row = (r&3) + 8*(r>>2) + 4*hi;
    int gr = R*32 + row;
    int dn = dstl[gr];
    float kv = ka[r] + EKf[(long)eidl[gr]*DD + oc];
    float p = kv * q[(long)dn*DD + oc];
    p += __shfl_xor(p, 1); p += __shfl_xor(p, 2);
    p += __shfl_xor(p, 4); p += __shfl_xor(p, 8);
    p += __shfl_xor(p, 16);
    if (c32 == 0) EXL[gr][C] = __expf(p);
  }
  __syncthreads();   // EXL + AGB ready

  // segment-reduce (dst-sorted rows): 512 threads = 128 cols x 4 row-groups of 16
  {
    const int col = t & 127;
    const int rg  = t >> 7;
    const int r0  = rg*16;
    const int h   = col >> 5;
    const unsigned char* ab = (rg < 2) ? KVB : INTB[0];   // wave-uniform
    const int rb = (rg & 1) * 16;
    float acc = 0.f;
    int cur = dstl[r0];
    for (int r=0; r<16; ++r){
      int dn = dstl[r0+r];
      if (dn != cur){
        atomicAdd(&agg[(long)cur*DD + col], acc);
        acc = 0.f; cur = dn;
      }
      acc += *(const float*)(ab + ((rb + r)*128 + col)*4) * EXL[r0+r][h];
    }
    atomicAdd(&agg[(long)cur*DD + col], acc);
    if (col < HH){
      float da = 0.f; int cur2 = dstl[r0];
      for (int r=r0; r<r0+16; ++r){
        int dn = dstl[r];
        if (dn != cur2){
          atomicAdd(&denom[cur2*HH + col], da);
          da = 0.f; cur2 = dn;
        }
        da += EXL[r][col];
      }
      atomicAdd(&denom[cur2*HH + col], da);
    }
  }
}

// fused: x1 = x + (agg/denom)@o_w^T;  x = x1 + relu(LN(x1)@wi^T)@wo^T;  emits xb
__global__ __launch_bounds__(256) void k_node(
    const float* __restrict__ agg, const float* __restrict__ denom,
    const ushort* __restrict__ owb,
    const float* __restrict__ lnw, const float* __restrict__ lnb,
    const ushort* __restrict__ wib, const ushort* __restrict__ wob,
    float* __restrict__ x, ushort* __restrict__ xb){
  __shared__ __align__(16) unsigned char AB[NT*256];
  __shared__ __align__(16) unsigned char IB[NT*1024];
  __shared__ __align__(16) float XO[NT][132];
  const int n0 = blockIdx.x*NT;
  const int t = threadIdx.x;
  const int e = t>>4, s = t&15;
  const int w = t>>6, l = t&63, lr = l&15, lg = l>>4;

  {
    const float* ap = agg + (long)(n0+e)*DD + s*8;
    float av[8];
    *(float4*)&av[0] = *(const float4*)ap;
    *(float4*)&av[4] = *(const float4*)(ap+4);
    float dinv = 1.f / denom[(n0+e)*HH + (s>>2)];
    bf16x8 hb;
    #pragma unroll
    for (int i=0;i<8;++i) hb[i] = (__bf16)(av[i]*dinv);
    *(bf16x8*)(AB + swz128(e, s*16)) = hb;
  }
  __syncthreads();

  {
    const int o0 = w*32;
    f32x4 z = {0.f,0.f,0.f,0.f};
    f32x4 acc[2] = {z,z};
    #pragma unroll
    for (int k4=0;k4<4;++k4){
      bf16x8 a = *(const bf16x8*)(AB + swz128(lr, k4*64 + lg*16));
      #pragma unroll
      for (int nt=0;nt<2;++nt){
        bf16x8 b = *(const bf16x8*)(owb + (long)(o0+nt*16+lr)*128 + k4*32 + lg*8);
        acc[nt] = MFMA(a, b, acc[nt]);
      }
    }
    #pragma unroll
    for (int nt=0;nt<2;++nt)
      #pragma unroll
      for (int r=0;r<4;++r)
        XO[lg*4+r][o0+nt*16+lr] = acc[nt][r];
  }
  __syncthreads();

  float x1[8];
  {
    const float* xp = x + (long)(n0+e)*DD + s*8;
    float xv[8];
    *(float4*)&xv[0] = *(const float4*)xp;
    *(float4*)&xv[4] = *(const float4*)(xp+4);
    #pragma unroll
    for (int i=0;i<8;++i) x1[i] = xv[i] + XO[e][s*8+i];
    float sm = 0.f;
    #pragma unroll
    for (int i=0;i<8;++i) sm += x1[i];
    sm += __shfl_xor(sm,1); sm += __shfl_xor(sm,2);
    sm += __shfl_xor(sm,4); sm += __shfl_xor(sm,8);
    float mu = sm*(1.f/DD);
    float sq = 0.f;
    #pragma unroll
    for (int i=0;i<8;++i){ float d = x1[i]-mu; sq += d*d; }
    sq += __shfl_xor(sq,1); sq += __shfl_xor(sq,2);
    sq += __shfl_xor(sq,4); sq += __shfl_xor(sq,8);
    float rstd = rsqrtf(sq*(1.f/DD) + EPS);
    float4 w0 = *(const float4*)(lnw + s*8), w1 = *(const float4*)(lnw + s*8 + 4);
    float4 b0 = *(const float4*)(lnb + s*8), b1 = *(const float4*)(lnb + s*8 + 4);
    float wv[8] = {w0.x,w0.y,w0.z,w0.w,w1.x,w1.y,w1.z,w1.w};
    float bv[8] = {b0.x,b0.y,b0.z,b0.w,b1.x,b1.y,b1.z,b1.w};
    bf16x8 hb;
    #pragma unroll
    for (int i=0;i<8;++i) hb[i] = (__bf16)((x1[i]-mu)*rstd*wv[i] + bv[i]);
    __syncthreads();
    *(bf16x8*)(AB + swz128(e, s*16)) = hb;
  }
  __syncthreads();

  {
    const int f0w = w*128;
    f32x4 z = {0.f,0.f,0.f,0.f};
    f32x4 acc[8] = {z,z,z,z,z,z,z,z};
    #pragma unroll
    for (int k4=0;k4<4;++k4){
      bf16x8 a = *(const bf16x8*)(AB + swz128(lr, k4*64 + lg*16));
      #pragma unroll
      for (int nt=0;nt<8;++nt){
        bf16x8 b = *(const bf16x8*)(wib + (long)(f0w+nt*16+lr)*128 + k4*32 + lg*8);
        acc[nt] = MFMA(a, b, acc[nt]);
      }
    }
    #pragma unroll
    for (int nt=0;nt<8;++nt)
      #pragma unroll
      for (int r=0;r<4;++r){
        int e2 = lg*4 + r;
        int f = f0w + nt*16 + lr;
        float va = acc[nt][r];
        *(__bf16*)(IB + swz512(e2, f*2)) = (__bf16)fmaxf(va, 0.f);
      }
  }
  __syncthreads();

  {
    const int o0 = w*32;
    f32x4 z = {0.f,0.f,0.f,0.f};
    f32x4 acc[2] = {z,z};
    #pragma unroll
    for (int k16=0;k16<16;++k16){
      bf16x8 a = *(const bf16x8*)(IB + swz512(lr, k16*64 + lg*16));
      #pragma unroll
      for (int nt=0;nt<2;++nt){
        bf16x8 b = *(const bf16x8*)(wob + (long)(o0+nt*16+lr)*512 + k16*32 + lg*8);
        acc[nt] = MFMA(a, b, acc[nt]);
      }
    }
    #pragma unroll
    for (int nt=0;nt<2;++nt)
      #pragma unroll
      for (int r=0;r<4;++r)
        XO[lg*4+r][o0+nt*16+lr] = acc[nt][r];
  }
  __syncthreads();

  {
    float xn[8];
    #pragma unroll
    for (int i=0;i<8;++i) xn[i] = x1[i] + XO[e][s*8+i];
    float* xp = x + (long)(n0+e)*DD + s*8;
    *(float4*)xp = *(float4*)&xn[0];
    *(float4*)(xp+4) = *(float4*)&xn[4];
    bf16x8 hb;
    #pragma unroll
    for (int i=0;i<8;++i) hb[i] = (__bf16)xn[i];
    *(bf16x8*)(xb + (long)(n0+e)*DD + s*8) = hb;
  }
}

extern "C" void kernel_launch(void* const* d_in, const int* in_sizes, int n_in,
                              void* d_out, int out_size, void* d_ws, size_t ws_size,
                              hipStream_t stream) {
  const int* node_ids   = (const int*)d_in[0];
  const int* edge_index = (const int*)d_in[1];
  const int* edge_ids   = (const int*)d_in[2];
  const float* node_emb = (const float*)d_in[3];
  const float* edge_emb = (const float*)d_in[4];
  const float* ln_w   = (const float*)d_in[5];
  const float* ln_b   = (const float*)d_in[6];
  const float* q_w    = (const float*)d_in[7];
  const float* relA_w = (const float*)d_in[8];
  const float* relA_b = (const float*)d_in[9];
  const float* relB_w = (const float*)d_in[10];
  const float* relB_b = (const float*)d_in[11];
  const float* relG_w = (const float*)d_in[12];
  const float* relG_b = (const float*)d_in[13];
  const float* k_w    = (const float*)d_in[14];
  const float* v_w    = (const float*)d_in[15];
  const float* o_w    = (const float*)d_in[16];
  const float* ff_ln_w= (const float*)d_in[17];
  const float* ff_ln_b= (const float*)d_in[18];
  const float* wi_w   = (const float*)d_in[19];
  const float* wo_w   = (const float*)d_in[20];
  const int* src = edge_index;        // edge_index[0] = j (kv side)
  const int* dst = edge_index + EE;   // edge_index[1] = i (query side)

  float* ws = (float*)d_ws;
  float* x   = ws;  ws += (long)NN*DD;
  float* q   = ws;  ws += (long)NN*DD;
  float* denom = ws; ws += NN*HH;
  float* agg   = ws; ws += (long)NN*DD;
  float* EKf   = ws; ws += (long)LL*RELV*DD;
  int* hist   = (int*)ws; ws += NN;
  int* perm   = (int*)ws; ws += EE;
  ushort* xb  = (ushort*)ws; ws += (long)NN*DD/2;
  ushort* XAb = (ushort*)ws; ws += (long)NN*FFF/2;
  ushort* EAb = (ushort*)ws; ws += (long)LL*RELV*FFF/2;
  ushort* A1b = (ushort*)ws; ws += (long)LL*FFF*DD/2;
  ushort* Gwb = (ushort*)ws; ws += (long)LL*DD*FFF/2;
  ushort* Bwb = (ushort*)ws; ws += (long)LL*DD*FFF/2;
  ushort* Kwb = (ushort*)ws; ws += (long)LL*DD*DD/2;
  ushort* Vwb = (ushort*)ws; ws += (long)LL*DD*DD/2;
  ushort* Qwb = (ushort*)ws; ws += (long)LL*DD*DD/2;
  ushort* Owb = (ushort*)ws; ws += (long)LL*DD*DD/2;
  ushort* Wib = (ushort*)ws; ws += (long)LL*FFF*DD/2;
  ushort* Wob = (ushort*)ws; ws += (long)LL*DD*FFF/2;

  hipMemsetAsync(hist, 0, NN*sizeof(int), stream);
  k_gx<<<NN/2, 256, 0, stream>>>(node_ids, node_emb, x, xb, dst, hist);
  k_scan<<<1, 256, 0, stream>>>(hist, hist);   // in-place: hist becomes cursor
  k_scatter<<<(EE+255)/256, 256, 0, stream>>>(dst, hist, perm);
  for (int l=0; l<LL; ++l){
    k_prep<<<256, 256, 0, stream>>>(
        relG_w + (long)l*DD*FFF, relB_w + (long)l*DD*FFF,
        k_w + (long)l*DD*256,    v_w + (long)l*DD*DD,
        relA_w + (long)l*FFF*256,
        Gwb + (long)l*DD*FFF, Bwb + (long)l*DD*FFF,
        Kwb + (long)l*DD*DD,  Vwb + (long)l*DD*DD, A1b + (long)l*FFF*DD);
    k_ea<<<RELV, 256, 0, stream>>>(edge_emb, relA_w + (long)l*FFF*256, relA_b + (long)l*FFF,
                                   k_w + (long)l*DD*256, EAb + (long)l*RELV*FFF, EKf + (long)l*RELV*DD);
  }
  k_f2b4<<<512, 256, 0, stream>>>(q_w, o_w, wi_w, wo_w, Qwb, Owb, Wib, Wob);

  for (int l=0; l<LL; ++l){
    k_lnq_xa<<<NN/NT, 256, 0, stream>>>(x, ln_w + l*DD, ln_b + l*DD,
        Qwb + (long)l*DD*DD, A1b + (long)l*FFF*DD, q, XAb, agg, denom);
    k_edge<<<EE/BM, 512, 0, stream>>>(xb, XAb, EAb + (long)l*RELV*FFF, EKf + (long)l*RELV*DD,
        q, src, dst, edge_ids, perm,
        Gwb + (long)l*DD*FFF,  relG_b + (long)l*DD,
        Bwb + (long)l*DD*FFF,  relB_b + (long)l*DD,
        Kwb + (long)l*DD*DD,   Vwb + (long)l*DD*DD,
        agg, denom);
    k_node<<<NN/NT, 256, 0, stream>>>(agg, denom, Owb + (long)l*DD*DD,
        ff_ln_w + l*DD, ff_ln_b + l*DD,
        Wib + (long)l*FFF*DD, Wob + (long)l*DD*FFF, x, xb);
  }
  hipMemcpyAsync(d_out, x, (size_t)NN*DD*sizeof(float), hipMemcpyDeviceToDevice, stream);
}

// Round 9
// 454.017 us; speedup vs baseline: 1.1005x; 1.1005x over previous
//
#include <hip/hip_runtime.h>
#include <hip/hip_bf16.h>

#define NN 10000
#define EE 160000
#define DD 128
#define HH 4
#define CC 32
#define FFF 512
#define LL 2
#define RELV 100
#define EPS 1e-6f
#define GATE_BIAS 3.0f
#define BM 64
#define NT 16

typedef __bf16 bf16x8 __attribute__((ext_vector_type(8)));
typedef float f32x4 __attribute__((ext_vector_type(4)));
typedef float f32x16 __attribute__((ext_vector_type(16)));

#define MFMA(a,b,c)   __builtin_amdgcn_mfma_f32_16x16x32_bf16((a),(b),(c),0,0,0)
#define MFMA32(a,b,c) __builtin_amdgcn_mfma_f32_32x32x16_bf16((a),(b),(c),0,0,0)

__device__ __forceinline__ int swzK(int e, int b){ return e*256 + (b ^ ((e&7)<<4)); }   // [64][128] bf16
__device__ __forceinline__ int swz128(int e, int b){ return e*256 + (b ^ ((e&7)<<4)); } // [16][128] bf16
__device__ __forceinline__ int swz512(int e, int b){ return e*1024 + (b ^ ((e&7)<<4)); }// [16][512] bf16

// v10: barrier that waits ONLY on LDS ops (lgkmcnt) -- register-destined global loads
// stay in flight across it. __syncthreads' implicit vmcnt(0) was force-draining the
// XA/EA gathers at every chunk barrier (~500cy exposed x4 per block).
// All cross-wave hazards in k_edge are ds_write->ds_read, covered by lgkmcnt(0).
__device__ __forceinline__ void barrier_lgkm(){
  __builtin_amdgcn_sched_barrier(0);
  asm volatile("s_waitcnt lgkmcnt(0)" ::: "memory");
  __builtin_amdgcn_s_barrier();
  __builtin_amdgcn_sched_barrier(0);
}

// 256-thr blocks (2 nodes each) + edge-histogram fused in (hist pre-zeroed via memset)
__global__ __launch_bounds__(256) void k_gx(
    const int* __restrict__ node_ids, const float* __restrict__ node_emb,
    float* __restrict__ x, ushort* __restrict__ xb,
    const int* __restrict__ dst, int* __restrict__ hist){
  int b = blockIdx.x, t = threadIdx.x;
  int n = b*2 + (t>>7);
  int c = t & 127;
  float v = node_emb[(long)node_ids[n]*DD + c];
  x[(long)n*DD + c] = v;
  __hip_bfloat16 h = __float2bfloat16(v);
  xb[(long)n*DD + c] = *(ushort*)&h;
  if (t < 32){
    int e = b*32 + t;
    atomicAdd(&hist[dst[e]], 1);
  }
}

// W[?][instride] fp32 -> MFMA32 fragment order bf16 (device helper)
__device__ __forceinline__ void wprep_one(
    const float* __restrict__ in, ushort* __restrict__ out, int tid, int IN, int instride){
  int lane = tid & 63;
  int grp  = tid >> 6;
  int nkb  = IN >> 4;
  int kb   = grp % nkb;
  int cb   = grp / nkb;
  int col  = cb*32 + (lane & 31);
  int k0   = kb*16 + (lane >> 5)*8;
  const float* p = in + (long)col*instride + k0;
  bf16x8 h;
  #pragma unroll
  for (int j=0;j<8;++j) h[j] = (__bf16)p[j];
  *(bf16x8*)(out + (long)tid*8) = h;
}

// fused per-layer weight prep (Gwb,Bwb,Kwb,Vwb wprep + A1b subcast), one launch/layer.
__global__ __launch_bounds__(256) void k_prep(
    const float* __restrict__ relG_w, const float* __restrict__ relB_w,
    const float* __restrict__ k_w, const float* __restrict__ v_w,
    const float* __restrict__ relA_w,
    ushort* __restrict__ Gwb, ushort* __restrict__ Bwb,
    ushort* __restrict__ Kwb, ushort* __restrict__ Vwb, ushort* __restrict__ A1b){
  int tid = blockIdx.x*256 + threadIdx.x;
  if (tid < DD*FFF/8){
    wprep_one(relG_w, Gwb, tid, FFF, FFF);
    wprep_one(relB_w, Bwb, tid, FFF, FFF);
  }
  if (tid < DD*DD/8){
    wprep_one(k_w, Kwb, tid, DD, 256);
    wprep_one(v_w, Vwb, tid, DD, DD);
  }
  {
    int o = tid / DD, i = tid % DD;
    __hip_bfloat16 h = __float2bfloat16(relA_w[(long)o*256 + i]);
    A1b[tid] = *(ushort*)&h;
  }
}

// the 4 plain casts (Qw,Ow,Wi,Wo both layers) in one launch. grid 512 x 256.
__global__ __launch_bounds__(256) void k_f2b4(
    const float* __restrict__ q_w, const float* __restrict__ o_w,
    const float* __restrict__ wi_w, const float* __restrict__ wo_w,
    ushort* __restrict__ Qwb, ushort* __restrict__ Owb,
    ushort* __restrict__ Wib, ushort* __restrict__ Wob){
  long i = (long)blockIdx.x*256 + threadIdx.x;
  const long nV = (long)LL*DD*DD;
  if (i < nV){
    __hip_bfloat16 h1 = __float2bfloat16(q_w[i]); Qwb[i] = *(ushort*)&h1;
    __hip_bfloat16 h2 = __float2bfloat16(o_w[i]); Owb[i] = *(ushort*)&h2;
  }
  {
    __hip_bfloat16 h3 = __float2bfloat16(wi_w[i]); Wib[i] = *(ushort*)&h3;
    __hip_bfloat16 h4 = __float2bfloat16(wo_w[i]); Wob[i] = *(ushort*)&h4;
  }
}

// per-relation precompute: EA2[rel][f] = bf16(emb@Aw2^T + Ab), EK[rel][o] = emb@Kw2^T (fp32)
__global__ __launch_bounds__(256) void k_ea(
    const float* __restrict__ edge_emb, const float* __restrict__ relA_w,
    const float* __restrict__ relA_b, const float* __restrict__ k_w,
    ushort* __restrict__ EA2b, float* __restrict__ EKf){
  int rel = blockIdx.x, t = threadIdx.x;
  __shared__ float emb[128];
  if (t < 128) emb[t] = edge_emb[(long)rel*DD + t];
  __syncthreads();
  for (int f=t; f<FFF; f+=256){
    const float* wr = relA_w + (long)f*256 + 128;
    float s = relA_b[f];
    for (int i=0;i<128;++i) s += emb[i]*wr[i];
    __hip_bfloat16 h = __float2bfloat16(s);
    EA2b[(long)rel*FFF + f] = *(ushort*)&h;
  }
  if (t < 128){
    const float* wr = k_w + (long)t*256 + 128;
    float s = 0.f;
    for (int i=0;i<128;++i) s += emb[i]*wr[i];
    EKf[(long)rel*DD + t] = s;
  }
}

// exclusive prefix of hist[NN] -> cursor[NN]; single block, 256 threads
__global__ __launch_bounds__(256) void k_scan(const int* __restrict__ hist, int* __restrict__ cursor){
  __shared__ int tsum[256];
  const int t = threadIdx.x;
  const int PER = (NN + 255) / 256;   // 40
  const int base = t*PER;
  int s = 0;
  for (int i=0;i<PER;++i){ int idx = base+i; if (idx < NN) s += hist[idx]; }
  tsum[t] = s;
  __syncthreads();
  if (t == 0){
    int run = 0;
    for (int i=0;i<256;++i){ int v = tsum[i]; tsum[i] = run; run += v; }
  }
  __syncthreads();
  int run = tsum[t];
  for (int i=0;i<PER;++i){
    int idx = base+i;
    if (idx < NN){ int v = hist[idx]; cursor[idx] = run; run += v; }
  }
}
__global__ __launch_bounds__(256) void k_scatter(const int* __restrict__ dst,
    int* __restrict__ cursor, int* __restrict__ perm){
  int e = blockIdx.x*256 + threadIdx.x;
  if (e < EE){
    int p = atomicAdd(&cursor[dst[e]], 1);
    perm[p] = e;
  }
}

// fused LN+q-proj AND XA = x@Aw1^T; also zeroes agg/denom for its 16 nodes.
__global__ __launch_bounds__(256) void k_lnq_xa(
    const float* __restrict__ x, const float* __restrict__ lnw, const float* __restrict__ lnb,
    const ushort* __restrict__ qwb, const ushort* __restrict__ a1b,
    float* __restrict__ q, ushort* __restrict__ XAb,
    float* __restrict__ agg, float* __restrict__ denom){
  __shared__ __align__(16) unsigned char HB[NT*256];    // LN'd x (bf16)
  __shared__ __align__(16) unsigned char HR[NT*256];    // raw x (bf16)
  const int n0 = blockIdx.x*NT;
  const int t = threadIdx.x;
  const int e = t>>4, s = t&15;
  const int w = t>>6, l = t&63, lr = l&15, lg = l>>4;
  {
    float4 z4 = {0.f,0.f,0.f,0.f};
    float* ap = agg + (long)n0*DD + t*8;
    *(float4*)ap = z4; *(float4*)(ap+4) = z4;
    if (t < NT*HH) denom[n0*HH + t] = 0.f;
  }
  {
    const float* xp = x + (long)(n0+e)*DD + s*8;
    float xv[8];
    *(float4*)&xv[0] = *(const float4*)xp;
    *(float4*)&xv[4] = *(const float4*)(xp+4);
    float sm = 0.f;
    #pragma unroll
    for (int i=0;i<8;++i) sm += xv[i];
    sm += __shfl_xor(sm,1); sm += __shfl_xor(sm,2);
    sm += __shfl_xor(sm,4); sm += __shfl_xor(sm,8);
    float mu = sm*(1.f/DD);
    float sq = 0.f;
    #pragma unroll
    for (int i=0;i<8;++i){ float d = xv[i]-mu; sq += d*d; }
    sq += __shfl_xor(sq,1); sq += __shfl_xor(sq,2);
    sq += __shfl_xor(sq,4); sq += __shfl_xor(sq,8);
    float rstd = rsqrtf(sq*(1.f/DD) + EPS);
    float4 w0 = *(const float4*)(lnw + s*8), w1 = *(const float4*)(lnw + s*8 + 4);
    float4 b0 = *(const float4*)(lnb + s*8), b1 = *(const float4*)(lnb + s*8 + 4);
    float wv[8] = {w0.x,w0.y,w0.z,w0.w,w1.x,w1.y,w1.z,w1.w};
    float bv[8] = {b0.x,b0.y,b0.z,b0.w,b1.x,b1.y,b1.z,b1.w};
    bf16x8 hb, hr;
    #pragma unroll
    for (int i=0;i<8;++i){
      hb[i] = (__bf16)((xv[i]-mu)*rstd*wv[i] + bv[i]);
      hr[i] = (__bf16)xv[i];
    }
    *(bf16x8*)(HB + swz128(e, s*16)) = hb;
    *(bf16x8*)(HR + swz128(e, s*16)) = hr;
  }
  __syncthreads();
  // q projection (K=128) from HB
  {
    const int o0 = w*32;
    f32x4 z = {0.f,0.f,0.f,0.f};
    f32x4 acc[2] = {z,z};
    #pragma unroll
    for (int k4=0;k4<4;++k4){
      bf16x8 a = *(const bf16x8*)(HB + swz128(lr, k4*64 + lg*16));
      #pragma unroll
      for (int nt=0;nt<2;++nt){
        bf16x8 b = *(const bf16x8*)(qwb + (long)(o0+nt*16+lr)*128 + k4*32 + lg*8);
        acc[nt] = MFMA(a, b, acc[nt]);
      }
    }
    #pragma unroll
    for (int nt=0;nt<2;++nt)
      #pragma unroll
      for (int r=0;r<4;++r)
        q[(long)(n0 + lg*4 + r)*DD + o0 + nt*16 + lr] = acc[nt][r];
  }
  // XA (512 out, K=128) from HR
  {
    const int f0w = w*128;
    f32x4 z = {0.f,0.f,0.f,0.f};
    f32x4 acc[8] = {z,z,z,z,z,z,z,z};
    #pragma unroll
    for (int k4=0;k4<4;++k4){
      bf16x8 a = *(const bf16x8*)(HR + swz128(lr, k4*64 + lg*16));
      #pragma unroll
      for (int nt=0;nt<8;++nt){
        bf16x8 b = *(const bf16x8*)(a1b + (long)(f0w+nt*16+lr)*128 + k4*32 + lg*8);
        acc[nt] = MFMA(a, b, acc[nt]);
      }
    }
    #pragma unroll
    for (int nt=0;nt<8;++nt)
      #pragma unroll
      for (int r=0;r<4;++r){
        __hip_bfloat16 h = __float2bfloat16(acc[nt][r]);
        XAb[(long)(n0+lg*4+r)*FFF + f0w+nt*16+lr] = *(ushort*)&h;
      }
  }
}

// --- fused edge kernel (dst-sorted) ---
// v8 structure ((512,4), wf[8] preload, 143us) + v10 lgkm-only barriers:
// gathers stay in flight across chunk barriers instead of being vmcnt(0)-drained.
__global__ __launch_bounds__(512,4) void k_edge(
    const ushort* __restrict__ xb, const ushort* __restrict__ XAb,
    const ushort* __restrict__ EAb, const float* __restrict__ EKf,
    const float* __restrict__ q,
    const int* __restrict__ src, const int* __restrict__ dst, const int* __restrict__ eids,
    const int* __restrict__ perm,
    const ushort* __restrict__ Gwb, const float* __restrict__ Gb,
    const ushort* __restrict__ Bwb, const float* __restrict__ Bb,
    const ushort* __restrict__ Kwb, const ushort* __restrict__ Vwb,
    float* __restrict__ agg, float* __restrict__ denom)
{
  __shared__ __align__(16) unsigned char KVB[BM*256];      // 16KB kv2 bf16 [64][128] swz; later AGB rows 0..31 (fp32 linear)
  __shared__ __align__(16) unsigned char INTB[2][BM*256];  // 32KB celu chunk dbuf; INTB[0] later AGB rows 32..63
  __shared__ float EXL[BM][HH];                            // 1KB
  __shared__ int srcl[BM], dstl[BM], eidl[BM];

  const int e0 = blockIdx.x * BM;
  const int t  = threadIdx.x;
  const int w  = t >> 6;
  const int l  = t & 63;
  const int c32 = l & 31;
  const int hi  = l >> 5;
  const int R = w >> 2;          // row-group (edges 32R..32R+32)
  const int C = w & 3;           // col-quarter / head
  const int oc = C*32 + c32;

  if (t < BM){
    int pe = perm[e0+t];
    srcl[t] = src[pe]; dstl[t] = dst[pe]; eidl[t] = eids[pe];
  }
  barrier_lgkm();

  // stage kv_j = xb[src] into KVB (first read is at blend -- chunk barriers cover the hazard)
  {
    const uint4* xbu = (const uint4*)xb;
    #pragma unroll
    for (int it=0; it<2; ++it){
      int g = it*512 + t;
      int e = g >> 4, qq = g & 15;
      *(uint4*)(KVB + swzK(e, qq*16)) = xbu[(long)srcl[e]*16 + qq];
    }
  }

  f32x16 gbG, gbB;
  {
    float bg = Gb[oc] + GATE_BIAS;
    float bb = Bb[oc];
    #pragma unroll
    for (int i=0;i<16;++i){ gbG[i] = bg; gbB[i] = bb; }
  }

  // prologue: issue chunk-0 gather
  bf16x8 xa8[2], ea8[2];
  #pragma unroll
  for (int it=0; it<2; ++it){
    int g = it*512 + t;
    int e = g >> 4, c8 = g & 15;
    xa8[it] = *(const bf16x8*)(XAb + (long)srcl[e]*FFF + c8*8);
    ea8[it] = *(const bf16x8*)(EAb + (long)eidl[e]*FFF + c8*8);
  }

  // 4 chunks of 128 FF-cols; INTB double-buffered: ONE (lgkm) barrier per chunk.
  #pragma unroll
  for (int ch=0; ch<4; ++ch){
    bf16x8 o[2];
    #pragma unroll
    for (int it=0; it<2; ++it){
      #pragma unroll
      for (int j=0;j<8;++j){
        float s = (float)xa8[it][j] + (float)ea8[it][j];
        o[it][j] = (__bf16)((s > 0.f) ? s : (__expf(s) - 1.f));
      }
    }
    unsigned char* INTp = INTB[ch & 1];
    #pragma unroll
    for (int it=0; it<2; ++it){
      int g = it*512 + t;
      int e = g >> 4, c8 = g & 15;
      *(bf16x8*)(INTp + swzK(e, c8*16)) = o[it];
    }
    barrier_lgkm();    // INT[p] visible; next-chunk gathers (issued below) fly across
    if (ch < 3){
      #pragma unroll
      for (int it=0; it<2; ++it){
        int g = it*512 + t;
        int e = g >> 4, c8 = g & 15;
        xa8[it] = *(const bf16x8*)(XAb + (long)srcl[e]*FFF + (ch+1)*128 + c8*8);
        ea8[it] = *(const bf16x8*)(EAb + (long)eidl[e]*FFF + (ch+1)*128 + c8*8);
      }
    }
    // gate GEMM: rows 32R.., cols 32C.., K=128
    {
      const ushort* Wg = Gwb + ((long)(C*32 + ch*8)*64 + l)*8;
      bf16x8 wf[8];
      #pragma unroll
      for (int i=0;i<8;++i) wf[i] = *(const bf16x8*)(Wg + (long)i*512);
      #pragma unroll
      for (int i=0;i<8;++i){
        bf16x8 a = *(const bf16x8*)(INTp + swzK(R*32 + c32, i*32 + hi*16));
        gbG = MFMA32(a, wf[i], gbG);
      }
    }
    // badd GEMM
    {
      const ushort* Wb = Bwb + ((long)(C*32 + ch*8)*64 + l)*8;
      bf16x8 wf[8];
      #pragma unroll
      for (int i=0;i<8;++i) wf[i] = *(const bf16x8*)(Wb + (long)i*512);
      #pragma unroll
      for (int i=0;i<8;++i){
        bf16x8 a = *(const bf16x8*)(INTp + swzK(R*32 + c32, i*32 + hi*16));
        gbB = MFMA32(a, wf[i], gbB);
      }
    }
  }

  // in-register blend: kv2 = badd + sigmoid(gate)*(kv - badd), write back to KVB
  #pragma unroll
  for (int r=0;r<16;++r){
    int row = (r&3) + 8*(r>>2) + 4*hi;
    int gr = R*32 + row;
    float g  = 1.f/(1.f + __expf(-gbG[r]));
    float kv = (float)*(const __bf16*)(KVB + swzK(gr, oc*2));
    float k2 = gbB[r] + g*(kv - gbB[r]);
    *(__bf16*)(KVB + swzK(gr, oc*2)) = (__bf16)k2;
  }
  barrier_lgkm();   // kv2 ready in KVB

  // K and V GEMMs: wave (R,C) computes K[32R..][32C..] and V[32R..][32C..], K=128
  f32x16 ka, va;
  #pragma unroll
  for (int i=0;i<16;++i){ ka[i] = 0.f; va[i] = 0.f; }
  {
    const ushort* Wk = Kwb + ((long)(C*8)*64 + l)*8;
    bf16x8 wf[8];
    #pragma unroll
    for (int i=0;i<8;++i) wf[i] = *(const bf16x8*)(Wk + (long)i*512);
    #pragma unroll
    for (int i=0;i<8;++i){
      bf16x8 a = *(const bf16x8*)(KVB + swzK(R*32 + c32, i*32 + hi*16));
      ka = MFMA32(a, wf[i], ka);
    }
  }
  {
    const ushort* Wv = Vwb + ((long)(C*8)*64 + l)*8;
    bf16x8 wf[8];
    #pragma unroll
    for (int i=0;i<8;++i) wf[i] = *(const bf16x8*)(Wv + (long)i*512);
    #pragma unroll
    for (int i=0;i<8;++i){
      bf16x8 a = *(const bf16x8*)(KVB + swzK(R*32 + c32, i*32 + hi*16));
      va = MFMA32(a, wf[i], va);
    }
  }
  barrier_lgkm();   // all KVB reads done; KVB + INTB[0] become fp32 AGB[64][128] (linear)

  // V -> AGB overlay (rows 0..31 -> KVB, 32..63 -> INTB[0])
  #pragma unroll
  for (int r=0;r<16;++r){
    int row = (r&3) + 8*(r>>2) + 4*hi;
    int gr = R*32 + row;
    unsigned char* ab = (gr < 32) ? KVB : INTB[0];
    *(float*)(ab + ((gr & 31)*128 + oc)*4) = va[r];
  }
  // score: k += EK[eid]; dot with q[dst] over head C's 32 cols; EXL = exp
  #pragma unroll
  for (int r=0;r<16;++r){
    int row = (r&3) + 8*(r>>2) + 4*hi;
    int gr = R*32 + row;
    int dn = dstl[gr];
    float kv = ka[r] + EKf[(long)eidl[gr]*DD + oc];
    float p = kv * q[(long)dn*DD + oc];
    p += __shfl_xor(p, 1); p += __shfl_xor(p, 2);
    p += __shfl_xor(p, 4); p += __shfl_xor(p, 8);
    p += __shfl_xor(p, 16);
    if (c32 == 0) EXL[gr][C] = __expf(p);
  }
  barrier_lgkm();   // EXL + AGB ready

  // segment-reduce (dst-sorted rows): 512 threads = 128 cols x 4 row-groups of 16
  {
    const int col = t & 127;
    const int rg  = t >> 7;
    const int r0  = rg*16;
    const int h   = col >> 5;
    const unsigned char* ab = (rg < 2) ? KVB : INTB[0];   // wave-uniform
    const int rb = (rg & 1) * 16;
    float acc = 0.f;
    int cur = dstl[r0];
    for (int r=0; r<16; ++r){
      int dn = dstl[r0+r];
      if (dn != cur){
        atomicAdd(&agg[(long)cur*DD + col], acc);
        acc = 0.f; cur = dn;
      }
      acc += *(const float*)(ab + ((rb + r)*128 + col)*4) * EXL[r0+r][h];
    }
    atomicAdd(&agg[(long)cur*DD + col], acc);
    if (col < HH){
      float da = 0.f; int cur2 = dstl[r0];
      for (int r=r0; r<r0+16; ++r){
        int dn = dstl[r];
        if (dn != cur2){
          atomicAdd(&denom[cur2*HH + col], da);
          da = 0.f; cur2 = dn;
        }
        da += EXL[r][col];
      }
      atomicAdd(&denom[cur2*HH + col], da);
    }
  }
}

// fused: x1 = x + (agg/denom)@o_w^T;  x = x1 + relu(LN(x1)@wi^T)@wo^T;  emits xb
__global__ __launch_bounds__(256) void k_node(
    const float* __restrict__ agg, const float* __restrict__ denom,
    const ushort* __restrict__ owb,
    const float* __restrict__ lnw, const float* __restrict__ lnb,
    const ushort* __restrict__ wib, const ushort* __restrict__ wob,
    float* __restrict__ x, ushort* __restrict__ xb){
  __shared__ __align__(16) unsigned char AB[NT*256];
  __shared__ __align__(16) unsigned char IB[NT*1024];
  __shared__ __align__(16) float XO[NT][132];
  const int n0 = blockIdx.x*NT;
  const int t = threadIdx.x;
  const int e = t>>4, s = t&15;
  const int w = t>>6, l = t&63, lr = l&15, lg = l>>4;

  {
    const float* ap = agg + (long)(n0+e)*DD + s*8;
    float av[8];
    *(float4*)&av[0] = *(const float4*)ap;
    *(float4*)&av[4] = *(const float4*)(ap+4);
    float dinv = 1.f / denom[(n0+e)*HH + (s>>2)];
    bf16x8 hb;
    #pragma unroll
    for (int i=0;i<8;++i) hb[i] = (__bf16)(av[i]*dinv);
    *(bf16x8*)(AB + swz128(e, s*16)) = hb;
  }
  __syncthreads();

  {
    const int o0 = w*32;
    f32x4 z = {0.f,0.f,0.f,0.f};
    f32x4 acc[2] = {z,z};
    #pragma unroll
    for (int k4=0;k4<4;++k4){
      bf16x8 a = *(const bf16x8*)(AB + swz128(lr, k4*64 + lg*16));
      #pragma unroll
      for (int nt=0;nt<2;++nt){
        bf16x8 b = *(const bf16x8*)(owb + (long)(o0+nt*16+lr)*128 + k4*32 + lg*8);
        acc[nt] = MFMA(a, b, acc[nt]);
      }
    }
    #pragma unroll
    for (int nt=0;nt<2;++nt)
      #pragma unroll
      for (int r=0;r<4;++r)
        XO[lg*4+r][o0+nt*16+lr] = acc[nt][r];
  }
  __syncthreads();

  float x1[8];
  {
    const float* xp = x + (long)(n0+e)*DD + s*8;
    float xv[8];
    *(float4*)&xv[0] = *(const float4*)xp;
    *(float4*)&xv[4] = *(const float4*)(xp+4);
    #pragma unroll
    for (int i=0;i<8;++i) x1[i] = xv[i] + XO[e][s*8+i];
    float sm = 0.f;
    #pragma unroll
    for (int i=0;i<8;++i) sm += x1[i];
    sm += __shfl_xor(sm,1); sm += __shfl_xor(sm,2);
    sm += __shfl_xor(sm,4); sm += __shfl_xor(sm,8);
    float mu = sm*(1.f/DD);
    float sq = 0.f;
    #pragma unroll
    for (int i=0;i<8;++i){ float d = x1[i]-mu; sq += d*d; }
    sq += __shfl_xor(sq,1); sq += __shfl_xor(sq,2);
    sq += __shfl_xor(sq,4); sq += __shfl_xor(sq,8);
    float rstd = rsqrtf(sq*(1.f/DD) + EPS);
    float4 w0 = *(const float4*)(lnw + s*8), w1 = *(const float4*)(lnw + s*8 + 4);
    float4 b0 = *(const float4*)(lnb + s*8), b1 = *(const float4*)(lnb + s*8 + 4);
    float wv[8] = {w0.x,w0.y,w0.z,w0.w,w1.x,w1.y,w1.z,w1.w};
    float bv[8] = {b0.x,b0.y,b0.z,b0.w,b1.x,b1.y,b1.z,b1.w};
    bf16x8 hb;
    #pragma unroll
    for (int i=0;i<8;++i) hb[i] = (__bf16)((x1[i]-mu)*rstd*wv[i] + bv[i]);
    __syncthreads();
    *(bf16x8*)(AB + swz128(e, s*16)) = hb;
  }
  __syncthreads();

  {
    const int f0w = w*128;
    f32x4 z = {0.f,0.f,0.f,0.f};
    f32x4 acc[8] = {z,z,z,z,z,z,z,z};
    #pragma unroll
    for (int k4=0;k4<4;++k4){
      bf16x8 a = *(const bf16x8*)(AB + swz128(lr, k4*64 + lg*16));
      #pragma unroll
      for (int nt=0;nt<8;++nt){
        bf16x8 b = *(const bf16x8*)(wib + (long)(f0w+nt*16+lr)*128 + k4*32 + lg*8);
        acc[nt] = MFMA(a, b, acc[nt]);
      }
    }
    #pragma unroll
    for (int nt=0;nt<8;++nt)
      #pragma unroll
      for (int r=0;r<4;++r){
        int e2 = lg*4 + r;
        int f = f0w + nt*16 + lr;
        float va = acc[nt][r];
        *(__bf16*)(IB + swz512(e2, f*2)) = (__bf16)fmaxf(va, 0.f);
      }
  }
  __syncthreads();

  {
    const int o0 = w*32;
    f32x4 z = {0.f,0.f,0.f,0.f};
    f32x4 acc[2] = {z,z};
    #pragma unroll
    for (int k16=0;k16<16;++k16){
      bf16x8 a = *(const bf16x8*)(IB + swz512(lr, k16*64 + lg*16));
      #pragma unroll
      for (int nt=0;nt<2;++nt){
        bf16x8 b = *(const bf16x8*)(wob + (long)(o0+nt*16+lr)*512 + k16*32 + lg*8);
        acc[nt] = MFMA(a, b, acc[nt]);
      }
    }
    #pragma unroll
    for (int nt=0;nt<2;++nt)
      #pragma unroll
      for (int r=0;r<4;++r)
        XO[lg*4+r][o0+nt*16+lr] = acc[nt][r];
  }
  __syncthreads();

  {
    float xn[8];
    #pragma unroll
    for (int i=0;i<8;++i) xn[i] = x1[i] + XO[e][s*8+i];
    float* xp = x + (long)(n0+e)*DD + s*8;
    *(float4*)xp = *(float4*)&xn[0];
    *(float4*)(xp+4) = *(float4*)&xn[4];
    bf16x8 hb;
    #pragma unroll
    for (int i=0;i<8;++i) hb[i] = (__bf16)xn[i];
    *(bf16x8*)(xb + (long)(n0+e)*DD + s*8) = hb;
  }
}

extern "C" void kernel_launch(void* const* d_in, const int* in_sizes, int n_in,
                              void* d_out, int out_size, void* d_ws, size_t ws_size,
                              hipStream_t stream) {
  const int* node_ids   = (const int*)d_in[0];
  const int* edge_index = (const int*)d_in[1];
  const int* edge_ids   = (const int*)d_in[2];
  const float* node_emb = (const float*)d_in[3];
  const float* edge_emb = (const float*)d_in[4];
  const float* ln_w   = (const float*)d_in[5];
  const float* ln_b   = (const float*)d_in[6];
  const float* q_w    = (const float*)d_in[7];
  const float* relA_w = (const float*)d_in[8];
  const float* relA_b = (const float*)d_in[9];
  const float* relB_w = (const float*)d_in[10];
  const float* relB_b = (const float*)d_in[11];
  const float* relG_w = (const float*)d_in[12];
  const float* relG_b = (const float*)d_in[13];
  const float* k_w    = (const float*)d_in[14];
  const float* v_w    = (const float*)d_in[15];
  const float* o_w    = (const float*)d_in[16];
  const float* ff_ln_w= (const float*)d_in[17];
  const float* ff_ln_b= (const float*)d_in[18];
  const float* wi_w   = (const float*)d_in[19];
  const float* wo_w   = (const float*)d_in[20];
  const int* src = edge_index;        // edge_index[0] = j (kv side)
  const int* dst = edge_index + EE;   // edge_index[1] = i (query side)

  float* ws = (float*)d_ws;
  float* x   = ws;  ws += (long)NN*DD;
  float* q   = ws;  ws += (long)NN*DD;
  float* denom = ws; ws += NN*HH;
  float* agg   = ws; ws += (long)NN*DD;
  float* EKf   = ws; ws += (long)LL*RELV*DD;
  int* hist   = (int*)ws; ws += NN;
  int* perm   = (int*)ws; ws += EE;
  ushort* xb  = (ushort*)ws; ws += (long)NN*DD/2;
  ushort* XAb = (ushort*)ws; ws += (long)NN*FFF/2;
  ushort* EAb = (ushort*)ws; ws += (long)LL*RELV*FFF/2;
  ushort* A1b = (ushort*)ws; ws += (long)LL*FFF*DD/2;
  ushort* Gwb = (ushort*)ws; ws += (long)LL*DD*FFF/2;
  ushort* Bwb = (ushort*)ws; ws += (long)LL*DD*FFF/2;
  ushort* Kwb = (ushort*)ws; ws += (long)LL*DD*DD/2;
  ushort* Vwb = (ushort*)ws; ws += (long)LL*DD*DD/2;
  ushort* Qwb = (ushort*)ws; ws += (long)LL*DD*DD/2;
  ushort* Owb = (ushort*)ws; ws += (long)LL*DD*DD/2;
  ushort* Wib = (ushort*)ws; ws += (long)LL*FFF*DD/2;
  ushort* Wob = (ushort*)ws; ws += (long)LL*DD*FFF/2;

  hipMemsetAsync(hist, 0, NN*sizeof(int), stream);
  k_gx<<<NN/2, 256, 0, stream>>>(node_ids, node_emb, x, xb, dst, hist);
  k_scan<<<1, 256, 0, stream>>>(hist, hist);   // in-place: hist becomes cursor
  k_scatter<<<(EE+255)/256, 256, 0, stream>>>(dst, hist, perm);
  for (int l=0; l<LL; ++l){
    k_prep<<<256, 256, 0, stream>>>(
        relG_w + (long)l*DD*FFF, relB_w + (long)l*DD*FFF,
        k_w + (long)l*DD*256,    v_w + (long)l*DD*DD,
        relA_w + (long)l*FFF*256,
        Gwb + (long)l*DD*FFF, Bwb + (long)l*DD*FFF,
        Kwb + (long)l*DD*DD,  Vwb + (long)l*DD*DD, A1b + (long)l*FFF*DD);
    k_ea<<<RELV, 256, 0, stream>>>(edge_emb, relA_w + (long)l*FFF*256, relA_b + (long)l*FFF,
                                   k_w + (long)l*DD*256, EAb + (long)l*RELV*FFF, EKf + (long)l*RELV*DD);
  }
  k_f2b4<<<512, 256, 0, stream>>>(q_w, o_w, wi_w, wo_w, Qwb, Owb, Wib, Wob);

  for (int l=0; l<LL; ++l){
    k_lnq_xa<<<NN/NT, 256, 0, stream>>>(x, ln_w + l*DD, ln_b + l*DD,
        Qwb + (long)l*DD*DD, A1b + (long)l*FFF*DD, q, XAb, agg, denom);
    k_edge<<<EE/BM, 512, 0, stream>>>(xb, XAb, EAb + (long)l*RELV*FFF, EKf + (long)l*RELV*DD,
        q, src, dst, edge_ids, perm,
        Gwb + (long)l*DD*FFF,  relG_b + (long)l*DD,
        Bwb + (long)l*DD*FFF,  relB_b + (long)l*DD,
        Kwb + (long)l*DD*DD,   Vwb + (long)l*DD*DD,
        agg, denom);
    k_node<<<NN/NT, 256, 0, stream>>>(agg, denom, Owb + (long)l*DD*DD,
        ff_ln_w + l*DD, ff_ln_b + l*DD,
        Wib + (long)l*FFF*DD, Wob + (long)l*DD*FFF, x, xb);
  }
  hipMemcpyAsync(d_out, x, (size_t)NN*DD*sizeof(float), hipMemcpyDeviceToDevice, stream);
}

// Round 10
// 438.667 us; speedup vs baseline: 1.1390x; 1.0350x over previous
//
#include <hip/hip_runtime.h>
#include <hip/hip_bf16.h>

#define NN 10000
#define EE 160000
#define DD 128
#define HH 4
#define CC 32
#define FFF 512
#define LL 2
#define RELV 100
#define EPS 1e-6f
#define GATE_BIAS 3.0f
#define BM 64
#define NT 16

typedef __bf16 bf16x8 __attribute__((ext_vector_type(8)));
typedef float f32x4 __attribute__((ext_vector_type(4)));
typedef float f32x16 __attribute__((ext_vector_type(16)));

#define MFMA(a,b,c)   __builtin_amdgcn_mfma_f32_16x16x32_bf16((a),(b),(c),0,0,0)
#define MFMA32(a,b,c) __builtin_amdgcn_mfma_f32_32x32x16_bf16((a),(b),(c),0,0,0)

__device__ __forceinline__ int swzK(int e, int b){ return e*256 + (b ^ ((e&7)<<4)); }   // [64][128] bf16
__device__ __forceinline__ int swz128(int e, int b){ return e*256 + (b ^ ((e&7)<<4)); } // [16][128] bf16
__device__ __forceinline__ int swz512(int e, int b){ return e*1024 + (b ^ ((e&7)<<4)); }// [16][512] bf16

// 256-thr blocks (2 nodes each) + edge-histogram fused in (hist pre-zeroed via memset)
__global__ __launch_bounds__(256) void k_gx(
    const int* __restrict__ node_ids, const float* __restrict__ node_emb,
    float* __restrict__ x, ushort* __restrict__ xb,
    const int* __restrict__ dst, int* __restrict__ hist){
  int b = blockIdx.x, t = threadIdx.x;
  int n = b*2 + (t>>7);
  int c = t & 127;
  float v = node_emb[(long)node_ids[n]*DD + c];
  x[(long)n*DD + c] = v;
  __hip_bfloat16 h = __float2bfloat16(v);
  xb[(long)n*DD + c] = *(ushort*)&h;
  if (t < 32){
    int e = b*32 + t;
    atomicAdd(&hist[dst[e]], 1);
  }
}

// W[?][instride] fp32 -> MFMA32 fragment order bf16 (device helper)
__device__ __forceinline__ void wprep_one(
    const float* __restrict__ in, ushort* __restrict__ out, int tid, int IN, int instride){
  int lane = tid & 63;
  int grp  = tid >> 6;
  int nkb  = IN >> 4;
  int kb   = grp % nkb;
  int cb   = grp / nkb;
  int col  = cb*32 + (lane & 31);
  int k0   = kb*16 + (lane >> 5)*8;
  const float* p = in + (long)col*instride + k0;
  bf16x8 h;
  #pragma unroll
  for (int j=0;j<8;++j) h[j] = (__bf16)p[j];
  *(bf16x8*)(out + (long)tid*8) = h;
}

// fused per-layer weight prep (Gwb,Bwb,Kwb,Vwb wprep + A1b subcast), one launch/layer.
__global__ __launch_bounds__(256) void k_prep(
    const float* __restrict__ relG_w, const float* __restrict__ relB_w,
    const float* __restrict__ k_w, const float* __restrict__ v_w,
    const float* __restrict__ relA_w,
    ushort* __restrict__ Gwb, ushort* __restrict__ Bwb,
    ushort* __restrict__ Kwb, ushort* __restrict__ Vwb, ushort* __restrict__ A1b){
  int tid = blockIdx.x*256 + threadIdx.x;
  if (tid < DD*FFF/8){
    wprep_one(relG_w, Gwb, tid, FFF, FFF);
    wprep_one(relB_w, Bwb, tid, FFF, FFF);
  }
  if (tid < DD*DD/8){
    wprep_one(k_w, Kwb, tid, DD, 256);
    wprep_one(v_w, Vwb, tid, DD, DD);
  }
  {
    int o = tid / DD, i = tid % DD;
    __hip_bfloat16 h = __float2bfloat16(relA_w[(long)o*256 + i]);
    A1b[tid] = *(ushort*)&h;
  }
}

// the 4 plain casts (Qw,Ow,Wi,Wo both layers) in one launch. grid 512 x 256.
__global__ __launch_bounds__(256) void k_f2b4(
    const float* __restrict__ q_w, const float* __restrict__ o_w,
    const float* __restrict__ wi_w, const float* __restrict__ wo_w,
    ushort* __restrict__ Qwb, ushort* __restrict__ Owb,
    ushort* __restrict__ Wib, ushort* __restrict__ Wob){
  long i = (long)blockIdx.x*256 + threadIdx.x;
  const long nV = (long)LL*DD*DD;
  if (i < nV){
    __hip_bfloat16 h1 = __float2bfloat16(q_w[i]); Qwb[i] = *(ushort*)&h1;
    __hip_bfloat16 h2 = __float2bfloat16(o_w[i]); Owb[i] = *(ushort*)&h2;
  }
  {
    __hip_bfloat16 h3 = __float2bfloat16(wi_w[i]); Wib[i] = *(ushort*)&h3;
    __hip_bfloat16 h4 = __float2bfloat16(wo_w[i]); Wob[i] = *(ushort*)&h4;
  }
}

// per-relation precompute: EA2[rel][f] = bf16(emb@Aw2^T + Ab), EK[rel][o] = emb@Kw2^T (fp32)
__global__ __launch_bounds__(256) void k_ea(
    const float* __restrict__ edge_emb, const float* __restrict__ relA_w,
    const float* __restrict__ relA_b, const float* __restrict__ k_w,
    ushort* __restrict__ EA2b, float* __restrict__ EKf){
  int rel = blockIdx.x, t = threadIdx.x;
  __shared__ float emb[128];
  if (t < 128) emb[t] = edge_emb[(long)rel*DD + t];
  __syncthreads();
  for (int f=t; f<FFF; f+=256){
    const float* wr = relA_w + (long)f*256 + 128;
    float s = relA_b[f];
    for (int i=0;i<128;++i) s += emb[i]*wr[i];
    __hip_bfloat16 h = __float2bfloat16(s);
    EA2b[(long)rel*FFF + f] = *(ushort*)&h;
  }
  if (t < 128){
    const float* wr = k_w + (long)t*256 + 128;
    float s = 0.f;
    for (int i=0;i<128;++i) s += emb[i]*wr[i];
    EKf[(long)rel*DD + t] = s;
  }
}

// exclusive prefix of hist[NN] -> cursor[NN]; single block, 256 threads
__global__ __launch_bounds__(256) void k_scan(const int* __restrict__ hist, int* __restrict__ cursor){
  __shared__ int tsum[256];
  const int t = threadIdx.x;
  const int PER = (NN + 255) / 256;   // 40
  const int base = t*PER;
  int s = 0;
  for (int i=0;i<PER;++i){ int idx = base+i; if (idx < NN) s += hist[idx]; }
  tsum[t] = s;
  __syncthreads();
  if (t == 0){
    int run = 0;
    for (int i=0;i<256;++i){ int v = tsum[i]; tsum[i] = run; run += v; }
  }
  __syncthreads();
  int run = tsum[t];
  for (int i=0;i<PER;++i){
    int idx = base+i;
    if (idx < NN){ int v = hist[idx]; cursor[idx] = run; run += v; }
  }
}
__global__ __launch_bounds__(256) void k_scatter(const int* __restrict__ dst,
    int* __restrict__ cursor, int* __restrict__ perm){
  int e = blockIdx.x*256 + threadIdx.x;
  if (e < EE){
    int p = atomicAdd(&cursor[dst[e]], 1);
    perm[p] = e;
  }
}

// fused LN+q-proj AND XA = x@Aw1^T; also zeroes agg/denom. (layer 0 only; later layers fused in k_node)
__global__ __launch_bounds__(256) void k_lnq_xa(
    const float* __restrict__ x, const float* __restrict__ lnw, const float* __restrict__ lnb,
    const ushort* __restrict__ qwb, const ushort* __restrict__ a1b,
    float* __restrict__ q, ushort* __restrict__ XAb,
    float* __restrict__ agg, float* __restrict__ denom){
  __shared__ __align__(16) unsigned char HB[NT*256];    // LN'd x (bf16)
  __shared__ __align__(16) unsigned char HR[NT*256];    // raw x (bf16)
  const int n0 = blockIdx.x*NT;
  const int t = threadIdx.x;
  const int e = t>>4, s = t&15;
  const int w = t>>6, l = t&63, lr = l&15, lg = l>>4;
  {
    float4 z4 = {0.f,0.f,0.f,0.f};
    float* ap = agg + (long)n0*DD + t*8;
    *(float4*)ap = z4; *(float4*)(ap+4) = z4;
    if (t < NT*HH) denom[n0*HH + t] = 0.f;
  }
  {
    const float* xp = x + (long)(n0+e)*DD + s*8;
    float xv[8];
    *(float4*)&xv[0] = *(const float4*)xp;
    *(float4*)&xv[4] = *(const float4*)(xp+4);
    float sm = 0.f;
    #pragma unroll
    for (int i=0;i<8;++i) sm += xv[i];
    sm += __shfl_xor(sm,1); sm += __shfl_xor(sm,2);
    sm += __shfl_xor(sm,4); sm += __shfl_xor(sm,8);
    float mu = sm*(1.f/DD);
    float sq = 0.f;
    #pragma unroll
    for (int i=0;i<8;++i){ float d = xv[i]-mu; sq += d*d; }
    sq += __shfl_xor(sq,1); sq += __shfl_xor(sq,2);
    sq += __shfl_xor(sq,4); sq += __shfl_xor(sq,8);
    float rstd = rsqrtf(sq*(1.f/DD) + EPS);
    float4 w0 = *(const float4*)(lnw + s*8), w1 = *(const float4*)(lnw + s*8 + 4);
    float4 b0 = *(const float4*)(lnb + s*8), b1 = *(const float4*)(lnb + s*8 + 4);
    float wv[8] = {w0.x,w0.y,w0.z,w0.w,w1.x,w1.y,w1.z,w1.w};
    float bv[8] = {b0.x,b0.y,b0.z,b0.w,b1.x,b1.y,b1.z,b1.w};
    bf16x8 hb, hr;
    #pragma unroll
    for (int i=0;i<8;++i){
      hb[i] = (__bf16)((xv[i]-mu)*rstd*wv[i] + bv[i]);
      hr[i] = (__bf16)xv[i];
    }
    *(bf16x8*)(HB + swz128(e, s*16)) = hb;
    *(bf16x8*)(HR + swz128(e, s*16)) = hr;
  }
  __syncthreads();
  // q projection (K=128) from HB
  {
    const int o0 = w*32;
    f32x4 z = {0.f,0.f,0.f,0.f};
    f32x4 acc[2] = {z,z};
    #pragma unroll
    for (int k4=0;k4<4;++k4){
      bf16x8 a = *(const bf16x8*)(HB + swz128(lr, k4*64 + lg*16));
      #pragma unroll
      for (int nt=0;nt<2;++nt){
        bf16x8 b = *(const bf16x8*)(qwb + (long)(o0+nt*16+lr)*128 + k4*32 + lg*8);
        acc[nt] = MFMA(a, b, acc[nt]);
      }
    }
    #pragma unroll
    for (int nt=0;nt<2;++nt)
      #pragma unroll
      for (int r=0;r<4;++r)
        q[(long)(n0 + lg*4 + r)*DD + o0 + nt*16 + lr] = acc[nt][r];
  }
  // XA (512 out, K=128) from HR
  {
    const int f0w = w*128;
    f32x4 z = {0.f,0.f,0.f,0.f};
    f32x4 acc[8] = {z,z,z,z,z,z,z,z};
    #pragma unroll
    for (int k4=0;k4<4;++k4){
      bf16x8 a = *(const bf16x8*)(HR + swz128(lr, k4*64 + lg*16));
      #pragma unroll
      for (int nt=0;nt<8;++nt){
        bf16x8 b = *(const bf16x8*)(a1b + (long)(f0w+nt*16+lr)*128 + k4*32 + lg*8);
        acc[nt] = MFMA(a, b, acc[nt]);
      }
    }
    #pragma unroll
    for (int nt=0;nt<8;++nt)
      #pragma unroll
      for (int r=0;r<4;++r){
        __hip_bfloat16 h = __float2bfloat16(acc[nt][r]);
        XAb[(long)(n0+lg*4+r)*FFF + f0w+nt*16+lr] = *(ushort*)&h;
      }
  }
}

// --- fused edge kernel (dst-sorted) --- v8 body (proven 143us) + bijective XCD block swizzle.
__global__ __launch_bounds__(512,4) void k_edge(
    const ushort* __restrict__ xb, const ushort* __restrict__ XAb,
    const ushort* __restrict__ EAb, const float* __restrict__ EKf,
    const float* __restrict__ q,
    const int* __restrict__ src, const int* __restrict__ dst, const int* __restrict__ eids,
    const int* __restrict__ perm,
    const ushort* __restrict__ Gwb, const float* __restrict__ Gb,
    const ushort* __restrict__ Bwb, const float* __restrict__ Bb,
    const ushort* __restrict__ Kwb, const ushort* __restrict__ Vwb,
    float* __restrict__ agg, float* __restrict__ denom)
{
  __shared__ __align__(16) unsigned char KVB[BM*256];      // 16KB kv2 bf16 [64][128] swz; later AGB rows 0..31 (fp32 linear)
  __shared__ __align__(16) unsigned char INTB[2][BM*256];  // 32KB celu chunk dbuf; INTB[0] later AGB rows 32..63
  __shared__ float EXL[BM][HH];                            // 1KB
  __shared__ int srcl[BM], dstl[BM], eidl[BM];

  // bijective XCD-chunked swizzle (m204 form; nwg=2500, nwg%8=4): consecutive dst-sorted
  // blocks (sharing q rows / agg rows) land on the same XCD's L2.
  int nb;
  {
    const int nwg = EE/BM;            // 2500
    const int q0 = nwg >> 3;          // 312
    const int r0 = nwg & 7;           // 4
    int xcd = blockIdx.x & 7, sub = blockIdx.x >> 3;
    nb = (xcd < r0 ? xcd*(q0+1) : r0*(q0+1) + (xcd - r0)*q0) + sub;
  }
  const int e0 = nb * BM;
  const int t  = threadIdx.x;
  const int w  = t >> 6;
  const int l  = t & 63;
  const int c32 = l & 31;
  const int hi  = l >> 5;
  const int R = w >> 2;          // row-group (edges 32R..32R+32)
  const int C = w & 3;           // col-quarter / head
  const int oc = C*32 + c32;

  if (t < BM){
    int pe = perm[e0+t];
    srcl[t] = src[pe]; dstl[t] = dst[pe]; eidl[t] = eids[pe];
  }
  __syncthreads();

  // stage kv_j = xb[src] into KVB (first read is at blend -- chunk syncs cover the hazard)
  {
    const uint4* xbu = (const uint4*)xb;
    #pragma unroll
    for (int it=0; it<2; ++it){
      int g = it*512 + t;
      int e = g >> 4, qq = g & 15;
      *(uint4*)(KVB + swzK(e, qq*16)) = xbu[(long)srcl[e]*16 + qq];
    }
  }

  f32x16 gbG, gbB;
  {
    float bg = Gb[oc] + GATE_BIAS;
    float bb = Bb[oc];
    #pragma unroll
    for (int i=0;i<16;++i){ gbG[i] = bg; gbB[i] = bb; }
  }

  // prologue: issue chunk-0 gather
  bf16x8 xa8[2], ea8[2];
  #pragma unroll
  for (int it=0; it<2; ++it){
    int g = it*512 + t;
    int e = g >> 4, c8 = g & 15;
    xa8[it] = *(const bf16x8*)(XAb + (long)srcl[e]*FFF + c8*8);
    ea8[it] = *(const bf16x8*)(EAb + (long)eidl[e]*FFF + c8*8);
  }

  // 4 chunks of 128 FF-cols; INTB double-buffered: ONE barrier per chunk.
  #pragma unroll
  for (int ch=0; ch<4; ++ch){
    bf16x8 o[2];
    #pragma unroll
    for (int it=0; it<2; ++it){
      #pragma unroll
      for (int j=0;j<8;++j){
        float s = (float)xa8[it][j] + (float)ea8[it][j];
        o[it][j] = (__bf16)((s > 0.f) ? s : (__expf(s) - 1.f));
      }
    }
    unsigned char* INTp = INTB[ch & 1];
    #pragma unroll
    for (int it=0; it<2; ++it){
      int g = it*512 + t;
      int e = g >> 4, c8 = g & 15;
      *(bf16x8*)(INTp + swzK(e, c8*16)) = o[it];
    }
    __syncthreads();   // INT[p] visible; GEMM(ch-2) readers of this buffer finished >=1 sync ago
    if (ch < 3){
      #pragma unroll
      for (int it=0; it<2; ++it){
        int g = it*512 + t;
        int e = g >> 4, c8 = g & 15;
        xa8[it] = *(const bf16x8*)(XAb + (long)srcl[e]*FFF + (ch+1)*128 + c8*8);
        ea8[it] = *(const bf16x8*)(EAb + (long)eidl[e]*FFF + (ch+1)*128 + c8*8);
      }
    }
    // gate GEMM: rows 32R.., cols 32C.., K=128
    {
      const ushort* Wg = Gwb + ((long)(C*32 + ch*8)*64 + l)*8;
      bf16x8 wf[8];
      #pragma unroll
      for (int i=0;i<8;++i) wf[i] = *(const bf16x8*)(Wg + (long)i*512);
      #pragma unroll
      for (int i=0;i<8;++i){
        bf16x8 a = *(const bf16x8*)(INTp + swzK(R*32 + c32, i*32 + hi*16));
        gbG = MFMA32(a, wf[i], gbG);
      }
    }
    // badd GEMM
    {
      const ushort* Wb = Bwb + ((long)(C*32 + ch*8)*64 + l)*8;
      bf16x8 wf[8];
      #pragma unroll
      for (int i=0;i<8;++i) wf[i] = *(const bf16x8*)(Wb + (long)i*512);
      #pragma unroll
      for (int i=0;i<8;++i){
        bf16x8 a = *(const bf16x8*)(INTp + swzK(R*32 + c32, i*32 + hi*16));
        gbB = MFMA32(a, wf[i], gbB);
      }
    }
  }

  // in-register blend: kv2 = badd + sigmoid(gate)*(kv - badd), write back to KVB
  #pragma unroll
  for (int r=0;r<16;++r){
    int row = (r&3) + 8*(r>>2) + 4*hi;
    int gr = R*32 + row;
    float g  = 1.f/(1.f + __expf(-gbG[r]));
    float kv = (float)*(const __bf16*)(KVB + swzK(gr, oc*2));
    float k2 = gbB[r] + g*(kv - gbB[r]);
    *(__bf16*)(KVB + swzK(gr, oc*2)) = (__bf16)k2;
  }
  __syncthreads();   // kv2 ready in KVB

  // K and V GEMMs: wave (R,C) computes K[32R..][32C..] and V[32R..][32C..], K=128
  f32x16 ka, va;
  #pragma unroll
  for (int i=0;i<16;++i){ ka[i] = 0.f; va[i] = 0.f; }
  {
    const ushort* Wk = Kwb + ((long)(C*8)*64 + l)*8;
    bf16x8 wf[8];
    #pragma unroll
    for (int i=0;i<8;++i) wf[i] = *(const bf16x8*)(Wk + (long)i*512);
    #pragma unroll
    for (int i=0;i<8;++i){
      bf16x8 a = *(const bf16x8*)(KVB + swzK(R*32 + c32, i*32 + hi*16));
      ka = MFMA32(a, wf[i], ka);
    }
  }
  {
    const ushort* Wv = Vwb + ((long)(C*8)*64 + l)*8;
    bf16x8 wf[8];
    #pragma unroll
    for (int i=0;i<8;++i) wf[i] = *(const bf16x8*)(Wv + (long)i*512);
    #pragma unroll
    for (int i=0;i<8;++i){
      bf16x8 a = *(const bf16x8*)(KVB + swzK(R*32 + c32, i*32 + hi*16));
      va = MFMA32(a, wf[i], va);
    }
  }
  __syncthreads();   // all KVB reads done; KVB + INTB[0] become fp32 AGB[64][128] (linear)

  // V -> AGB overlay (rows 0..31 -> KVB, 32..63 -> INTB[0])
  #pragma unroll
  for (int r=0;r<16;++r){
    int row = (r&3) + 8*(r>>2) + 4*hi;
    int gr = R*32 + row;
    unsigned char* ab = (gr < 32) ? KVB : INTB[0];
    *(float*)(ab + ((gr & 31)*128 + oc)*4) = va[r];
  }
  // score: k += EK[eid]; dot with q[dst] over head C's 32 cols; EXL = exp
  #pragma unroll
  for (int r=0;r<16;++r){
    int row = (r&3) + 8*(r>>2) + 4*hi;
    int gr = R*32 + row;
    int dn = dstl[gr];
    float kv = ka[r] + EKf[(long)eidl[gr]*DD + oc];
    float p = kv * q[(long)dn*DD + oc];
    p += __shfl_xor(p, 1); p += __shfl_xor(p, 2);
    p += __shfl_xor(p, 4); p += __shfl_xor(p, 8);
    p += __shfl_xor(p, 16);
    if (c32 == 0) EXL[gr][C] = __expf(p);
  }
  __syncthreads();   // EXL + AGB ready

  // segment-reduce (dst-sorted rows): 512 threads = 128 cols x 4 row-groups of 16
  {
    const int col = t & 127;
    const int rg  = t >> 7;
    const int r0  = rg*16;
    const int h   = col >> 5;
    const unsigned char* ab = (rg < 2) ? KVB : INTB[0];   // wave-uniform
    const int rb = (rg & 1) * 16;
    float acc = 0.f;
    int cur = dstl[r0];
    for (int r=0; r<16; ++r){
      int dn = dstl[r0+r];
      if (dn != cur){
        atomicAdd(&agg[(long)cur*DD + col], acc);
        acc = 0.f; cur = dn;
      }
      acc += *(const float*)(ab + ((rb + r)*128 + col)*4) * EXL[r0+r][h];
    }
    atomicAdd(&agg[(long)cur*DD + col], acc);
    if (col < HH){
      float da = 0.f; int cur2 = dstl[r0];
      for (int r=r0; r<r0+16; ++r){
        int dn = dstl[r];
        if (dn != cur2){
          atomicAdd(&denom[cur2*HH + col], da);
          da = 0.f; cur2 = dn;
        }
        da += EXL[r][col];
      }
      atomicAdd(&denom[cur2*HH + col], da);
    }
  }
}

// fused: x1 = x + (agg/denom)@o_w^T;  x = x1 + relu(LN(x1)@wi^T)@wo^T;  emits x, xb.
// v11: FUSE_LNQ tail runs the NEXT layer's LN + q-proj + XA-proj on xn while it is
// still in registers (AB/IB reused as staging; agg/denom re-zeroed for the next k_edge).
template<bool FUSE_LNQ>
__global__ __launch_bounds__(256) void k_node(
    const float* __restrict__ agg, const float* __restrict__ denom,
    const ushort* __restrict__ owb,
    const float* __restrict__ lnw, const float* __restrict__ lnb,
    const ushort* __restrict__ wib, const ushort* __restrict__ wob,
    float* __restrict__ x, ushort* __restrict__ xb,
    const float* __restrict__ nlnw, const float* __restrict__ nlnb,
    const ushort* __restrict__ nqwb, const ushort* __restrict__ na1b,
    float* __restrict__ q, ushort* __restrict__ XAb){
  __shared__ __align__(16) unsigned char AB[NT*256];
  __shared__ __align__(16) unsigned char IB[NT*1024];
  __shared__ __align__(16) float XO[NT][132];
  const int n0 = blockIdx.x*NT;
  const int t = threadIdx.x;
  const int e = t>>4, s = t&15;
  const int w = t>>6, l = t&63, lr = l&15, lg = l>>4;

  {
    const float* ap = agg + (long)(n0+e)*DD + s*8;
    float av[8];
    *(float4*)&av[0] = *(const float4*)ap;
    *(float4*)&av[4] = *(const float4*)(ap+4);
    float dinv = 1.f / denom[(n0+e)*HH + (s>>2)];
    bf16x8 hb;
    #pragma unroll
    for (int i=0;i<8;++i) hb[i] = (__bf16)(av[i]*dinv);
    *(bf16x8*)(AB + swz128(e, s*16)) = hb;
  }
  __syncthreads();

  {
    const int o0 = w*32;
    f32x4 z = {0.f,0.f,0.f,0.f};
    f32x4 acc[2] = {z,z};
    #pragma unroll
    for (int k4=0;k4<4;++k4){
      bf16x8 a = *(const bf16x8*)(AB + swz128(lr, k4*64 + lg*16));
      #pragma unroll
      for (int nt=0;nt<2;++nt){
        bf16x8 b = *(const bf16x8*)(owb + (long)(o0+nt*16+lr)*128 + k4*32 + lg*8);
        acc[nt] = MFMA(a, b, acc[nt]);
      }
    }
    #pragma unroll
    for (int nt=0;nt<2;++nt)
      #pragma unroll
      for (int r=0;r<4;++r)
        XO[lg*4+r][o0+nt*16+lr] = acc[nt][r];
  }
  __syncthreads();

  float x1[8];
  {
    const float* xp = x + (long)(n0+e)*DD + s*8;
    float xv[8];
    *(float4*)&xv[0] = *(const float4*)xp;
    *(float4*)&xv[4] = *(const float4*)(xp+4);
    #pragma unroll
    for (int i=0;i<8;++i) x1[i] = xv[i] + XO[e][s*8+i];
    float sm = 0.f;
    #pragma unroll
    for (int i=0;i<8;++i) sm += x1[i];
    sm += __shfl_xor(sm,1); sm += __shfl_xor(sm,2);
    sm += __shfl_xor(sm,4); sm += __shfl_xor(sm,8);
    float mu = sm*(1.f/DD);
    float sq = 0.f;
    #pragma unroll
    for (int i=0;i<8;++i){ float d = x1[i]-mu; sq += d*d; }
    sq += __shfl_xor(sq,1); sq += __shfl_xor(sq,2);
    sq += __shfl_xor(sq,4); sq += __shfl_xor(sq,8);
    float rstd = rsqrtf(sq*(1.f/DD) + EPS);
    float4 w0 = *(const float4*)(lnw + s*8), w1 = *(const float4*)(lnw + s*8 + 4);
    float4 b0 = *(const float4*)(lnb + s*8), b1 = *(const float4*)(lnb + s*8 + 4);
    float wv[8] = {w0.x,w0.y,w0.z,w0.w,w1.x,w1.y,w1.z,w1.w};
    float bv[8] = {b0.x,b0.y,b0.z,b0.w,b1.x,b1.y,b1.z,b1.w};
    bf16x8 hb;
    #pragma unroll
    for (int i=0;i<8;++i) hb[i] = (__bf16)((x1[i]-mu)*rstd*wv[i] + bv[i]);
    __syncthreads();
    *(bf16x8*)(AB + swz128(e, s*16)) = hb;
  }
  __syncthreads();

  {
    const int f0w = w*128;
    f32x4 z = {0.f,0.f,0.f,0.f};
    f32x4 acc[8] = {z,z,z,z,z,z,z,z};
    #pragma unroll
    for (int k4=0;k4<4;++k4){
      bf16x8 a = *(const bf16x8*)(AB + swz128(lr, k4*64 + lg*16));
      #pragma unroll
      for (int nt=0;nt<8;++nt){
        bf16x8 b = *(const bf16x8*)(wib + (long)(f0w+nt*16+lr)*128 + k4*32 + lg*8);
        acc[nt] = MFMA(a, b, acc[nt]);
      }
    }
    #pragma unroll
    for (int nt=0;nt<8;++nt)
      #pragma unroll
      for (int r=0;r<4;++r){
        int e2 = lg*4 + r;
        int f = f0w + nt*16 + lr;
        float va = acc[nt][r];
        *(__bf16*)(IB + swz512(e2, f*2)) = (__bf16)fmaxf(va, 0.f);
      }
  }
  __syncthreads();

  {
    const int o0 = w*32;
    f32x4 z = {0.f,0.f,0.f,0.f};
    f32x4 acc[2] = {z,z};
    #pragma unroll
    for (int k16=0;k16<16;++k16){
      bf16x8 a = *(const bf16x8*)(IB + swz512(lr, k16*64 + lg*16));
      #pragma unroll
      for (int nt=0;nt<2;++nt){
        bf16x8 b = *(const bf16x8*)(wob + (long)(o0+nt*16+lr)*512 + k16*32 + lg*8);
        acc[nt] = MFMA(a, b, acc[nt]);
      }
    }
    #pragma unroll
    for (int nt=0;nt<2;++nt)
      #pragma unroll
      for (int r=0;r<4;++r)
        XO[lg*4+r][o0+nt*16+lr] = acc[nt][r];
  }
  __syncthreads();

  float xn[8];
  {
    #pragma unroll
    for (int i=0;i<8;++i) xn[i] = x1[i] + XO[e][s*8+i];
    float* xp = x + (long)(n0+e)*DD + s*8;
    *(float4*)xp = *(float4*)&xn[0];
    *(float4*)(xp+4) = *(float4*)&xn[4];
    bf16x8 hb;
    #pragma unroll
    for (int i=0;i<8;++i) hb[i] = (__bf16)xn[i];
    *(bf16x8*)(xb + (long)(n0+e)*DD + s*8) = hb;
  }

  if constexpr (FUSE_LNQ){
    // re-zero agg/denom for the next layer's k_edge (own rows only; read above is done)
    {
      float4 z4 = {0.f,0.f,0.f,0.f};
      float* ap = (float*)agg + (long)n0*DD + t*8;
      *(float4*)ap = z4; *(float4*)(ap+4) = z4;
      if (t < NT*HH) ((float*)denom)[n0*HH + t] = 0.f;
    }
    // next-layer LN on xn (still in registers)
    {
      float sm = 0.f;
      #pragma unroll
      for (int i=0;i<8;++i) sm += xn[i];
      sm += __shfl_xor(sm,1); sm += __shfl_xor(sm,2);
      sm += __shfl_xor(sm,4); sm += __shfl_xor(sm,8);
      float mu = sm*(1.f/DD);
      float sq = 0.f;
      #pragma unroll
      for (int i=0;i<8;++i){ float d = xn[i]-mu; sq += d*d; }
      sq += __shfl_xor(sq,1); sq += __shfl_xor(sq,2);
      sq += __shfl_xor(sq,4); sq += __shfl_xor(sq,8);
      float rstd = rsqrtf(sq*(1.f/DD) + EPS);
      float4 w0 = *(const float4*)(nlnw + s*8), w1 = *(const float4*)(nlnw + s*8 + 4);
      float4 b0 = *(const float4*)(nlnb + s*8), b1 = *(const float4*)(nlnb + s*8 + 4);
      float wv[8] = {w0.x,w0.y,w0.z,w0.w,w1.x,w1.y,w1.z,w1.w};
      float bv[8] = {b0.x,b0.y,b0.z,b0.w,b1.x,b1.y,b1.z,b1.w};
      bf16x8 hb, hr;
      #pragma unroll
      for (int i=0;i<8;++i){
        hb[i] = (__bf16)((xn[i]-mu)*rstd*wv[i] + bv[i]);
        hr[i] = (__bf16)xn[i];
      }
      *(bf16x8*)(AB + swz128(e, s*16)) = hb;             // AB := HB (dead after wi GEMM)
      *(bf16x8*)(IB + swz128(e, s*16)) = hr;             // IB[0:4K] := HR (dead after wo GEMM)
    }
    __syncthreads();
    // q projection (K=128) from AB
    {
      const int o0 = w*32;
      f32x4 z = {0.f,0.f,0.f,0.f};
      f32x4 acc[2] = {z,z};
      #pragma unroll
      for (int k4=0;k4<4;++k4){
        bf16x8 a = *(const bf16x8*)(AB + swz128(lr, k4*64 + lg*16));
        #pragma unroll
        for (int nt=0;nt<2;++nt){
          bf16x8 b = *(const bf16x8*)(nqwb + (long)(o0+nt*16+lr)*128 + k4*32 + lg*8);
          acc[nt] = MFMA(a, b, acc[nt]);
        }
      }
      #pragma unroll
      for (int nt=0;nt<2;++nt)
        #pragma unroll
        for (int r=0;r<4;++r)
          q[(long)(n0 + lg*4 + r)*DD + o0 + nt*16 + lr] = acc[nt][r];
    }
    // XA (512 out, K=128) from IB(HR)
    {
      const int f0w = w*128;
      f32x4 z = {0.f,0.f,0.f,0.f};
      f32x4 acc[8] = {z,z,z,z,z,z,z,z};
      #pragma unroll
      for (int k4=0;k4<4;++k4){
        bf16x8 a = *(const bf16x8*)(IB + swz128(lr, k4*64 + lg*16));
        #pragma unroll
        for (int nt=0;nt<8;++nt){
          bf16x8 b = *(const bf16x8*)(na1b + (long)(f0w+nt*16+lr)*128 + k4*32 + lg*8);
          acc[nt] = MFMA(a, b, acc[nt]);
        }
      }
      #pragma unroll
      for (int nt=0;nt<8;++nt)
        #pragma unroll
        for (int r=0;r<4;++r){
          __hip_bfloat16 h = __float2bfloat16(acc[nt][r]);
          XAb[(long)(n0+lg*4+r)*FFF + f0w+nt*16+lr] = *(ushort*)&h;
        }
    }
  }
}

extern "C" void kernel_launch(void* const* d_in, const int* in_sizes, int n_in,
                              void* d_out, int out_size, void* d_ws, size_t ws_size,
                              hipStream_t stream) {
  const int* node_ids   = (const int*)d_in[0];
  const int* edge_index = (const int*)d_in[1];
  const int* edge_ids   = (const int*)d_in[2];
  const float* node_emb = (const float*)d_in[3];
  const float* edge_emb = (const float*)d_in[4];
  const float* ln_w   = (const float*)d_in[5];
  const float* ln_b   = (const float*)d_in[6];
  const float* q_w    = (const float*)d_in[7];
  const float* relA_w = (const float*)d_in[8];
  const float* relA_b = (const float*)d_in[9];
  const float* relB_w = (const float*)d_in[10];
  const float* relB_b = (const float*)d_in[11];
  const float* relG_w = (const float*)d_in[12];
  const float* relG_b = (const float*)d_in[13];
  const float* k_w    = (const float*)d_in[14];
  const float* v_w    = (const float*)d_in[15];
  const float* o_w    = (const float*)d_in[16];
  const float* ff_ln_w= (const float*)d_in[17];
  const float* ff_ln_b= (const float*)d_in[18];
  const float* wi_w   = (const float*)d_in[19];
  const float* wo_w   = (const float*)d_in[20];
  const int* src = edge_index;        // edge_index[0] = j (kv side)
  const int* dst = edge_index + EE;   // edge_index[1] = i (query side)

  float* ws = (float*)d_ws;
  float* x   = ws;  ws += (long)NN*DD;
  float* q   = ws;  ws += (long)NN*DD;
  float* denom = ws; ws += NN*HH;
  float* agg   = ws; ws += (long)NN*DD;
  float* EKf   = ws; ws += (long)LL*RELV*DD;
  int* hist   = (int*)ws; ws += NN;
  int* perm   = (int*)ws; ws += EE;
  ushort* xb  = (ushort*)ws; ws += (long)NN*DD/2;
  ushort* XAb = (ushort*)ws; ws += (long)NN*FFF/2;
  ushort* EAb = (ushort*)ws; ws += (long)LL*RELV*FFF/2;
  ushort* A1b = (ushort*)ws; ws += (long)LL*FFF*DD/2;
  ushort* Gwb = (ushort*)ws; ws += (long)LL*DD*FFF/2;
  ushort* Bwb = (ushort*)ws; ws += (long)LL*DD*FFF/2;
  ushort* Kwb = (ushort*)ws; ws += (long)LL*DD*DD/2;
  ushort* Vwb = (ushort*)ws; ws += (long)LL*DD*DD/2;
  ushort* Qwb = (ushort*)ws; ws += (long)LL*DD*DD/2;
  ushort* Owb = (ushort*)ws; ws += (long)LL*DD*DD/2;
  ushort* Wib = (ushort*)ws; ws += (long)LL*FFF*DD/2;
  ushort* Wob = (ushort*)ws; ws += (long)LL*DD*FFF/2;

  hipMemsetAsync(hist, 0, NN*sizeof(int), stream);
  k_gx<<<NN/2, 256, 0, stream>>>(node_ids, node_emb, x, xb, dst, hist);
  k_scan<<<1, 256, 0, stream>>>(hist, hist);   // in-place: hist becomes cursor
  k_scatter<<<(EE+255)/256, 256, 0, stream>>>(dst, hist, perm);
  for (int l=0; l<LL; ++l){
    k_prep<<<256, 256, 0, stream>>>(
        relG_w + (long)l*DD*FFF, relB_w + (long)l*DD*FFF,
        k_w + (long)l*DD*256,    v_w + (long)l*DD*DD,
        relA_w + (long)l*FFF*256,
        Gwb + (long)l*DD*FFF, Bwb + (long)l*DD*FFF,
        Kwb + (long)l*DD*DD,  Vwb + (long)l*DD*DD, A1b + (long)l*FFF*DD);
    k_ea<<<RELV, 256, 0, stream>>>(edge_emb, relA_w + (long)l*FFF*256, relA_b + (long)l*FFF,
                                   k_w + (long)l*DD*256, EAb + (long)l*RELV*FFF, EKf + (long)l*RELV*DD);
  }
  k_f2b4<<<512, 256, 0, stream>>>(q_w, o_w, wi_w, wo_w, Qwb, Owb, Wib, Wob);

  // layer 0 front-end
  k_lnq_xa<<<NN/NT, 256, 0, stream>>>(x, ln_w, ln_b, Qwb, A1b, q, XAb, agg, denom);
  for (int l=0; l<LL; ++l){
    k_edge<<<EE/BM, 512, 0, stream>>>(xb, XAb, EAb + (long)l*RELV*FFF, EKf + (long)l*RELV*DD,
        q, src, dst, edge_ids, perm,
        Gwb + (long)l*DD*FFF,  relG_b + (long)l*DD,
        Bwb + (long)l*DD*FFF,  relB_b + (long)l*DD,
        Kwb + (long)l*DD*DD,   Vwb + (long)l*DD*DD,
        agg, denom);
    if (l < LL-1){
      k_node<true><<<NN/NT, 256, 0, stream>>>(agg, denom, Owb + (long)l*DD*DD,
          ff_ln_w + l*DD, ff_ln_b + l*DD,
          Wib + (long)l*FFF*DD, Wob + (long)l*DD*FFF, x, xb,
          ln_w + (l+1)*DD, ln_b + (l+1)*DD,
          Qwb + (long)(l+1)*DD*DD, A1b + (long)(l+1)*FFF*DD, q, XAb);
    } else {
      k_node<false><<<NN/NT, 256, 0, stream>>>(agg, denom, Owb + (long)l*DD*DD,
          ff_ln_w + l*DD, ff_ln_b + l*DD,
          Wib + (long)l*FFF*DD, Wob + (long)l*DD*FFF, x, xb,
          nullptr, nullptr, nullptr, nullptr, nullptr, nullptr);
    }
  }
  hipMemcpyAsync(d_out, x, (size_t)NN*DD*sizeof(float), hipMemcpyDeviceToDevice, stream);
}

// Round 11
// 437.216 us; speedup vs baseline: 1.1428x; 1.0033x over previous
//
#include <hip/hip_runtime.h>
#include <hip/hip_bf16.h>

#define NN 10000
#define EE 160000
#define DD 128
#define HH 4
#define CC 32
#define FFF 512
#define LL 2
#define RELV 100
#define EPS 1e-6f
#define GATE_BIAS 3.0f
#define BM 64
#define NT 16

typedef __bf16 bf16x8 __attribute__((ext_vector_type(8)));
typedef float f32x4 __attribute__((ext_vector_type(4)));
typedef float f32x16 __attribute__((ext_vector_type(16)));

#define MFMA(a,b,c)   __builtin_amdgcn_mfma_f32_16x16x32_bf16((a),(b),(c),0,0,0)
#define MFMA32(a,b,c) __builtin_amdgcn_mfma_f32_32x32x16_bf16((a),(b),(c),0,0,0)

__device__ __forceinline__ int swzK(int e, int b){ return e*256 + (b ^ ((e&7)<<4)); }   // [64][128] bf16
__device__ __forceinline__ int swz128(int e, int b){ return e*256 + (b ^ ((e&7)<<4)); } // [16][128] bf16
__device__ __forceinline__ int swz512(int e, int b){ return e*1024 + (b ^ ((e&7)<<4)); }// [16][512] bf16

// 256-thr blocks (2 nodes each) + edge-histogram fused in (hist pre-zeroed via memset)
__global__ __launch_bounds__(256) void k_gx(
    const int* __restrict__ node_ids, const float* __restrict__ node_emb,
    float* __restrict__ x, ushort* __restrict__ xb,
    const int* __restrict__ dst, int* __restrict__ hist){
  int b = blockIdx.x, t = threadIdx.x;
  int n = b*2 + (t>>7);
  int c = t & 127;
  float v = node_emb[(long)node_ids[n]*DD + c];
  x[(long)n*DD + c] = v;
  __hip_bfloat16 h = __float2bfloat16(v);
  xb[(long)n*DD + c] = *(ushort*)&h;
  if (t < 32){
    int e = b*32 + t;
    atomicAdd(&hist[dst[e]], 1);
  }
}

// W[?][instride] fp32 -> MFMA32 fragment order bf16 (device helper)
__device__ __forceinline__ void wprep_one(
    const float* __restrict__ in, ushort* __restrict__ out, int tid, int IN, int instride){
  int lane = tid & 63;
  int grp  = tid >> 6;
  int nkb  = IN >> 4;
  int kb   = grp % nkb;
  int cb   = grp / nkb;
  int col  = cb*32 + (lane & 31);
  int k0   = kb*16 + (lane >> 5)*8;
  const float* p = in + (long)col*instride + k0;
  bf16x8 h;
  #pragma unroll
  for (int j=0;j<8;++j) h[j] = (__bf16)p[j];
  *(bf16x8*)(out + (long)tid*8) = h;
}

// fused per-layer weight prep (Gwb,Bwb,Kwb,Vwb wprep + A1b subcast), one launch/layer.
__global__ __launch_bounds__(256) void k_prep(
    const float* __restrict__ relG_w, const float* __restrict__ relB_w,
    const float* __restrict__ k_w, const float* __restrict__ v_w,
    const float* __restrict__ relA_w,
    ushort* __restrict__ Gwb, ushort* __restrict__ Bwb,
    ushort* __restrict__ Kwb, ushort* __restrict__ Vwb, ushort* __restrict__ A1b){
  int tid = blockIdx.x*256 + threadIdx.x;
  if (tid < DD*FFF/8){
    wprep_one(relG_w, Gwb, tid, FFF, FFF);
    wprep_one(relB_w, Bwb, tid, FFF, FFF);
  }
  if (tid < DD*DD/8){
    wprep_one(k_w, Kwb, tid, DD, 256);
    wprep_one(v_w, Vwb, tid, DD, DD);
  }
  {
    int o = tid / DD, i = tid % DD;
    __hip_bfloat16 h = __float2bfloat16(relA_w[(long)o*256 + i]);
    A1b[tid] = *(ushort*)&h;
  }
}

// the 4 plain casts (Qw,Ow,Wi,Wo both layers) in one launch. grid 512 x 256.
__global__ __launch_bounds__(256) void k_f2b4(
    const float* __restrict__ q_w, const float* __restrict__ o_w,
    const float* __restrict__ wi_w, const float* __restrict__ wo_w,
    ushort* __restrict__ Qwb, ushort* __restrict__ Owb,
    ushort* __restrict__ Wib, ushort* __restrict__ Wob){
  long i = (long)blockIdx.x*256 + threadIdx.x;
  const long nV = (long)LL*DD*DD;
  if (i < nV){
    __hip_bfloat16 h1 = __float2bfloat16(q_w[i]); Qwb[i] = *(ushort*)&h1;
    __hip_bfloat16 h2 = __float2bfloat16(o_w[i]); Owb[i] = *(ushort*)&h2;
  }
  {
    __hip_bfloat16 h3 = __float2bfloat16(wi_w[i]); Wib[i] = *(ushort*)&h3;
    __hip_bfloat16 h4 = __float2bfloat16(wo_w[i]); Wob[i] = *(ushort*)&h4;
  }
}

// per-relation precompute: EA2[rel][f] = bf16(emb@Aw2^T + Ab), EK[rel][o] = emb@Kw2^T (fp32)
__global__ __launch_bounds__(256) void k_ea(
    const float* __restrict__ edge_emb, const float* __restrict__ relA_w,
    const float* __restrict__ relA_b, const float* __restrict__ k_w,
    ushort* __restrict__ EA2b, float* __restrict__ EKf){
  int rel = blockIdx.x, t = threadIdx.x;
  __shared__ float emb[128];
  if (t < 128) emb[t] = edge_emb[(long)rel*DD + t];
  __syncthreads();
  for (int f=t; f<FFF; f+=256){
    const float* wr = relA_w + (long)f*256 + 128;
    float s = relA_b[f];
    for (int i=0;i<128;++i) s += emb[i]*wr[i];
    __hip_bfloat16 h = __float2bfloat16(s);
    EA2b[(long)rel*FFF + f] = *(ushort*)&h;
  }
  if (t < 128){
    const float* wr = k_w + (long)t*256 + 128;
    float s = 0.f;
    for (int i=0;i<128;++i) s += emb[i]*wr[i];
    EKf[(long)rel*DD + t] = s;
  }
}

// exclusive prefix of hist[NN] -> cursor[NN]; single block, 256 threads
__global__ __launch_bounds__(256) void k_scan(const int* __restrict__ hist, int* __restrict__ cursor){
  __shared__ int tsum[256];
  const int t = threadIdx.x;
  const int PER = (NN + 255) / 256;   // 40
  const int base = t*PER;
  int s = 0;
  for (int i=0;i<PER;++i){ int idx = base+i; if (idx < NN) s += hist[idx]; }
  tsum[t] = s;
  __syncthreads();
  if (t == 0){
    int run = 0;
    for (int i=0;i<256;++i){ int v = tsum[i]; tsum[i] = run; run += v; }
  }
  __syncthreads();
  int run = tsum[t];
  for (int i=0;i<PER;++i){
    int idx = base+i;
    if (idx < NN){ int v = hist[idx]; cursor[idx] = run; run += v; }
  }
}
__global__ __launch_bounds__(256) void k_scatter(const int* __restrict__ dst,
    int* __restrict__ cursor, int* __restrict__ perm){
  int e = blockIdx.x*256 + threadIdx.x;
  if (e < EE){
    int p = atomicAdd(&cursor[dst[e]], 1);
    perm[p] = e;
  }
}

// fused LN+q-proj AND XA = x@Aw1^T; also zeroes agg/denom. (layer 0 only; later layers fused in k_node)
__global__ __launch_bounds__(256) void k_lnq_xa(
    const float* __restrict__ x, const float* __restrict__ lnw, const float* __restrict__ lnb,
    const ushort* __restrict__ qwb, const ushort* __restrict__ a1b,
    float* __restrict__ q, ushort* __restrict__ XAb,
    float* __restrict__ agg, float* __restrict__ denom){
  __shared__ __align__(16) unsigned char HB[NT*256];    // LN'd x (bf16)
  __shared__ __align__(16) unsigned char HR[NT*256];    // raw x (bf16)
  const int n0 = blockIdx.x*NT;
  const int t = threadIdx.x;
  const int e = t>>4, s = t&15;
  const int w = t>>6, l = t&63, lr = l&15, lg = l>>4;
  {
    float4 z4 = {0.f,0.f,0.f,0.f};
    float* ap = agg + (long)n0*DD + t*8;
    *(float4*)ap = z4; *(float4*)(ap+4) = z4;
    if (t < NT*HH) denom[n0*HH + t] = 0.f;
  }
  {
    const float* xp = x + (long)(n0+e)*DD + s*8;
    float xv[8];
    *(float4*)&xv[0] = *(const float4*)xp;
    *(float4*)&xv[4] = *(const float4*)(xp+4);
    float sm = 0.f;
    #pragma unroll
    for (int i=0;i<8;++i) sm += xv[i];
    sm += __shfl_xor(sm,1); sm += __shfl_xor(sm,2);
    sm += __shfl_xor(sm,4); sm += __shfl_xor(sm,8);
    float mu = sm*(1.f/DD);
    float sq = 0.f;
    #pragma unroll
    for (int i=0;i<8;++i){ float d = xv[i]-mu; sq += d*d; }
    sq += __shfl_xor(sq,1); sq += __shfl_xor(sq,2);
    sq += __shfl_xor(sq,4); sq += __shfl_xor(sq,8);
    float rstd = rsqrtf(sq*(1.f/DD) + EPS);
    float4 w0 = *(const float4*)(lnw + s*8), w1 = *(const float4*)(lnw + s*8 + 4);
    float4 b0 = *(const float4*)(lnb + s*8), b1 = *(const float4*)(lnb + s*8 + 4);
    float wv[8] = {w0.x,w0.y,w0.z,w0.w,w1.x,w1.y,w1.z,w1.w};
    float bv[8] = {b0.x,b0.y,b0.z,b0.w,b1.x,b1.y,b1.z,b1.w};
    bf16x8 hb, hr;
    #pragma unroll
    for (int i=0;i<8;++i){
      hb[i] = (__bf16)((xv[i]-mu)*rstd*wv[i] + bv[i]);
      hr[i] = (__bf16)xv[i];
    }
    *(bf16x8*)(HB + swz128(e, s*16)) = hb;
    *(bf16x8*)(HR + swz128(e, s*16)) = hr;
  }
  __syncthreads();
  // q projection (K=128) from HB
  {
    const int o0 = w*32;
    f32x4 z = {0.f,0.f,0.f,0.f};
    f32x4 acc[2] = {z,z};
    #pragma unroll
    for (int k4=0;k4<4;++k4){
      bf16x8 a = *(const bf16x8*)(HB + swz128(lr, k4*64 + lg*16));
      #pragma unroll
      for (int nt=0;nt<2;++nt){
        bf16x8 b = *(const bf16x8*)(qwb + (long)(o0+nt*16+lr)*128 + k4*32 + lg*8);
        acc[nt] = MFMA(a, b, acc[nt]);
      }
    }
    #pragma unroll
    for (int nt=0;nt<2;++nt)
      #pragma unroll
      for (int r=0;r<4;++r)
        q[(long)(n0 + lg*4 + r)*DD + o0 + nt*16 + lr] = acc[nt][r];
  }
  // XA (512 out, K=128) from HR
  {
    const int f0w = w*128;
    f32x4 z = {0.f,0.f,0.f,0.f};
    f32x4 acc[8] = {z,z,z,z,z,z,z,z};
    #pragma unroll
    for (int k4=0;k4<4;++k4){
      bf16x8 a = *(const bf16x8*)(HR + swz128(lr, k4*64 + lg*16));
      #pragma unroll
      for (int nt=0;nt<8;++nt){
        bf16x8 b = *(const bf16x8*)(a1b + (long)(f0w+nt*16+lr)*128 + k4*32 + lg*8);
        acc[nt] = MFMA(a, b, acc[nt]);
      }
    }
    #pragma unroll
    for (int nt=0;nt<8;++nt)
      #pragma unroll
      for (int r=0;r<4;++r){
        __hip_bfloat16 h = __float2bfloat16(acc[nt][r]);
        XAb[(long)(n0+lg*4+r)*FFF + f0w+nt*16+lr] = *(ushort*)&h;
      }
  }
}

// --- fused edge kernel (dst-sorted) ---
// v12: reduce tail eliminated. Wave (R,C) already holds both ex(row) (after the score
// butterfly, ALL lanes have the row's full score) and va[row][col in head C] -- the
// weighted scatter va*ex happens in-register with a 4-run segment merge + atomics.
// Removes AGB overlay, EXL staging, the segment-reduce phase, and 2 barriers (8 -> 6).
__global__ __launch_bounds__(512,4) void k_edge(
    const ushort* __restrict__ xb, const ushort* __restrict__ XAb,
    const ushort* __restrict__ EAb, const float* __restrict__ EKf,
    const float* __restrict__ q,
    const int* __restrict__ src, const int* __restrict__ dst, const int* __restrict__ eids,
    const int* __restrict__ perm,
    const ushort* __restrict__ Gwb, const float* __restrict__ Gb,
    const ushort* __restrict__ Bwb, const float* __restrict__ Bb,
    const ushort* __restrict__ Kwb, const ushort* __restrict__ Vwb,
    float* __restrict__ agg, float* __restrict__ denom)
{
  __shared__ __align__(16) unsigned char KVB[BM*256];      // 16KB kv2 bf16 [64][128] swz
  __shared__ __align__(16) unsigned char INTB[2][BM*256];  // 32KB celu chunk dbuf
  __shared__ int srcl[BM], dstl[BM], eidl[BM];

  // bijective XCD-chunked swizzle (nwg=2500, nwg%8=4)
  int nb;
  {
    const int nwg = EE/BM;
    const int q0 = nwg >> 3;
    const int r0 = nwg & 7;
    int xcd = blockIdx.x & 7, sub = blockIdx.x >> 3;
    nb = (xcd < r0 ? xcd*(q0+1) : r0*(q0+1) + (xcd - r0)*q0) + sub;
  }
  const int e0 = nb * BM;
  const int t  = threadIdx.x;
  const int w  = t >> 6;
  const int l  = t & 63;
  const int c32 = l & 31;
  const int hi  = l >> 5;
  const int R = w >> 2;          // row-group (edges 32R..32R+32)
  const int C = w & 3;           // col-quarter / head
  const int oc = C*32 + c32;

  if (t < BM){
    int pe = perm[e0+t];
    srcl[t] = src[pe]; dstl[t] = dst[pe]; eidl[t] = eids[pe];
  }
  __syncthreads();

  // stage kv_j = xb[src] into KVB (first read is at blend -- chunk syncs cover the hazard)
  {
    const uint4* xbu = (const uint4*)xb;
    #pragma unroll
    for (int it=0; it<2; ++it){
      int g = it*512 + t;
      int e = g >> 4, qq = g & 15;
      *(uint4*)(KVB + swzK(e, qq*16)) = xbu[(long)srcl[e]*16 + qq];
    }
  }

  f32x16 gbG, gbB;
  {
    float bg = Gb[oc] + GATE_BIAS;
    float bb = Bb[oc];
    #pragma unroll
    for (int i=0;i<16;++i){ gbG[i] = bg; gbB[i] = bb; }
  }

  // prologue: issue chunk-0 gather
  bf16x8 xa8[2], ea8[2];
  #pragma unroll
  for (int it=0; it<2; ++it){
    int g = it*512 + t;
    int e = g >> 4, c8 = g & 15;
    xa8[it] = *(const bf16x8*)(XAb + (long)srcl[e]*FFF + c8*8);
    ea8[it] = *(const bf16x8*)(EAb + (long)eidl[e]*FFF + c8*8);
  }

  // 4 chunks of 128 FF-cols; INTB double-buffered: ONE barrier per chunk.
  #pragma unroll
  for (int ch=0; ch<4; ++ch){
    bf16x8 o[2];
    #pragma unroll
    for (int it=0; it<2; ++it){
      #pragma unroll
      for (int j=0;j<8;++j){
        float s = (float)xa8[it][j] + (float)ea8[it][j];
        o[it][j] = (__bf16)((s > 0.f) ? s : (__expf(s) - 1.f));
      }
    }
    unsigned char* INTp = INTB[ch & 1];
    #pragma unroll
    for (int it=0; it<2; ++it){
      int g = it*512 + t;
      int e = g >> 4, c8 = g & 15;
      *(bf16x8*)(INTp + swzK(e, c8*16)) = o[it];
    }
    __syncthreads();   // INT[p] visible; GEMM(ch-2) readers of this buffer finished >=1 sync ago
    if (ch < 3){
      #pragma unroll
      for (int it=0; it<2; ++it){
        int g = it*512 + t;
        int e = g >> 4, c8 = g & 15;
        xa8[it] = *(const bf16x8*)(XAb + (long)srcl[e]*FFF + (ch+1)*128 + c8*8);
        ea8[it] = *(const bf16x8*)(EAb + (long)eidl[e]*FFF + (ch+1)*128 + c8*8);
      }
    }
    // gate GEMM: rows 32R.., cols 32C.., K=128
    {
      const ushort* Wg = Gwb + ((long)(C*32 + ch*8)*64 + l)*8;
      bf16x8 wf[8];
      #pragma unroll
      for (int i=0;i<8;++i) wf[i] = *(const bf16x8*)(Wg + (long)i*512);
      #pragma unroll
      for (int i=0;i<8;++i){
        bf16x8 a = *(const bf16x8*)(INTp + swzK(R*32 + c32, i*32 + hi*16));
        gbG = MFMA32(a, wf[i], gbG);
      }
    }
    // badd GEMM
    {
      const ushort* Wb = Bwb + ((long)(C*32 + ch*8)*64 + l)*8;
      bf16x8 wf[8];
      #pragma unroll
      for (int i=0;i<8;++i) wf[i] = *(const bf16x8*)(Wb + (long)i*512);
      #pragma unroll
      for (int i=0;i<8;++i){
        bf16x8 a = *(const bf16x8*)(INTp + swzK(R*32 + c32, i*32 + hi*16));
        gbB = MFMA32(a, wf[i], gbB);
      }
    }
  }

  // in-register blend: kv2 = badd + sigmoid(gate)*(kv - badd), write back to KVB
  #pragma unroll
  for (int r=0;r<16;++r){
    int row = (r&3) + 8*(r>>2) + 4*hi;
    int gr = R*32 + row;
    float g  = 1.f/(1.f + __expf(-gbG[r]));
    float kv = (float)*(const __bf16*)(KVB + swzK(gr, oc*2));
    float k2 = gbB[r] + g*(kv - gbB[r]);
    *(__bf16*)(KVB + swzK(gr, oc*2)) = (__bf16)k2;
  }
  __syncthreads();   // kv2 ready in KVB

  // K and V GEMMs: wave (R,C) computes K[32R..][32C..] and V[32R..][32C..], K=128
  f32x16 ka, va;
  #pragma unroll
  for (int i=0;i<16;++i){ ka[i] = 0.f; va[i] = 0.f; }
  {
    const ushort* Wk = Kwb + ((long)(C*8)*64 + l)*8;
    bf16x8 wf[8];
    #pragma unroll
    for (int i=0;i<8;++i) wf[i] = *(const bf16x8*)(Wk + (long)i*512);
    #pragma unroll
    for (int i=0;i<8;++i){
      bf16x8 a = *(const bf16x8*)(KVB + swzK(R*32 + c32, i*32 + hi*16));
      ka = MFMA32(a, wf[i], ka);
    }
  }
  {
    const ushort* Wv = Vwb + ((long)(C*8)*64 + l)*8;
    bf16x8 wf[8];
    #pragma unroll
    for (int i=0;i<8;++i) wf[i] = *(const bf16x8*)(Wv + (long)i*512);
    #pragma unroll
    for (int i=0;i<8;++i){
      bf16x8 a = *(const bf16x8*)(KVB + swzK(R*32 + c32, i*32 + hi*16));
      va = MFMA32(a, wf[i], va);
    }
  }
  // no barrier needed: nothing writes LDS after this point.

  // fused score + exp + weighted in-register segment scatter.
  // Thread owns rows {8q+4hi+j + 32R : q=0..3, j=0..3}: 4 runs of 4 CONSECUTIVE sorted rows.
  #pragma unroll
  for (int qq=0; qq<4; ++qq){
    const int base = R*32 + 8*qq + 4*hi;
    float ex[4];
    #pragma unroll
    for (int j=0;j<4;++j){
      int r = qq*4 + j;
      int gr = base + j;
      float kv = ka[r] + EKf[(long)eidl[gr]*DD + oc];
      float p = kv * q[(long)dstl[gr]*DD + oc];
      p += __shfl_xor(p, 1); p += __shfl_xor(p, 2);
      p += __shfl_xor(p, 4); p += __shfl_xor(p, 8);
      p += __shfl_xor(p, 16);
      ex[j] = __expf(p);          // all 32 lanes of the half-wave hold the row's score
    }
    // agg scatter: merge consecutive rows sharing dst (branch is half-wave-uniform)
    {
      float acc = va[qq*4]*ex[0];
      int cur = dstl[base];
      #pragma unroll
      for (int j=1;j<4;++j){
        int dn = dstl[base+j];
        if (dn != cur){
          atomicAdd(&agg[(long)cur*DD + oc], acc);
          acc = 0.f; cur = dn;
        }
        acc += va[qq*4+j]*ex[j];
      }
      atomicAdd(&agg[(long)cur*DD + oc], acc);
    }
    // denom scatter: one lane per half-wave
    if (c32 == 0){
      float da = ex[0];
      int cur = dstl[base];
      #pragma unroll
      for (int j=1;j<4;++j){
        int dn = dstl[base+j];
        if (dn != cur){
          atomicAdd(&denom[cur*HH + C], da);
          da = 0.f; cur = dn;
        }
        da += ex[j];
      }
      atomicAdd(&denom[cur*HH + C], da);
    }
  }
}

// fused: x1 = x + (agg/denom)@o_w^T;  x = x1 + relu(LN(x1)@wi^T)@wo^T;  emits x, xb.
// FUSE_LNQ tail runs the NEXT layer's LN + q-proj + XA-proj on xn in registers.
template<bool FUSE_LNQ>
__global__ __launch_bounds__(256) void k_node(
    const float* __restrict__ agg, const float* __restrict__ denom,
    const ushort* __restrict__ owb,
    const float* __restrict__ lnw, const float* __restrict__ lnb,
    const ushort* __restrict__ wib, const ushort* __restrict__ wob,
    float* __restrict__ x, ushort* __restrict__ xb,
    const float* __restrict__ nlnw, const float* __restrict__ nlnb,
    const ushort* __restrict__ nqwb, const ushort* __restrict__ na1b,
    float* __restrict__ q, ushort* __restrict__ XAb){
  __shared__ __align__(16) unsigned char AB[NT*256];
  __shared__ __align__(16) unsigned char IB[NT*1024];
  __shared__ __align__(16) float XO[NT][132];
  const int n0 = blockIdx.x*NT;
  const int t = threadIdx.x;
  const int e = t>>4, s = t&15;
  const int w = t>>6, l = t&63, lr = l&15, lg = l>>4;

  {
    const float* ap = agg + (long)(n0+e)*DD + s*8;
    float av[8];
    *(float4*)&av[0] = *(const float4*)ap;
    *(float4*)&av[4] = *(const float4*)(ap+4);
    float dinv = 1.f / denom[(n0+e)*HH + (s>>2)];
    bf16x8 hb;
    #pragma unroll
    for (int i=0;i<8;++i) hb[i] = (__bf16)(av[i]*dinv);
    *(bf16x8*)(AB + swz128(e, s*16)) = hb;
  }
  __syncthreads();

  {
    const int o0 = w*32;
    f32x4 z = {0.f,0.f,0.f,0.f};
    f32x4 acc[2] = {z,z};
    #pragma unroll
    for (int k4=0;k4<4;++k4){
      bf16x8 a = *(const bf16x8*)(AB + swz128(lr, k4*64 + lg*16));
      #pragma unroll
      for (int nt=0;nt<2;++nt){
        bf16x8 b = *(const bf16x8*)(owb + (long)(o0+nt*16+lr)*128 + k4*32 + lg*8);
        acc[nt] = MFMA(a, b, acc[nt]);
      }
    }
    #pragma unroll
    for (int nt=0;nt<2;++nt)
      #pragma unroll
      for (int r=0;r<4;++r)
        XO[lg*4+r][o0+nt*16+lr] = acc[nt][r];
  }
  __syncthreads();

  float x1[8];
  {
    const float* xp = x + (long)(n0+e)*DD + s*8;
    float xv[8];
    *(float4*)&xv[0] = *(const float4*)xp;
    *(float4*)&xv[4] = *(const float4*)(xp+4);
    #pragma unroll
    for (int i=0;i<8;++i) x1[i] = xv[i] + XO[e][s*8+i];
    float sm = 0.f;
    #pragma unroll
    for (int i=0;i<8;++i) sm += x1[i];
    sm += __shfl_xor(sm,1); sm += __shfl_xor(sm,2);
    sm += __shfl_xor(sm,4); sm += __shfl_xor(sm,8);
    float mu = sm*(1.f/DD);
    float sq = 0.f;
    #pragma unroll
    for (int i=0;i<8;++i){ float d = x1[i]-mu; sq += d*d; }
    sq += __shfl_xor(sq,1); sq += __shfl_xor(sq,2);
    sq += __shfl_xor(sq,4); sq += __shfl_xor(sq,8);
    float rstd = rsqrtf(sq*(1.f/DD) + EPS);
    float4 w0 = *(const float4*)(lnw + s*8), w1 = *(const float4*)(lnw + s*8 + 4);
    float4 b0 = *(const float4*)(lnb + s*8), b1 = *(const float4*)(lnb + s*8 + 4);
    float wv[8] = {w0.x,w0.y,w0.z,w0.w,w1.x,w1.y,w1.z,w1.w};
    float bv[8] = {b0.x,b0.y,b0.z,b0.w,b1.x,b1.y,b1.z,b1.w};
    bf16x8 hb;
    #pragma unroll
    for (int i=0;i<8;++i) hb[i] = (__bf16)((x1[i]-mu)*rstd*wv[i] + bv[i]);
    __syncthreads();
    *(bf16x8*)(AB + swz128(e, s*16)) = hb;
  }
  __syncthreads();

  {
    const int f0w = w*128;
    f32x4 z = {0.f,0.f,0.f,0.f};
    f32x4 acc[8] = {z,z,z,z,z,z,z,z};
    #pragma unroll
    for (int k4=0;k4<4;++k4){
      bf16x8 a = *(const bf16x8*)(AB + swz128(lr, k4*64 + lg*16));
      #pragma unroll
      for (int nt=0;nt<8;++nt){
        bf16x8 b = *(const bf16x8*)(wib + (long)(f0w+nt*16+lr)*128 + k4*32 + lg*8);
        acc[nt] = MFMA(a, b, acc[nt]);
      }
    }
    #pragma unroll
    for (int nt=0;nt<8;++nt)
      #pragma unroll
      for (int r=0;r<4;++r){
        int e2 = lg*4 + r;
        int f = f0w + nt*16 + lr;
        float va = acc[nt][r];
        *(__bf16*)(IB + swz512(e2, f*2)) = (__bf16)fmaxf(va, 0.f);
      }
  }
  __syncthreads();

  {
    const int o0 = w*32;
    f32x4 z = {0.f,0.f,0.f,0.f};
    f32x4 acc[2] = {z,z};
    #pragma unroll
    for (int k16=0;k16<16;++k16){
      bf16x8 a = *(const bf16x8*)(IB + swz512(lr, k16*64 + lg*16));
      #pragma unroll
      for (int nt=0;nt<2;++nt){
        bf16x8 b = *(const bf16x8*)(wob + (long)(o0+nt*16+lr)*512 + k16*32 + lg*8);
        acc[nt] = MFMA(a, b, acc[nt]);
      }
    }
    #pragma unroll
    for (int nt=0;nt<2;++nt)
      #pragma unroll
      for (int r=0;r<4;++r)
        XO[lg*4+r][o0+nt*16+lr] = acc[nt][r];
  }
  __syncthreads();

  float xn[8];
  {
    #pragma unroll
    for (int i=0;i<8;++i) xn[i] = x1[i] + XO[e][s*8+i];
    float* xp = x + (long)(n0+e)*DD + s*8;
    *(float4*)xp = *(float4*)&xn[0];
    *(float4*)(xp+4) = *(float4*)&xn[4];
    bf16x8 hb;
    #pragma unroll
    for (int i=0;i<8;++i) hb[i] = (__bf16)xn[i];
    *(bf16x8*)(xb + (long)(n0+e)*DD + s*8) = hb;
  }

  if constexpr (FUSE_LNQ){
    // re-zero agg/denom for the next layer's k_edge (own rows only; read above is done)
    {
      float4 z4 = {0.f,0.f,0.f,0.f};
      float* ap = (float*)agg + (long)n0*DD + t*8;
      *(float4*)ap = z4; *(float4*)(ap+4) = z4;
      if (t < NT*HH) ((float*)denom)[n0*HH + t] = 0.f;
    }
    // next-layer LN on xn (still in registers)
    {
      float sm = 0.f;
      #pragma unroll
      for (int i=0;i<8;++i) sm += xn[i];
      sm += __shfl_xor(sm,1); sm += __shfl_xor(sm,2);
      sm += __shfl_xor(sm,4); sm += __shfl_xor(sm,8);
      float mu = sm*(1.f/DD);
      float sq = 0.f;
      #pragma unroll
      for (int i=0;i<8;++i){ float d = xn[i]-mu; sq += d*d; }
      sq += __shfl_xor(sq,1); sq += __shfl_xor(sq,2);
      sq += __shfl_xor(sq,4); sq += __shfl_xor(sq,8);
      float rstd = rsqrtf(sq*(1.f/DD) + EPS);
      float4 w0 = *(const float4*)(nlnw + s*8), w1 = *(const float4*)(nlnw + s*8 + 4);
      float4 b0 = *(const float4*)(nlnb + s*8), b1 = *(const float4*)(nlnb + s*8 + 4);
      float wv[8] = {w0.x,w0.y,w0.z,w0.w,w1.x,w1.y,w1.z,w1.w};
      float bv[8] = {b0.x,b0.y,b0.z,b0.w,b1.x,b1.y,b1.z,b1.w};
      bf16x8 hb, hr;
      #pragma unroll
      for (int i=0;i<8;++i){
        hb[i] = (__bf16)((xn[i]-mu)*rstd*wv[i] + bv[i]);
        hr[i] = (__bf16)xn[i];
      }
      *(bf16x8*)(AB + swz128(e, s*16)) = hb;             // AB := HB (dead after wi GEMM)
      *(bf16x8*)(IB + swz128(e, s*16)) = hr;             // IB[0:4K] := HR (dead after wo GEMM)
    }
    __syncthreads();
    // q projection (K=128) from AB
    {
      const int o0 = w*32;
      f32x4 z = {0.f,0.f,0.f,0.f};
      f32x4 acc[2] = {z,z};
      #pragma unroll
      for (int k4=0;k4<4;++k4){
        bf16x8 a = *(const bf16x8*)(AB + swz128(lr, k4*64 + lg*16));
        #pragma unroll
        for (int nt=0;nt<2;++nt){
          bf16x8 b = *(const bf16x8*)(nqwb + (long)(o0+nt*16+lr)*128 + k4*32 + lg*8);
          acc[nt] = MFMA(a, b, acc[nt]);
        }
      }
      #pragma unroll
      for (int nt=0;nt<2;++nt)
        #pragma unroll
        for (int r=0;r<4;++r)
          q[(long)(n0 + lg*4 + r)*DD + o0 + nt*16 + lr] = acc[nt][r];
    }
    // XA (512 out, K=128) from IB(HR)
    {
      const int f0w = w*128;
      f32x4 z = {0.f,0.f,0.f,0.f};
      f32x4 acc[8] = {z,z,z,z,z,z,z,z};
      #pragma unroll
      for (int k4=0;k4<4;++k4){
        bf16x8 a = *(const bf16x8*)(IB + swz128(lr, k4*64 + lg*16));
        #pragma unroll
        for (int nt=0;nt<8;++nt){
          bf16x8 b = *(const bf16x8*)(na1b + (long)(f0w+nt*16+lr)*128 + k4*32 + lg*8);
          acc[nt] = MFMA(a, b, acc[nt]);
        }
      }
      #pragma unroll
      for (int nt=0;nt<8;++nt)
        #pragma unroll
        for (int r=0;r<4;++r){
          __hip_bfloat16 h = __float2bfloat16(acc[nt][r]);
          XAb[(long)(n0+lg*4+r)*FFF + f0w+nt*16+lr] = *(ushort*)&h;
        }
    }
  }
}

extern "C" void kernel_launch(void* const* d_in, const int* in_sizes, int n_in,
                              void* d_out, int out_size, void* d_ws, size_t ws_size,
                              hipStream_t stream) {
  const int* node_ids   = (const int*)d_in[0];
  const int* edge_index = (const int*)d_in[1];
  const int* edge_ids   = (const int*)d_in[2];
  const float* node_emb = (const float*)d_in[3];
  const float* edge_emb = (const float*)d_in[4];
  const float* ln_w   = (const float*)d_in[5];
  const float* ln_b   = (const float*)d_in[6];
  const float* q_w    = (const float*)d_in[7];
  const float* relA_w = (const float*)d_in[8];
  const float* relA_b = (const float*)d_in[9];
  const float* relB_w = (const float*)d_in[10];
  const float* relB_b = (const float*)d_in[11];
  const float* relG_w = (const float*)d_in[12];
  const float* relG_b = (const float*)d_in[13];
  const float* k_w    = (const float*)d_in[14];
  const float* v_w    = (const float*)d_in[15];
  const float* o_w    = (const float*)d_in[16];
  const float* ff_ln_w= (const float*)d_in[17];
  const float* ff_ln_b= (const float*)d_in[18];
  const float* wi_w   = (const float*)d_in[19];
  const float* wo_w   = (const float*)d_in[20];
  const int* src = edge_index;        // edge_index[0] = j (kv side)
  const int* dst = edge_index + EE;   // edge_index[1] = i (query side)

  float* ws = (float*)d_ws;
  float* x   = ws;  ws += (long)NN*DD;
  float* q   = ws;  ws += (long)NN*DD;
  float* denom = ws; ws += NN*HH;
  float* agg   = ws; ws += (long)NN*DD;
  float* EKf   = ws; ws += (long)LL*RELV*DD;
  int* hist   = (int*)ws; ws += NN;
  int* perm   = (int*)ws; ws += EE;
  ushort* xb  = (ushort*)ws; ws += (long)NN*DD/2;
  ushort* XAb = (ushort*)ws; ws += (long)NN*FFF/2;
  ushort* EAb = (ushort*)ws; ws += (long)LL*RELV*FFF/2;
  ushort* A1b = (ushort*)ws; ws += (long)LL*FFF*DD/2;
  ushort* Gwb = (ushort*)ws; ws += (long)LL*DD*FFF/2;
  ushort* Bwb = (ushort*)ws; ws += (long)LL*DD*FFF/2;
  ushort* Kwb = (ushort*)ws; ws += (long)LL*DD*DD/2;
  ushort* Vwb = (ushort*)ws; ws += (long)LL*DD*DD/2;
  ushort* Qwb = (ushort*)ws; ws += (long)LL*DD*DD/2;
  ushort* Owb = (ushort*)ws; ws += (long)LL*DD*DD/2;
  ushort* Wib = (ushort*)ws; ws += (long)LL*FFF*DD/2;
  ushort* Wob = (ushort*)ws; ws += (long)LL*DD*FFF/2;

  hipMemsetAsync(hist, 0, NN*sizeof(int), stream);
  k_gx<<<NN/2, 256, 0, stream>>>(node_ids, node_emb, x, xb, dst, hist);
  k_scan<<<1, 256, 0, stream>>>(hist, hist);   // in-place: hist becomes cursor
  k_scatter<<<(EE+255)/256, 256, 0, stream>>>(dst, hist, perm);
  for (int l=0; l<LL; ++l){
    k_prep<<<256, 256, 0, stream>>>(
        relG_w + (long)l*DD*FFF, relB_w + (long)l*DD*FFF,
        k_w + (long)l*DD*256,    v_w + (long)l*DD*DD,
        relA_w + (long)l*FFF*256,
        Gwb + (long)l*DD*FFF, Bwb + (long)l*DD*FFF,
        Kwb + (long)l*DD*DD,  Vwb + (long)l*DD*DD, A1b + (long)l*FFF*DD);
    k_ea<<<RELV, 256, 0, stream>>>(edge_emb, relA_w + (long)l*FFF*256, relA_b + (long)l*FFF,
                                   k_w + (long)l*DD*256, EAb + (long)l*RELV*FFF, EKf + (long)l*RELV*DD);
  }
  k_f2b4<<<512, 256, 0, stream>>>(q_w, o_w, wi_w, wo_w, Qwb, Owb, Wib, Wob);

  // layer 0 front-end
  k_lnq_xa<<<NN/NT, 256, 0, stream>>>(x, ln_w, ln_b, Qwb, A1b, q, XAb, agg, denom);
  for (int l=0; l<LL; ++l){
    k_edge<<<EE/BM, 512, 0, stream>>>(xb, XAb, EAb + (long)l*RELV*FFF, EKf + (long)l*RELV*DD,
        q, src, dst, edge_ids, perm,
        Gwb + (long)l*DD*FFF,  relG_b + (long)l*DD,
        Bwb + (long)l*DD*FFF,  relB_b + (long)l*DD,
        Kwb + (long)l*DD*DD,   Vwb + (long)l*DD*DD,
        agg, denom);
    if (l < LL-1){
      k_node<true><<<NN/NT, 256, 0, stream>>>(agg, denom, Owb + (long)l*DD*DD,
          ff_ln_w + l*DD, ff_ln_b + l*DD,
          Wib + (long)l*FFF*DD, Wob + (long)l*DD*FFF, x, xb,
          ln_w + (l+1)*DD, ln_b + (l+1)*DD,
          Qwb + (long)(l+1)*DD*DD, A1b + (long)(l+1)*FFF*DD, q, XAb);
    } else {
      k_node<false><<<NN/NT, 256, 0, stream>>>(agg, denom, Owb + (long)l*DD*DD,
          ff_ln_w + l*DD, ff_ln_b + l*DD,
          Wib + (long)l*FFF*DD, Wob + (long)l*DD*FFF, x, xb,
          nullptr, nullptr, nullptr, nullptr, nullptr, nullptr);
    }
  }
  hipMemcpyAsync(d_out, x, (size_t)NN*DD*sizeof(float), hipMemcpyDeviceToDevice, stream);
}

// Round 12
// 426.067 us; speedup vs baseline: 1.1727x; 1.0262x over previous
//
#include <hip/hip_runtime.h>
#include <hip/hip_bf16.h>

#define NN 10000
#define EE 160000
#define DD 128
#define HH 4
#define CC 32
#define FFF 512
#define LL 2
#define RELV 100
#define EPS 1e-6f
#define GATE_BIAS 3.0f
#define BM 32
#define NT 16

typedef __bf16 bf16x8 __attribute__((ext_vector_type(8)));
typedef float f32x4 __attribute__((ext_vector_type(4)));
typedef float f32x16 __attribute__((ext_vector_type(16)));

#define MFMA(a,b,c)   __builtin_amdgcn_mfma_f32_16x16x32_bf16((a),(b),(c),0,0,0)
#define MFMA32(a,b,c) __builtin_amdgcn_mfma_f32_32x32x16_bf16((a),(b),(c),0,0,0)

__device__ __forceinline__ int swzK(int e, int b){ return e*256 + (b ^ ((e&7)<<4)); }   // [R][128] bf16
__device__ __forceinline__ int swz128(int e, int b){ return e*256 + (b ^ ((e&7)<<4)); } // [16][128] bf16
__device__ __forceinline__ int swz512(int e, int b){ return e*1024 + (b ^ ((e&7)<<4)); }// [16][512] bf16

// 256-thr blocks (2 nodes each) + edge-histogram fused in (hist pre-zeroed via memset)
__global__ __launch_bounds__(256) void k_gx(
    const int* __restrict__ node_ids, const float* __restrict__ node_emb,
    float* __restrict__ x, ushort* __restrict__ xb,
    const int* __restrict__ dst, int* __restrict__ hist){
  int b = blockIdx.x, t = threadIdx.x;
  int n = b*2 + (t>>7);
  int c = t & 127;
  float v = node_emb[(long)node_ids[n]*DD + c];
  x[(long)n*DD + c] = v;
  __hip_bfloat16 h = __float2bfloat16(v);
  xb[(long)n*DD + c] = *(ushort*)&h;
  if (t < 32){
    int e = b*32 + t;
    atomicAdd(&hist[dst[e]], 1);
  }
}

// W[?][instride] fp32 -> MFMA32 fragment order bf16 (device helper)
__device__ __forceinline__ void wprep_one(
    const float* __restrict__ in, ushort* __restrict__ out, int tid, int IN, int instride){
  int lane = tid & 63;
  int grp  = tid >> 6;
  int nkb  = IN >> 4;
  int kb   = grp % nkb;
  int cb   = grp / nkb;
  int col  = cb*32 + (lane & 31);
  int k0   = kb*16 + (lane >> 5)*8;
  const float* p = in + (long)col*instride + k0;
  bf16x8 h;
  #pragma unroll
  for (int j=0;j<8;++j) h[j] = (__bf16)p[j];
  *(bf16x8*)(out + (long)tid*8) = h;
}

// fused per-layer weight prep (Gwb,Bwb,Kwb,Vwb wprep + A1b subcast), one launch/layer.
__global__ __launch_bounds__(256) void k_prep(
    const float* __restrict__ relG_w, const float* __restrict__ relB_w,
    const float* __restrict__ k_w, const float* __restrict__ v_w,
    const float* __restrict__ relA_w,
    ushort* __restrict__ Gwb, ushort* __restrict__ Bwb,
    ushort* __restrict__ Kwb, ushort* __restrict__ Vwb, ushort* __restrict__ A1b){
  int tid = blockIdx.x*256 + threadIdx.x;
  if (tid < DD*FFF/8){
    wprep_one(relG_w, Gwb, tid, FFF, FFF);
    wprep_one(relB_w, Bwb, tid, FFF, FFF);
  }
  if (tid < DD*DD/8){
    wprep_one(k_w, Kwb, tid, DD, 256);
    wprep_one(v_w, Vwb, tid, DD, DD);
  }
  {
    int o = tid / DD, i = tid % DD;
    __hip_bfloat16 h = __float2bfloat16(relA_w[(long)o*256 + i]);
    A1b[tid] = *(ushort*)&h;
  }
}

// the 4 plain casts (Qw,Ow,Wi,Wo both layers) in one launch. grid 512 x 256.
__global__ __launch_bounds__(256) void k_f2b4(
    const float* __restrict__ q_w, const float* __restrict__ o_w,
    const float* __restrict__ wi_w, const float* __restrict__ wo_w,
    ushort* __restrict__ Qwb, ushort* __restrict__ Owb,
    ushort* __restrict__ Wib, ushort* __restrict__ Wob){
  long i = (long)blockIdx.x*256 + threadIdx.x;
  const long nV = (long)LL*DD*DD;
  if (i < nV){
    __hip_bfloat16 h1 = __float2bfloat16(q_w[i]); Qwb[i] = *(ushort*)&h1;
    __hip_bfloat16 h2 = __float2bfloat16(o_w[i]); Owb[i] = *(ushort*)&h2;
  }
  {
    __hip_bfloat16 h3 = __float2bfloat16(wi_w[i]); Wib[i] = *(ushort*)&h3;
    __hip_bfloat16 h4 = __float2bfloat16(wo_w[i]); Wob[i] = *(ushort*)&h4;
  }
}

// per-relation precompute: EA2[rel][f] = bf16(emb@Aw2^T + Ab), EK[rel][o] = emb@Kw2^T (fp32)
__global__ __launch_bounds__(256) void k_ea(
    const float* __restrict__ edge_emb, const float* __restrict__ relA_w,
    const float* __restrict__ relA_b, const float* __restrict__ k_w,
    ushort* __restrict__ EA2b, float* __restrict__ EKf){
  int rel = blockIdx.x, t = threadIdx.x;
  __shared__ float emb[128];
  if (t < 128) emb[t] = edge_emb[(long)rel*DD + t];
  __syncthreads();
  for (int f=t; f<FFF; f+=256){
    const float* wr = relA_w + (long)f*256 + 128;
    float s = relA_b[f];
    for (int i=0;i<128;++i) s += emb[i]*wr[i];
    __hip_bfloat16 h = __float2bfloat16(s);
    EA2b[(long)rel*FFF + f] = *(ushort*)&h;
  }
  if (t < 128){
    const float* wr = k_w + (long)t*256 + 128;
    float s = 0.f;
    for (int i=0;i<128;++i) s += emb[i]*wr[i];
    EKf[(long)rel*DD + t] = s;
  }
}

// exclusive prefix of hist[NN] -> cursor[NN]; single block, 256 threads
__global__ __launch_bounds__(256) void k_scan(const int* __restrict__ hist, int* __restrict__ cursor){
  __shared__ int tsum[256];
  const int t = threadIdx.x;
  const int PER = (NN + 255) / 256;   // 40
  const int base = t*PER;
  int s = 0;
  for (int i=0;i<PER;++i){ int idx = base+i; if (idx < NN) s += hist[idx]; }
  tsum[t] = s;
  __syncthreads();
  if (t == 0){
    int run = 0;
    for (int i=0;i<256;++i){ int v = tsum[i]; tsum[i] = run; run += v; }
  }
  __syncthreads();
  int run = tsum[t];
  for (int i=0;i<PER;++i){
    int idx = base+i;
    if (idx < NN){ int v = hist[idx]; cursor[idx] = run; run += v; }
  }
}
__global__ __launch_bounds__(256) void k_scatter(const int* __restrict__ dst,
    int* __restrict__ cursor, int* __restrict__ perm){
  int e = blockIdx.x*256 + threadIdx.x;
  if (e < EE){
    int p = atomicAdd(&cursor[dst[e]], 1);
    perm[p] = e;
  }
}

// fused LN+q-proj AND XA = x@Aw1^T; also zeroes agg/denom. (layer 0 only; later layers fused in k_node)
__global__ __launch_bounds__(256) void k_lnq_xa(
    const float* __restrict__ x, const float* __restrict__ lnw, const float* __restrict__ lnb,
    const ushort* __restrict__ qwb, const ushort* __restrict__ a1b,
    float* __restrict__ q, ushort* __restrict__ XAb,
    float* __restrict__ agg, float* __restrict__ denom){
  __shared__ __align__(16) unsigned char HB[NT*256];    // LN'd x (bf16)
  __shared__ __align__(16) unsigned char HR[NT*256];    // raw x (bf16)
  const int n0 = blockIdx.x*NT;
  const int t = threadIdx.x;
  const int e = t>>4, s = t&15;
  const int w = t>>6, l = t&63, lr = l&15, lg = l>>4;
  {
    float4 z4 = {0.f,0.f,0.f,0.f};
    float* ap = agg + (long)n0*DD + t*8;
    *(float4*)ap = z4; *(float4*)(ap+4) = z4;
    if (t < NT*HH) denom[n0*HH + t] = 0.f;
  }
  {
    const float* xp = x + (long)(n0+e)*DD + s*8;
    float xv[8];
    *(float4*)&xv[0] = *(const float4*)xp;
    *(float4*)&xv[4] = *(const float4*)(xp+4);
    float sm = 0.f;
    #pragma unroll
    for (int i=0;i<8;++i) sm += xv[i];
    sm += __shfl_xor(sm,1); sm += __shfl_xor(sm,2);
    sm += __shfl_xor(sm,4); sm += __shfl_xor(sm,8);
    float mu = sm*(1.f/DD);
    float sq = 0.f;
    #pragma unroll
    for (int i=0;i<8;++i){ float d = xv[i]-mu; sq += d*d; }
    sq += __shfl_xor(sq,1); sq += __shfl_xor(sq,2);
    sq += __shfl_xor(sq,4); sq += __shfl_xor(sq,8);
    float rstd = rsqrtf(sq*(1.f/DD) + EPS);
    float4 w0 = *(const float4*)(lnw + s*8), w1 = *(const float4*)(lnw + s*8 + 4);
    float4 b0 = *(const float4*)(lnb + s*8), b1 = *(const float4*)(lnb + s*8 + 4);
    float wv[8] = {w0.x,w0.y,w0.z,w0.w,w1.x,w1.y,w1.z,w1.w};
    float bv[8] = {b0.x,b0.y,b0.z,b0.w,b1.x,b1.y,b1.z,b1.w};
    bf16x8 hb, hr;
    #pragma unroll
    for (int i=0;i<8;++i){
      hb[i] = (__bf16)((xv[i]-mu)*rstd*wv[i] + bv[i]);
      hr[i] = (__bf16)xv[i];
    }
    *(bf16x8*)(HB + swz128(e, s*16)) = hb;
    *(bf16x8*)(HR + swz128(e, s*16)) = hr;
  }
  __syncthreads();
  // q projection (K=128) from HB
  {
    const int o0 = w*32;
    f32x4 z = {0.f,0.f,0.f,0.f};
    f32x4 acc[2] = {z,z};
    #pragma unroll
    for (int k4=0;k4<4;++k4){
      bf16x8 a = *(const bf16x8*)(HB + swz128(lr, k4*64 + lg*16));
      #pragma unroll
      for (int nt=0;nt<2;++nt){
        bf16x8 b = *(const bf16x8*)(qwb + (long)(o0+nt*16+lr)*128 + k4*32 + lg*8);
        acc[nt] = MFMA(a, b, acc[nt]);
      }
    }
    #pragma unroll
    for (int nt=0;nt<2;++nt)
      #pragma unroll
      for (int r=0;r<4;++r)
        q[(long)(n0 + lg*4 + r)*DD + o0 + nt*16 + lr] = acc[nt][r];
  }
  // XA (512 out, K=128) from HR
  {
    const int f0w = w*128;
    f32x4 z = {0.f,0.f,0.f,0.f};
    f32x4 acc[8] = {z,z,z,z,z,z,z,z};
    #pragma unroll
    for (int k4=0;k4<4;++k4){
      bf16x8 a = *(const bf16x8*)(HR + swz128(lr, k4*64 + lg*16));
      #pragma unroll
      for (int nt=0;nt<8;++nt){
        bf16x8 b = *(const bf16x8*)(a1b + (long)(f0w+nt*16+lr)*128 + k4*32 + lg*8);
        acc[nt] = MFMA(a, b, acc[nt]);
      }
    }
    #pragma unroll
    for (int nt=0;nt<8;++nt)
      #pragma unroll
      for (int r=0;r<4;++r){
        __hip_bfloat16 h = __float2bfloat16(acc[nt][r]);
        XAb[(long)(n0+lg*4+r)*FFF + f0w+nt*16+lr] = *(ushort*)&h;
      }
  }
}

// --- fused edge kernel (dst-sorted) ---
// v13: same per-wave/per-thread work as v12, but BM=32 with 256-thread blocks:
//     barrier domain halves (4 waves, not 8) and the CU hosts ~2x more INDEPENDENT
//     barrier groups -> one tile's barrier stall overlaps another tile's compute.
//     (v6's BM=32 regression kept 512 threads = half work/thread; this keeps work/thread.)
//     LDS ~24.6KB/block. grid = 5000 (divisible by 8 -> exact XCD swizzle).
__global__ __launch_bounds__(256,4) void k_edge(
    const ushort* __restrict__ xb, const ushort* __restrict__ XAb,
    const ushort* __restrict__ EAb, const float* __restrict__ EKf,
    const float* __restrict__ q,
    const int* __restrict__ src, const int* __restrict__ dst, const int* __restrict__ eids,
    const int* __restrict__ perm,
    const ushort* __restrict__ Gwb, const float* __restrict__ Gb,
    const ushort* __restrict__ Bwb, const float* __restrict__ Bb,
    const ushort* __restrict__ Kwb, const ushort* __restrict__ Vwb,
    float* __restrict__ agg, float* __restrict__ denom)
{
  __shared__ __align__(16) unsigned char KVB[BM*256];      // 8KB kv2 bf16 [32][128] swz
  __shared__ __align__(16) unsigned char INTB[2][BM*256];  // 16KB celu chunk dbuf
  __shared__ int srcl[BM], dstl[BM], eidl[BM];

  // exact XCD swizzle: nwg = 5000, divisible by 8
  int nb;
  {
    const int cpx = (EE/BM) >> 3;     // 625
    nb = (blockIdx.x & 7)*cpx + (blockIdx.x >> 3);
  }
  const int e0 = nb * BM;
  const int t  = threadIdx.x;
  const int w  = t >> 6;
  const int l  = t & 63;
  const int c32 = l & 31;
  const int hi  = l >> 5;
  const int C = w;               // head / col-quarter (4 waves)
  const int oc = C*32 + c32;

  if (t < BM){
    int pe = perm[e0+t];
    srcl[t] = src[pe]; dstl[t] = dst[pe]; eidl[t] = eids[pe];
  }
  __syncthreads();

  // stage kv_j = xb[src] into KVB (32 edges x 16 uint4 = 512 over 256 thr)
  {
    const uint4* xbu = (const uint4*)xb;
    #pragma unroll
    for (int it=0; it<2; ++it){
      int g = it*256 + t;
      int e = g >> 4, qq = g & 15;
      *(uint4*)(KVB + swzK(e, qq*16)) = xbu[(long)srcl[e]*16 + qq];
    }
  }

  f32x16 gbG, gbB;
  {
    float bg = Gb[oc] + GATE_BIAS;
    float bb = Bb[oc];
    #pragma unroll
    for (int i=0;i<16;++i){ gbG[i] = bg; gbB[i] = bb; }
  }

  // prologue: issue chunk-0 gather (32 edges x 128 cols = 512 bf16x8 over 256 thr)
  bf16x8 xa8[2], ea8[2];
  #pragma unroll
  for (int it=0; it<2; ++it){
    int g = it*256 + t;
    int e = g >> 4, c8 = g & 15;
    xa8[it] = *(const bf16x8*)(XAb + (long)srcl[e]*FFF + c8*8);
    ea8[it] = *(const bf16x8*)(EAb + (long)eidl[e]*FFF + c8*8);
  }

  // 4 chunks of 128 FF-cols; INTB double-buffered: ONE barrier per chunk.
  #pragma unroll
  for (int ch=0; ch<4; ++ch){
    bf16x8 o[2];
    #pragma unroll
    for (int it=0; it<2; ++it){
      #pragma unroll
      for (int j=0;j<8;++j){
        float s = (float)xa8[it][j] + (float)ea8[it][j];
        o[it][j] = (__bf16)((s > 0.f) ? s : (__expf(s) - 1.f));
      }
    }
    unsigned char* INTp = INTB[ch & 1];
    #pragma unroll
    for (int it=0; it<2; ++it){
      int g = it*256 + t;
      int e = g >> 4, c8 = g & 15;
      *(bf16x8*)(INTp + swzK(e, c8*16)) = o[it];
    }
    __syncthreads();   // INT[p] visible; GEMM(ch-2) readers finished >=1 sync ago
    if (ch < 3){
      #pragma unroll
      for (int it=0; it<2; ++it){
        int g = it*256 + t;
        int e = g >> 4, c8 = g & 15;
        xa8[it] = *(const bf16x8*)(XAb + (long)srcl[e]*FFF + (ch+1)*128 + c8*8);
        ea8[it] = *(const bf16x8*)(EAb + (long)eidl[e]*FFF + (ch+1)*128 + c8*8);
      }
    }
    // gate GEMM: rows 0..31, cols 32C.., K=128
    {
      const ushort* Wg = Gwb + ((long)(C*32 + ch*8)*64 + l)*8;
      bf16x8 wf[8];
      #pragma unroll
      for (int i=0;i<8;++i) wf[i] = *(const bf16x8*)(Wg + (long)i*512);
      #pragma unroll
      for (int i=0;i<8;++i){
        bf16x8 a = *(const bf16x8*)(INTp + swzK(c32, i*32 + hi*16));
        gbG = MFMA32(a, wf[i], gbG);
      }
    }
    // badd GEMM
    {
      const ushort* Wb = Bwb + ((long)(C*32 + ch*8)*64 + l)*8;
      bf16x8 wf[8];
      #pragma unroll
      for (int i=0;i<8;++i) wf[i] = *(const bf16x8*)(Wb + (long)i*512);
      #pragma unroll
      for (int i=0;i<8;++i){
        bf16x8 a = *(const bf16x8*)(INTp + swzK(c32, i*32 + hi*16));
        gbB = MFMA32(a, wf[i], gbB);
      }
    }
  }

  // in-register blend: kv2 = badd + sigmoid(gate)*(kv - badd), write back to KVB
  #pragma unroll
  for (int r=0;r<16;++r){
    int row = (r&3) + 8*(r>>2) + 4*hi;
    float g  = 1.f/(1.f + __expf(-gbG[r]));
    float kv = (float)*(const __bf16*)(KVB + swzK(row, oc*2));
    float k2 = gbB[r] + g*(kv - gbB[r]);
    *(__bf16*)(KVB + swzK(row, oc*2)) = (__bf16)k2;
  }
  __syncthreads();   // kv2 ready in KVB

  // K and V GEMMs: wave C computes K[0..32][32C..] and V[0..32][32C..], K=128
  f32x16 ka, va;
  #pragma unroll
  for (int i=0;i<16;++i){ ka[i] = 0.f; va[i] = 0.f; }
  {
    const ushort* Wk = Kwb + ((long)(C*8)*64 + l)*8;
    bf16x8 wf[8];
    #pragma unroll
    for (int i=0;i<8;++i) wf[i] = *(const bf16x8*)(Wk + (long)i*512);
    #pragma unroll
    for (int i=0;i<8;++i){
      bf16x8 a = *(const bf16x8*)(KVB + swzK(c32, i*32 + hi*16));
      ka = MFMA32(a, wf[i], ka);
    }
  }
  {
    const ushort* Wv = Vwb + ((long)(C*8)*64 + l)*8;
    bf16x8 wf[8];
    #pragma unroll
    for (int i=0;i<8;++i) wf[i] = *(const bf16x8*)(Wv + (long)i*512);
    #pragma unroll
    for (int i=0;i<8;++i){
      bf16x8 a = *(const bf16x8*)(KVB + swzK(c32, i*32 + hi*16));
      va = MFMA32(a, wf[i], va);
    }
  }
  // no barrier needed: nothing writes LDS after this point.

  // fused score + exp + weighted in-register segment scatter.
  // Thread owns rows {8q+4hi+j : q=0..3, j=0..3}: 4 runs of 4 CONSECUTIVE sorted rows.
  #pragma unroll
  for (int qq=0; qq<4; ++qq){
    const int base = 8*qq + 4*hi;
    float ex[4];
    #pragma unroll
    for (int j=0;j<4;++j){
      int r = qq*4 + j;
      int gr = base + j;
      float kv = ka[r] + EKf[(long)eidl[gr]*DD + oc];
      float p = kv * q[(long)dstl[gr]*DD + oc];
      p += __shfl_xor(p, 1); p += __shfl_xor(p, 2);
      p += __shfl_xor(p, 4); p += __shfl_xor(p, 8);
      p += __shfl_xor(p, 16);
      ex[j] = __expf(p);          // all 32 lanes of the half-wave hold the row's score
    }
    // agg scatter: merge consecutive rows sharing dst (branch is half-wave-uniform)
    {
      float acc = va[qq*4]*ex[0];
      int cur = dstl[base];
      #pragma unroll
      for (int j=1;j<4;++j){
        int dn = dstl[base+j];
        if (dn != cur){
          atomicAdd(&agg[(long)cur*DD + oc], acc);
          acc = 0.f; cur = dn;
        }
        acc += va[qq*4+j]*ex[j];
      }
      atomicAdd(&agg[(long)cur*DD + oc], acc);
    }
    // denom scatter: one lane per half-wave
    if (c32 == 0){
      float da = ex[0];
      int cur = dstl[base];
      #pragma unroll
      for (int j=1;j<4;++j){
        int dn = dstl[base+j];
        if (dn != cur){
          atomicAdd(&denom[cur*HH + C], da);
          da = 0.f; cur = dn;
        }
        da += ex[j];
      }
      atomicAdd(&denom[cur*HH + C], da);
    }
  }
}

// fused: x1 = x + (agg/denom)@o_w^T;  x = x1 + relu(LN(x1)@wi^T)@wo^T;  emits x, xb.
// FUSE_LNQ tail runs the NEXT layer's LN + q-proj + XA-proj on xn in registers.
template<bool FUSE_LNQ>
__global__ __launch_bounds__(256) void k_node(
    const float* __restrict__ agg, const float* __restrict__ denom,
    const ushort* __restrict__ owb,
    const float* __restrict__ lnw, const float* __restrict__ lnb,
    const ushort* __restrict__ wib, const ushort* __restrict__ wob,
    float* __restrict__ x, ushort* __restrict__ xb,
    const float* __restrict__ nlnw, const float* __restrict__ nlnb,
    const ushort* __restrict__ nqwb, const ushort* __restrict__ na1b,
    float* __restrict__ q, ushort* __restrict__ XAb){
  __shared__ __align__(16) unsigned char AB[NT*256];
  __shared__ __align__(16) unsigned char IB[NT*1024];
  __shared__ __align__(16) float XO[NT][132];
  const int n0 = blockIdx.x*NT;
  const int t = threadIdx.x;
  const int e = t>>4, s = t&15;
  const int w = t>>6, l = t&63, lr = l&15, lg = l>>4;

  {
    const float* ap = agg + (long)(n0+e)*DD + s*8;
    float av[8];
    *(float4*)&av[0] = *(const float4*)ap;
    *(float4*)&av[4] = *(const float4*)(ap+4);
    float dinv = 1.f / denom[(n0+e)*HH + (s>>2)];
    bf16x8 hb;
    #pragma unroll
    for (int i=0;i<8;++i) hb[i] = (__bf16)(av[i]*dinv);
    *(bf16x8*)(AB + swz128(e, s*16)) = hb;
  }
  __syncthreads();

  {
    const int o0 = w*32;
    f32x4 z = {0.f,0.f,0.f,0.f};
    f32x4 acc[2] = {z,z};
    #pragma unroll
    for (int k4=0;k4<4;++k4){
      bf16x8 a = *(const bf16x8*)(AB + swz128(lr, k4*64 + lg*16));
      #pragma unroll
      for (int nt=0;nt<2;++nt){
        bf16x8 b = *(const bf16x8*)(owb + (long)(o0+nt*16+lr)*128 + k4*32 + lg*8);
        acc[nt] = MFMA(a, b, acc[nt]);
      }
    }
    #pragma unroll
    for (int nt=0;nt<2;++nt)
      #pragma unroll
      for (int r=0;r<4;++r)
        XO[lg*4+r][o0+nt*16+lr] = acc[nt][r];
  }
  __syncthreads();

  float x1[8];
  {
    const float* xp = x + (long)(n0+e)*DD + s*8;
    float xv[8];
    *(float4*)&xv[0] = *(const float4*)xp;
    *(float4*)&xv[4] = *(const float4*)(xp+4);
    #pragma unroll
    for (int i=0;i<8;++i) x1[i] = xv[i] + XO[e][s*8+i];
    float sm = 0.f;
    #pragma unroll
    for (int i=0;i<8;++i) sm += x1[i];
    sm += __shfl_xor(sm,1); sm += __shfl_xor(sm,2);
    sm += __shfl_xor(sm,4); sm += __shfl_xor(sm,8);
    float mu = sm*(1.f/DD);
    float sq = 0.f;
    #pragma unroll
    for (int i=0;i<8;++i){ float d = x1[i]-mu; sq += d*d; }
    sq += __shfl_xor(sq,1); sq += __shfl_xor(sq,2);
    sq += __shfl_xor(sq,4); sq += __shfl_xor(sq,8);
    float rstd = rsqrtf(sq*(1.f/DD) + EPS);
    float4 w0 = *(const float4*)(lnw + s*8), w1 = *(const float4*)(lnw + s*8 + 4);
    float4 b0 = *(const float4*)(lnb + s*8), b1 = *(const float4*)(lnb + s*8 + 4);
    float wv[8] = {w0.x,w0.y,w0.z,w0.w,w1.x,w1.y,w1.z,w1.w};
    float bv[8] = {b0.x,b0.y,b0.z,b0.w,b1.x,b1.y,b1.z,b1.w};
    bf16x8 hb;
    #pragma unroll
    for (int i=0;i<8;++i) hb[i] = (__bf16)((x1[i]-mu)*rstd*wv[i] + bv[i]);
    __syncthreads();
    *(bf16x8*)(AB + swz128(e, s*16)) = hb;
  }
  __syncthreads();

  {
    const int f0w = w*128;
    f32x4 z = {0.f,0.f,0.f,0.f};
    f32x4 acc[8] = {z,z,z,z,z,z,z,z};
    #pragma unroll
    for (int k4=0;k4<4;++k4){
      bf16x8 a = *(const bf16x8*)(AB + swz128(lr, k4*64 + lg*16));
      #pragma unroll
      for (int nt=0;nt<8;++nt){
        bf16x8 b = *(const bf16x8*)(wib + (long)(f0w+nt*16+lr)*128 + k4*32 + lg*8);
        acc[nt] = MFMA(a, b, acc[nt]);
      }
    }
    #pragma unroll
    for (int nt=0;nt<8;++nt)
      #pragma unroll
      for (int r=0;r<4;++r){
        int e2 = lg*4 + r;
        int f = f0w + nt*16 + lr;
        float va = acc[nt][r];
        *(__bf16*)(IB + swz512(e2, f*2)) = (__bf16)fmaxf(va, 0.f);
      }
  }
  __syncthreads();

  {
    const int o0 = w*32;
    f32x4 z = {0.f,0.f,0.f,0.f};
    f32x4 acc[2] = {z,z};
    #pragma unroll
    for (int k16=0;k16<16;++k16){
      bf16x8 a = *(const bf16x8*)(IB + swz512(lr, k16*64 + lg*16));
      #pragma unroll
      for (int nt=0;nt<2;++nt){
        bf16x8 b = *(const bf16x8*)(wob + (long)(o0+nt*16+lr)*512 + k16*32 + lg*8);
        acc[nt] = MFMA(a, b, acc[nt]);
      }
    }
    #pragma unroll
    for (int nt=0;nt<2;++nt)
      #pragma unroll
      for (int r=0;r<4;++r)
        XO[lg*4+r][o0+nt*16+lr] = acc[nt][r];
  }
  __syncthreads();

  float xn[8];
  {
    #pragma unroll
    for (int i=0;i<8;++i) xn[i] = x1[i] + XO[e][s*8+i];
    float* xp = x + (long)(n0+e)*DD + s*8;
    *(float4*)xp = *(float4*)&xn[0];
    *(float4*)(xp+4) = *(float4*)&xn[4];
    bf16x8 hb;
    #pragma unroll
    for (int i=0;i<8;++i) hb[i] = (__bf16)xn[i];
    *(bf16x8*)(xb + (long)(n0+e)*DD + s*8) = hb;
  }

  if constexpr (FUSE_LNQ){
    // re-zero agg/denom for the next layer's k_edge (own rows only; read above is done)
    {
      float4 z4 = {0.f,0.f,0.f,0.f};
      float* ap = (float*)agg + (long)n0*DD + t*8;
      *(float4*)ap = z4; *(float4*)(ap+4) = z4;
      if (t < NT*HH) ((float*)denom)[n0*HH + t] = 0.f;
    }
    // next-layer LN on xn (still in registers)
    {
      float sm = 0.f;
      #pragma unroll
      for (int i=0;i<8;++i) sm += xn[i];
      sm += __shfl_xor(sm,1); sm += __shfl_xor(sm,2);
      sm += __shfl_xor(sm,4); sm += __shfl_xor(sm,8);
      float mu = sm*(1.f/DD);
      float sq = 0.f;
      #pragma unroll
      for (int i=0;i<8;++i){ float d = xn[i]-mu; sq += d*d; }
      sq += __shfl_xor(sq,1); sq += __shfl_xor(sq,2);
      sq += __shfl_xor(sq,4); sq += __shfl_xor(sq,8);
      float rstd = rsqrtf(sq*(1.f/DD) + EPS);
      float4 w0 = *(const float4*)(nlnw + s*8), w1 = *(const float4*)(nlnw + s*8 + 4);
      float4 b0 = *(const float4*)(nlnb + s*8), b1 = *(const float4*)(nlnb + s*8 + 4);
      float wv[8] = {w0.x,w0.y,w0.z,w0.w,w1.x,w1.y,w1.z,w1.w};
      float bv[8] = {b0.x,b0.y,b0.z,b0.w,b1.x,b1.y,b1.z,b1.w};
      bf16x8 hb, hr;
      #pragma unroll
      for (int i=0;i<8;++i){
        hb[i] = (__bf16)((xn[i]-mu)*rstd*wv[i] + bv[i]);
        hr[i] = (__bf16)xn[i];
      }
      *(bf16x8*)(AB + swz128(e, s*16)) = hb;             // AB := HB (dead after wi GEMM)
      *(bf16x8*)(IB + swz128(e, s*16)) = hr;             // IB[0:4K] := HR (dead after wo GEMM)
    }
    __syncthreads();
    // q projection (K=128) from AB
    {
      const int o0 = w*32;
      f32x4 z = {0.f,0.f,0.f,0.f};
      f32x4 acc[2] = {z,z};
      #pragma unroll
      for (int k4=0;k4<4;++k4){
        bf16x8 a = *(const bf16x8*)(AB + swz128(lr, k4*64 + lg*16));
        #pragma unroll
        for (int nt=0;nt<2;++nt){
          bf16x8 b = *(const bf16x8*)(nqwb + (long)(o0+nt*16+lr)*128 + k4*32 + lg*8);
          acc[nt] = MFMA(a, b, acc[nt]);
        }
      }
      #pragma unroll
      for (int nt=0;nt<2;++nt)
        #pragma unroll
        for (int r=0;r<4;++r)
          q[(long)(n0 + lg*4 + r)*DD + o0 + nt*16 + lr] = acc[nt][r];
    }
    // XA (512 out, K=128) from IB(HR)
    {
      const int f0w = w*128;
      f32x4 z = {0.f,0.f,0.f,0.f};
      f32x4 acc[8] = {z,z,z,z,z,z,z,z};
      #pragma unroll
      for (int k4=0;k4<4;++k4){
        bf16x8 a = *(const bf16x8*)(IB + swz128(lr, k4*64 + lg*16));
        #pragma unroll
        for (int nt=0;nt<8;++nt){
          bf16x8 b = *(const bf16x8*)(na1b + (long)(f0w+nt*16+lr)*128 + k4*32 + lg*8);
          acc[nt] = MFMA(a, b, acc[nt]);
        }
      }
      #pragma unroll
      for (int nt=0;nt<8;++nt)
        #pragma unroll
        for (int r=0;r<4;++r){
          __hip_bfloat16 h = __float2bfloat16(acc[nt][r]);
          XAb[(long)(n0+lg*4+r)*FFF + f0w+nt*16+lr] = *(ushort*)&h;
        }
    }
  }
}

extern "C" void kernel_launch(void* const* d_in, const int* in_sizes, int n_in,
                              void* d_out, int out_size, void* d_ws, size_t ws_size,
                              hipStream_t stream) {
  const int* node_ids   = (const int*)d_in[0];
  const int* edge_index = (const int*)d_in[1];
  const int* edge_ids   = (const int*)d_in[2];
  const float* node_emb = (const float*)d_in[3];
  const float* edge_emb = (const float*)d_in[4];
  const float* ln_w   = (const float*)d_in[5];
  const float* ln_b   = (const float*)d_in[6];
  const float* q_w    = (const float*)d_in[7];
  const float* relA_w = (const float*)d_in[8];
  const float* relA_b = (const float*)d_in[9];
  const float* relB_w = (const float*)d_in[10];
  const float* relB_b = (const float*)d_in[11];
  const float* relG_w = (const float*)d_in[12];
  const float* relG_b = (const float*)d_in[13];
  const float* k_w    = (const float*)d_in[14];
  const float* v_w    = (const float*)d_in[15];
  const float* o_w    = (const float*)d_in[16];
  const float* ff_ln_w= (const float*)d_in[17];
  const float* ff_ln_b= (const float*)d_in[18];
  const float* wi_w   = (const float*)d_in[19];
  const float* wo_w   = (const float*)d_in[20];
  const int* src = edge_index;        // edge_index[0] = j (kv side)
  const int* dst = edge_index + EE;   // edge_index[1] = i (query side)

  float* ws = (float*)d_ws;
  float* x   = ws;  ws += (long)NN*DD;
  float* q   = ws;  ws += (long)NN*DD;
  float* denom = ws; ws += NN*HH;
  float* agg   = ws; ws += (long)NN*DD;
  float* EKf   = ws; ws += (long)LL*RELV*DD;
  int* hist   = (int*)ws; ws += NN;
  int* perm   = (int*)ws; ws += EE;
  ushort* xb  = (ushort*)ws; ws += (long)NN*DD/2;
  ushort* XAb = (ushort*)ws; ws += (long)NN*FFF/2;
  ushort* EAb = (ushort*)ws; ws += (long)LL*RELV*FFF/2;
  ushort* A1b = (ushort*)ws; ws += (long)LL*FFF*DD/2;
  ushort* Gwb = (ushort*)ws; ws += (long)LL*DD*FFF/2;
  ushort* Bwb = (ushort*)ws; ws += (long)LL*DD*FFF/2;
  ushort* Kwb = (ushort*)ws; ws += (long)LL*DD*DD/2;
  ushort* Vwb = (ushort*)ws; ws += (long)LL*DD*DD/2;
  ushort* Qwb = (ushort*)ws; ws += (long)LL*DD*DD/2;
  ushort* Owb = (ushort*)ws; ws += (long)LL*DD*DD/2;
  ushort* Wib = (ushort*)ws; ws += (long)LL*FFF*DD/2;
  ushort* Wob = (ushort*)ws; ws += (long)LL*DD*FFF/2;

  hipMemsetAsync(hist, 0, NN*sizeof(int), stream);
  k_gx<<<NN/2, 256, 0, stream>>>(node_ids, node_emb, x, xb, dst, hist);
  k_scan<<<1, 256, 0, stream>>>(hist, hist);   // in-place: hist becomes cursor
  k_scatter<<<(EE+255)/256, 256, 0, stream>>>(dst, hist, perm);
  for (int l=0; l<LL; ++l){
    k_prep<<<256, 256, 0, stream>>>(
        relG_w + (long)l*DD*FFF, relB_w + (long)l*DD*FFF,
        k_w + (long)l*DD*256,    v_w + (long)l*DD*DD,
        relA_w + (long)l*FFF*256,
        Gwb + (long)l*DD*FFF, Bwb + (long)l*DD*FFF,
        Kwb + (long)l*DD*DD,  Vwb + (long)l*DD*DD, A1b + (long)l*FFF*DD);
    k_ea<<<RELV, 256, 0, stream>>>(edge_emb, relA_w + (long)l*FFF*256, relA_b + (long)l*FFF,
                                   k_w + (long)l*DD*256, EAb + (long)l*RELV*FFF, EKf + (long)l*RELV*DD);
  }
  k_f2b4<<<512, 256, 0, stream>>>(q_w, o_w, wi_w, wo_w, Qwb, Owb, Wib, Wob);

  // layer 0 front-end
  k_lnq_xa<<<NN/NT, 256, 0, stream>>>(x, ln_w, ln_b, Qwb, A1b, q, XAb, agg, denom);
  for (int l=0; l<LL; ++l){
    k_edge<<<EE/BM, 256, 0, stream>>>(xb, XAb, EAb + (long)l*RELV*FFF, EKf + (long)l*RELV*DD,
        q, src, dst, edge_ids, perm,
        Gwb + (long)l*DD*FFF,  relG_b + (long)l*DD,
        Bwb + (long)l*DD*FFF,  relB_b + (long)l*DD,
        Kwb + (long)l*DD*DD,   Vwb + (long)l*DD*DD,
        agg, denom);
    if (l < LL-1){
      k_node<true><<<NN/NT, 256, 0, stream>>>(agg, denom, Owb + (long)l*DD*DD,
          ff_ln_w + l*DD, ff_ln_b + l*DD,
          Wib + (long)l*FFF*DD, Wob + (long)l*DD*FFF, x, xb,
          ln_w + (l+1)*DD, ln_b + (l+1)*DD,
          Qwb + (long)(l+1)*DD*DD, A1b + (long)(l+1)*FFF*DD, q, XAb);
    } else {
      k_node<false><<<NN/NT, 256, 0, stream>>>(agg, denom, Owb + (long)l*DD*DD,
          ff_ln_w + l*DD, ff_ln_b + l*DD,
          Wib + (long)l*FFF*DD, Wob + (long)l*DD*FFF, x, xb,
          nullptr, nullptr, nullptr, nullptr, nullptr, nullptr);
    }
  }
  hipMemcpyAsync(d_out, x, (size_t)NN*DD*sizeof(float), hipMemcpyDeviceToDevice, stream);
}

// Round 13
// 420.979 us; speedup vs baseline: 1.1869x; 1.0121x over previous
//
#include <hip/hip_runtime.h>
#include <hip/hip_bf16.h>

#define NN 10000
#define EE 160000
#define DD 128
#define HH 4
#define CC 32
#define FFF 512
#define LL 2
#define RELV 100
#define EPS 1e-6f
#define GATE_BIAS 3.0f
#define BM 32
#define NT 16

typedef __bf16 bf16x8 __attribute__((ext_vector_type(8)));
typedef float f32x4 __attribute__((ext_vector_type(4)));
typedef float f32x16 __attribute__((ext_vector_type(16)));

#define MFMA(a,b,c)   __builtin_amdgcn_mfma_f32_16x16x32_bf16((a),(b),(c),0,0,0)
#define MFMA32(a,b,c) __builtin_amdgcn_mfma_f32_32x32x16_bf16((a),(b),(c),0,0,0)

__device__ __forceinline__ int swzK(int e, int b){ return e*256 + (b ^ ((e&7)<<4)); }   // [R][128] bf16
__device__ __forceinline__ int swzI(int e, int b){ return e*512 + (b ^ ((e&7)<<4)); }   // [32][256] bf16
__device__ __forceinline__ int swz128(int e, int b){ return e*256 + (b ^ ((e&7)<<4)); } // [16][128] bf16
__device__ __forceinline__ int swz512(int e, int b){ return e*1024 + (b ^ ((e&7)<<4)); }// [16][512] bf16

// 256-thr blocks (2 nodes each) + edge-histogram fused in (hist pre-zeroed via memset)
__global__ __launch_bounds__(256) void k_gx(
    const int* __restrict__ node_ids, const float* __restrict__ node_emb,
    float* __restrict__ x, ushort* __restrict__ xb,
    const int* __restrict__ dst, int* __restrict__ hist){
  int b = blockIdx.x, t = threadIdx.x;
  int n = b*2 + (t>>7);
  int c = t & 127;
  float v = node_emb[(long)node_ids[n]*DD + c];
  x[(long)n*DD + c] = v;
  __hip_bfloat16 h = __float2bfloat16(v);
  xb[(long)n*DD + c] = *(ushort*)&h;
  if (t < 32){
    int e = b*32 + t;
    atomicAdd(&hist[dst[e]], 1);
  }
}

// W[?][instride] fp32 -> MFMA32 fragment order bf16 (device helper)
__device__ __forceinline__ void wprep_one(
    const float* __restrict__ in, ushort* __restrict__ out, int tid, int IN, int instride){
  int lane = tid & 63;
  int grp  = tid >> 6;
  int nkb  = IN >> 4;
  int kb   = grp % nkb;
  int cb   = grp / nkb;
  int col  = cb*32 + (lane & 31);
  int k0   = kb*16 + (lane >> 5)*8;
  const float* p = in + (long)col*instride + k0;
  bf16x8 h;
  #pragma unroll
  for (int j=0;j<8;++j) h[j] = (__bf16)p[j];
  *(bf16x8*)(out + (long)tid*8) = h;
}

// v14: ALL weight prep in ONE launch (both layers' wprep + A1 subcast + the 4 plain casts).
// grid 512 x 256 = 131072 threads. layer = blockIdx>>8, tidl in [0,65536).
__global__ __launch_bounds__(256) void k_prep2(
    const float* __restrict__ relG_w, const float* __restrict__ relB_w,
    const float* __restrict__ k_w, const float* __restrict__ v_w,
    const float* __restrict__ relA_w,
    const float* __restrict__ q_w, const float* __restrict__ o_w,
    const float* __restrict__ wi_w, const float* __restrict__ wo_w,
    ushort* __restrict__ Gwb, ushort* __restrict__ Bwb,
    ushort* __restrict__ Kwb, ushort* __restrict__ Vwb, ushort* __restrict__ A1b,
    ushort* __restrict__ Qwb, ushort* __restrict__ Owb,
    ushort* __restrict__ Wib, ushort* __restrict__ Wob){
  const int bid = blockIdx.x;
  const int l   = bid >> 8;
  const int tidl = (bid & 255)*256 + threadIdx.x;
  const long gid = (long)bid*256 + threadIdx.x;
  if (tidl < DD*FFF/8){
    wprep_one(relG_w + (long)l*DD*FFF, Gwb + (long)l*DD*FFF, tidl, FFF, FFF);
    wprep_one(relB_w + (long)l*DD*FFF, Bwb + (long)l*DD*FFF, tidl, FFF, FFF);
  }
  if (tidl < DD*DD/8){
    wprep_one(k_w + (long)l*DD*256, Kwb + (long)l*DD*DD, tidl, DD, 256);
    wprep_one(v_w + (long)l*DD*DD,  Vwb + (long)l*DD*DD, tidl, DD, DD);
  }
  {
    int o = tidl / DD, i = tidl % DD;
    __hip_bfloat16 h = __float2bfloat16(relA_w[(long)l*FFF*256 + (long)o*256 + i]);
    A1b[(long)l*FFF*DD + tidl] = *(ushort*)&h;
  }
  if (gid < (long)LL*DD*DD){
    __hip_bfloat16 h1 = __float2bfloat16(q_w[gid]); Qwb[gid] = *(ushort*)&h1;
    __hip_bfloat16 h2 = __float2bfloat16(o_w[gid]); Owb[gid] = *(ushort*)&h2;
  }
  {
    __hip_bfloat16 h3 = __float2bfloat16(wi_w[gid]); Wib[gid] = *(ushort*)&h3;
    __hip_bfloat16 h4 = __float2bfloat16(wo_w[gid]); Wob[gid] = *(ushort*)&h4;
  }
}

// v14: both layers' per-relation precompute in one launch (grid 2*RELV).
__global__ __launch_bounds__(256) void k_ea2(
    const float* __restrict__ edge_emb, const float* __restrict__ relA_w,
    const float* __restrict__ relA_b, const float* __restrict__ k_w,
    ushort* __restrict__ EA2b, float* __restrict__ EKf){
  int l = blockIdx.x / RELV, rel = blockIdx.x % RELV, t = threadIdx.x;
  const float* Aw = relA_w + (long)l*FFF*256;
  const float* Ab = relA_b + (long)l*FFF;
  const float* Kw = k_w + (long)l*DD*256;
  ushort* EAo = EA2b + (long)l*RELV*FFF;
  float* EKo  = EKf + (long)l*RELV*DD;
  __shared__ float emb[128];
  if (t < 128) emb[t] = edge_emb[(long)rel*DD + t];
  __syncthreads();
  for (int f=t; f<FFF; f+=256){
    const float* wr = Aw + (long)f*256 + 128;
    float s = Ab[f];
    for (int i=0;i<128;++i) s += emb[i]*wr[i];
    __hip_bfloat16 h = __float2bfloat16(s);
    EAo[(long)rel*FFF + f] = *(ushort*)&h;
  }
  if (t < 128){
    const float* wr = Kw + (long)t*256 + 128;
    float s = 0.f;
    for (int i=0;i<128;++i) s += emb[i]*wr[i];
    EKo[(long)rel*DD + t] = s;
  }
}

// exclusive prefix of hist[NN] -> cursor[NN]; single block, 256 threads
__global__ __launch_bounds__(256) void k_scan(const int* __restrict__ hist, int* __restrict__ cursor){
  __shared__ int tsum[256];
  const int t = threadIdx.x;
  const int PER = (NN + 255) / 256;   // 40
  const int base = t*PER;
  int s = 0;
  for (int i=0;i<PER;++i){ int idx = base+i; if (idx < NN) s += hist[idx]; }
  tsum[t] = s;
  __syncthreads();
  if (t == 0){
    int run = 0;
    for (int i=0;i<256;++i){ int v = tsum[i]; tsum[i] = run; run += v; }
  }
  __syncthreads();
  int run = tsum[t];
  for (int i=0;i<PER;++i){
    int idx = base+i;
    if (idx < NN){ int v = hist[idx]; cursor[idx] = run; run += v; }
  }
}
__global__ __launch_bounds__(256) void k_scatter(const int* __restrict__ dst,
    int* __restrict__ cursor, int* __restrict__ perm){
  int e = blockIdx.x*256 + threadIdx.x;
  if (e < EE){
    int p = atomicAdd(&cursor[dst[e]], 1);
    perm[p] = e;
  }
}

// fused LN+q-proj AND XA = x@Aw1^T; also zeroes agg/denom. (layer 0 only; later layers fused in k_node)
__global__ __launch_bounds__(256) void k_lnq_xa(
    const float* __restrict__ x, const float* __restrict__ lnw, const float* __restrict__ lnb,
    const ushort* __restrict__ qwb, const ushort* __restrict__ a1b,
    float* __restrict__ q, ushort* __restrict__ XAb,
    float* __restrict__ agg, float* __restrict__ denom){
  __shared__ __align__(16) unsigned char HB[NT*256];    // LN'd x (bf16)
  __shared__ __align__(16) unsigned char HR[NT*256];    // raw x (bf16)
  const int n0 = blockIdx.x*NT;
  const int t = threadIdx.x;
  const int e = t>>4, s = t&15;
  const int w = t>>6, l = t&63, lr = l&15, lg = l>>4;
  {
    float4 z4 = {0.f,0.f,0.f,0.f};
    float* ap = agg + (long)n0*DD + t*8;
    *(float4*)ap = z4; *(float4*)(ap+4) = z4;
    if (t < NT*HH) denom[n0*HH + t] = 0.f;
  }
  {
    const float* xp = x + (long)(n0+e)*DD + s*8;
    float xv[8];
    *(float4*)&xv[0] = *(const float4*)xp;
    *(float4*)&xv[4] = *(const float4*)(xp+4);
    float sm = 0.f;
    #pragma unroll
    for (int i=0;i<8;++i) sm += xv[i];
    sm += __shfl_xor(sm,1); sm += __shfl_xor(sm,2);
    sm += __shfl_xor(sm,4); sm += __shfl_xor(sm,8);
    float mu = sm*(1.f/DD);
    float sq = 0.f;
    #pragma unroll
    for (int i=0;i<8;++i){ float d = xv[i]-mu; sq += d*d; }
    sq += __shfl_xor(sq,1); sq += __shfl_xor(sq,2);
    sq += __shfl_xor(sq,4); sq += __shfl_xor(sq,8);
    float rstd = rsqrtf(sq*(1.f/DD) + EPS);
    float4 w0 = *(const float4*)(lnw + s*8), w1 = *(const float4*)(lnw + s*8 + 4);
    float4 b0 = *(const float4*)(lnb + s*8), b1 = *(const float4*)(lnb + s*8 + 4);
    float wv[8] = {w0.x,w0.y,w0.z,w0.w,w1.x,w1.y,w1.z,w1.w};
    float bv[8] = {b0.x,b0.y,b0.z,b0.w,b1.x,b1.y,b1.z,b1.w};
    bf16x8 hb, hr;
    #pragma unroll
    for (int i=0;i<8;++i){
      hb[i] = (__bf16)((xv[i]-mu)*rstd*wv[i] + bv[i]);
      hr[i] = (__bf16)xv[i];
    }
    *(bf16x8*)(HB + swz128(e, s*16)) = hb;
    *(bf16x8*)(HR + swz128(e, s*16)) = hr;
  }
  __syncthreads();
  // q projection (K=128) from HB
  {
    const int o0 = w*32;
    f32x4 z = {0.f,0.f,0.f,0.f};
    f32x4 acc[2] = {z,z};
    #pragma unroll
    for (int k4=0;k4<4;++k4){
      bf16x8 a = *(const bf16x8*)(HB + swz128(lr, k4*64 + lg*16));
      #pragma unroll
      for (int nt=0;nt<2;++nt){
        bf16x8 b = *(const bf16x8*)(qwb + (long)(o0+nt*16+lr)*128 + k4*32 + lg*8);
        acc[nt] = MFMA(a, b, acc[nt]);
      }
    }
    #pragma unroll
    for (int nt=0;nt<2;++nt)
      #pragma unroll
      for (int r=0;r<4;++r)
        q[(long)(n0 + lg*4 + r)*DD + o0 + nt*16 + lr] = acc[nt][r];
  }
  // XA (512 out, K=128) from HR
  {
    const int f0w = w*128;
    f32x4 z = {0.f,0.f,0.f,0.f};
    f32x4 acc[8] = {z,z,z,z,z,z,z,z};
    #pragma unroll
    for (int k4=0;k4<4;++k4){
      bf16x8 a = *(const bf16x8*)(HR + swz128(lr, k4*64 + lg*16));
      #pragma unroll
      for (int nt=0;nt<8;++nt){
        bf16x8 b = *(const bf16x8*)(a1b + (long)(f0w+nt*16+lr)*128 + k4*32 + lg*8);
        acc[nt] = MFMA(a, b, acc[nt]);
      }
    }
    #pragma unroll
    for (int nt=0;nt<8;++nt)
      #pragma unroll
      for (int r=0;r<4;++r){
        __hip_bfloat16 h = __float2bfloat16(acc[nt][r]);
        XAb[(long)(n0+lg*4+r)*FFF + f0w+nt*16+lr] = *(ushort*)&h;
      }
  }
}

// --- fused edge kernel (dst-sorted) ---
// v14: 256-col chunks (2 instead of 4; single INTB [32][256] bf16). Chunk barriers 4 -> 3,
//     gather batches double (8 in flight), chunk-1 gather hides under 64 MFMA.
//     LDS ~24.7KB unchanged. Rest identical to v13 (BM=32, 256 thr, in-reg scatter tail).
__global__ __launch_bounds__(256,4) void k_edge(
    const ushort* __restrict__ xb, const ushort* __restrict__ XAb,
    const ushort* __restrict__ EAb, const float* __restrict__ EKf,
    const float* __restrict__ q,
    const int* __restrict__ src, const int* __restrict__ dst, const int* __restrict__ eids,
    const int* __restrict__ perm,
    const ushort* __restrict__ Gwb, const float* __restrict__ Gb,
    const ushort* __restrict__ Bwb, const float* __restrict__ Bb,
    const ushort* __restrict__ Kwb, const ushort* __restrict__ Vwb,
    float* __restrict__ agg, float* __restrict__ denom)
{
  __shared__ __align__(16) unsigned char KVB[BM*256];   // 8KB kv2 bf16 [32][128] swz
  __shared__ __align__(16) unsigned char INTB[BM*512];  // 16KB celu chunk [32][256] swz
  __shared__ int srcl[BM], dstl[BM], eidl[BM];

  // exact XCD swizzle: nwg = 5000, divisible by 8
  int nb;
  {
    const int cpx = (EE/BM) >> 3;     // 625
    nb = (blockIdx.x & 7)*cpx + (blockIdx.x >> 3);
  }
  const int e0 = nb * BM;
  const int t  = threadIdx.x;
  const int w  = t >> 6;
  const int l  = t & 63;
  const int c32 = l & 31;
  const int hi  = l >> 5;
  const int C = w;               // head / col-quarter (4 waves)
  const int oc = C*32 + c32;

  if (t < BM){
    int pe = perm[e0+t];
    srcl[t] = src[pe]; dstl[t] = dst[pe]; eidl[t] = eids[pe];
  }
  __syncthreads();

  // stage kv_j = xb[src] into KVB (32 edges x 16 uint4 = 512 over 256 thr)
  {
    const uint4* xbu = (const uint4*)xb;
    #pragma unroll
    for (int it=0; it<2; ++it){
      int g = it*256 + t;
      int e = g >> 4, qq = g & 15;
      *(uint4*)(KVB + swzK(e, qq*16)) = xbu[(long)srcl[e]*16 + qq];
    }
  }

  f32x16 gbG, gbB;
  {
    float bg = Gb[oc] + GATE_BIAS;
    float bb = Bb[oc];
    #pragma unroll
    for (int i=0;i<16;++i){ gbG[i] = bg; gbB[i] = bb; }
  }

  // prologue: issue chunk-0 gather (32 edges x 256 cols = 1024 bf16x8 over 256 thr = 4/thr)
  bf16x8 xa8[4], ea8[4];
  #pragma unroll
  for (int it=0; it<4; ++it){
    int g = it*256 + t;
    int e = g >> 5, c8 = g & 31;
    xa8[it] = *(const bf16x8*)(XAb + (long)srcl[e]*FFF + c8*8);
    ea8[it] = *(const bf16x8*)(EAb + (long)eidl[e]*FFF + c8*8);
  }

  // 2 chunks of 256 FF-cols; single INTB buffer, 3 chunk barriers total.
  #pragma unroll
  for (int ch=0; ch<2; ++ch){
    // celu + write
    #pragma unroll
    for (int it=0; it<4; ++it){
      bf16x8 o;
      #pragma unroll
      for (int j=0;j<8;++j){
        float s = (float)xa8[it][j] + (float)ea8[it][j];
        o[j] = (__bf16)((s > 0.f) ? s : (__expf(s) - 1.f));
      }
      int g = it*256 + t;
      int e = g >> 5, c8 = g & 31;
      *(bf16x8*)(INTB + swzI(e, c8*16)) = o;
    }
    __syncthreads();   // INTB visible (for ch=1: GEMM0 reads finished at the ch=0 tail barrier)
    if (ch == 0){
      // issue chunk-1 gather: flies under GEMM0 (64 MFMA)
      #pragma unroll
      for (int it=0; it<4; ++it){
        int g = it*256 + t;
        int e = g >> 5, c8 = g & 31;
        xa8[it] = *(const bf16x8*)(XAb + (long)srcl[e]*FFF + 256 + c8*8);
        ea8[it] = *(const bf16x8*)(EAb + (long)eidl[e]*FFF + 256 + c8*8);
      }
    }
    // gate GEMM: rows 0..31, cols 32C.., K=256
    {
      const ushort* Wg = Gwb + ((long)(C*32 + ch*16)*64 + l)*8;
      #pragma unroll
      for (int h2=0; h2<2; ++h2){
        bf16x8 wf[8];
        #pragma unroll
        for (int i=0;i<8;++i) wf[i] = *(const bf16x8*)(Wg + (long)(h2*8+i)*512);
        #pragma unroll
        for (int i=0;i<8;++i){
          bf16x8 a = *(const bf16x8*)(INTB + swzI(c32, (h2*8+i)*32 + hi*16));
          gbG = MFMA32(a, wf[i], gbG);
        }
      }
    }
    // badd GEMM: K=256
    {
      const ushort* Wb = Bwb + ((long)(C*32 + ch*16)*64 + l)*8;
      #pragma unroll
      for (int h2=0; h2<2; ++h2){
        bf16x8 wf[8];
        #pragma unroll
        for (int i=0;i<8;++i) wf[i] = *(const bf16x8*)(Wb + (long)(h2*8+i)*512);
        #pragma unroll
        for (int i=0;i<8;++i){
          bf16x8 a = *(const bf16x8*)(INTB + swzI(c32, (h2*8+i)*32 + hi*16));
          gbB = MFMA32(a, wf[i], gbB);
        }
      }
    }
    if (ch == 0) __syncthreads();   // GEMM0 reads done before chunk-1 overwrites INTB
  }

  // in-register blend: kv2 = badd + sigmoid(gate)*(kv - badd), write back to KVB
  #pragma unroll
  for (int r=0;r<16;++r){
    int row = (r&3) + 8*(r>>2) + 4*hi;
    float g  = 1.f/(1.f + __expf(-gbG[r]));
    float kv = (float)*(const __bf16*)(KVB + swzK(row, oc*2));
    float k2 = gbB[r] + g*(kv - gbB[r]);
    *(__bf16*)(KVB + swzK(row, oc*2)) = (__bf16)k2;
  }
  __syncthreads();   // kv2 ready in KVB

  // K and V GEMMs: wave C computes K[0..32][32C..] and V[0..32][32C..], K=128
  f32x16 ka, va;
  #pragma unroll
  for (int i=0;i<16;++i){ ka[i] = 0.f; va[i] = 0.f; }
  {
    const ushort* Wk = Kwb + ((long)(C*8)*64 + l)*8;
    bf16x8 wf[8];
    #pragma unroll
    for (int i=0;i<8;++i) wf[i] = *(const bf16x8*)(Wk + (long)i*512);
    #pragma unroll
    for (int i=0;i<8;++i){
      bf16x8 a = *(const bf16x8*)(KVB + swzK(c32, i*32 + hi*16));
      ka = MFMA32(a, wf[i], ka);
    }
  }
  {
    const ushort* Wv = Vwb + ((long)(C*8)*64 + l)*8;
    bf16x8 wf[8];
    #pragma unroll
    for (int i=0;i<8;++i) wf[i] = *(const bf16x8*)(Wv + (long)i*512);
    #pragma unroll
    for (int i=0;i<8;++i){
      bf16x8 a = *(const bf16x8*)(KVB + swzK(c32, i*32 + hi*16));
      va = MFMA32(a, wf[i], va);
    }
  }
  // no barrier needed: nothing writes LDS after this point.

  // fused score + exp + weighted in-register segment scatter.
  // Thread owns rows {8q+4hi+j : q=0..3, j=0..3}: 4 runs of 4 CONSECUTIVE sorted rows.
  #pragma unroll
  for (int qq=0; qq<4; ++qq){
    const int base = 8*qq + 4*hi;
    float ex[4];
    #pragma unroll
    for (int j=0;j<4;++j){
      int r = qq*4 + j;
      int gr = base + j;
      float kv = ka[r] + EKf[(long)eidl[gr]*DD + oc];
      float p = kv * q[(long)dstl[gr]*DD + oc];
      p += __shfl_xor(p, 1); p += __shfl_xor(p, 2);
      p += __shfl_xor(p, 4); p += __shfl_xor(p, 8);
      p += __shfl_xor(p, 16);
      ex[j] = __expf(p);          // all 32 lanes of the half-wave hold the row's score
    }
    // agg scatter: merge consecutive rows sharing dst (branch is half-wave-uniform)
    {
      float acc = va[qq*4]*ex[0];
      int cur = dstl[base];
      #pragma unroll
      for (int j=1;j<4;++j){
        int dn = dstl[base+j];
        if (dn != cur){
          atomicAdd(&agg[(long)cur*DD + oc], acc);
          acc = 0.f; cur = dn;
        }
        acc += va[qq*4+j]*ex[j];
      }
      atomicAdd(&agg[(long)cur*DD + oc], acc);
    }
    // denom scatter: one lane per half-wave
    if (c32 == 0){
      float da = ex[0];
      int cur = dstl[base];
      #pragma unroll
      for (int j=1;j<4;++j){
        int dn = dstl[base+j];
        if (dn != cur){
          atomicAdd(&denom[cur*HH + C], da);
          da = 0.f; cur = dn;
        }
        da += ex[j];
      }
      atomicAdd(&denom[cur*HH + C], da);
    }
  }
}

// fused: x1 = x + (agg/denom)@o_w^T;  x = x1 + relu(LN(x1)@wi^T)@wo^T;  emits x, xb.
// FUSE_LNQ tail runs the NEXT layer's LN + q-proj + XA-proj on xn in registers.
template<bool FUSE_LNQ>
__global__ __launch_bounds__(256) void k_node(
    const float* __restrict__ agg, const float* __restrict__ denom,
    const ushort* __restrict__ owb,
    const float* __restrict__ lnw, const float* __restrict__ lnb,
    const ushort* __restrict__ wib, const ushort* __restrict__ wob,
    float* __restrict__ x, ushort* __restrict__ xb,
    const float* __restrict__ nlnw, const float* __restrict__ nlnb,
    const ushort* __restrict__ nqwb, const ushort* __restrict__ na1b,
    float* __restrict__ q, ushort* __restrict__ XAb){
  __shared__ __align__(16) unsigned char AB[NT*256];
  __shared__ __align__(16) unsigned char IB[NT*1024];
  __shared__ __align__(16) float XO[NT][132];
  const int n0 = blockIdx.x*NT;
  const int t = threadIdx.x;
  const int e = t>>4, s = t&15;
  const int w = t>>6, l = t&63, lr = l&15, lg = l>>4;

  {
    const float* ap = agg + (long)(n0+e)*DD + s*8;
    float av[8];
    *(float4*)&av[0] = *(const float4*)ap;
    *(float4*)&av[4] = *(const float4*)(ap+4);
    float dinv = 1.f / denom[(n0+e)*HH + (s>>2)];
    bf16x8 hb;
    #pragma unroll
    for (int i=0;i<8;++i) hb[i] = (__bf16)(av[i]*dinv);
    *(bf16x8*)(AB + swz128(e, s*16)) = hb;
  }
  __syncthreads();

  {
    const int o0 = w*32;
    f32x4 z = {0.f,0.f,0.f,0.f};
    f32x4 acc[2] = {z,z};
    #pragma unroll
    for (int k4=0;k4<4;++k4){
      bf16x8 a = *(const bf16x8*)(AB + swz128(lr, k4*64 + lg*16));
      #pragma unroll
      for (int nt=0;nt<2;++nt){
        bf16x8 b = *(const bf16x8*)(owb + (long)(o0+nt*16+lr)*128 + k4*32 + lg*8);
        acc[nt] = MFMA(a, b, acc[nt]);
      }
    }
    #pragma unroll
    for (int nt=0;nt<2;++nt)
      #pragma unroll
      for (int r=0;r<4;++r)
        XO[lg*4+r][o0+nt*16+lr] = acc[nt][r];
  }
  __syncthreads();

  float x1[8];
  {
    const float* xp = x + (long)(n0+e)*DD + s*8;
    float xv[8];
    *(float4*)&xv[0] = *(const float4*)xp;
    *(float4*)&xv[4] = *(const float4*)(xp+4);
    #pragma unroll
    for (int i=0;i<8;++i) x1[i] = xv[i] + XO[e][s*8+i];
    float sm = 0.f;
    #pragma unroll
    for (int i=0;i<8;++i) sm += x1[i];
    sm += __shfl_xor(sm,1); sm += __shfl_xor(sm,2);
    sm += __shfl_xor(sm,4); sm += __shfl_xor(sm,8);
    float mu = sm*(1.f/DD);
    float sq = 0.f;
    #pragma unroll
    for (int i=0;i<8;++i){ float d = x1[i]-mu; sq += d*d; }
    sq += __shfl_xor(sq,1); sq += __shfl_xor(sq,2);
    sq += __shfl_xor(sq,4); sq += __shfl_xor(sq,8);
    float rstd = rsqrtf(sq*(1.f/DD) + EPS);
    float4 w0 = *(const float4*)(lnw + s*8), w1 = *(const float4*)(lnw + s*8 + 4);
    float4 b0 = *(const float4*)(lnb + s*8), b1 = *(const float4*)(lnb + s*8 + 4);
    float wv[8] = {w0.x,w0.y,w0.z,w0.w,w1.x,w1.y,w1.z,w1.w};
    float bv[8] = {b0.x,b0.y,b0.z,b0.w,b1.x,b1.y,b1.z,b1.w};
    bf16x8 hb;
    #pragma unroll
    for (int i=0;i<8;++i) hb[i] = (__bf16)((x1[i]-mu)*rstd*wv[i] + bv[i]);
    __syncthreads();
    *(bf16x8*)(AB + swz128(e, s*16)) = hb;
  }
  __syncthreads();

  {
    const int f0w = w*128;
    f32x4 z = {0.f,0.f,0.f,0.f};
    f32x4 acc[8] = {z,z,z,z,z,z,z,z};
    #pragma unroll
    for (int k4=0;k4<4;++k4){
      bf16x8 a = *(const bf16x8*)(AB + swz128(lr, k4*64 + lg*16));
      #pragma unroll
      for (int nt=0;nt<8;++nt){
        bf16x8 b = *(const bf16x8*)(wib + (long)(f0w+nt*16+lr)*128 + k4*32 + lg*8);
        acc[nt] = MFMA(a, b, acc[nt]);
      }
    }
    #pragma unroll
    for (int nt=0;nt<8;++nt)
      #pragma unroll
      for (int r=0;r<4;++r){
        int e2 = lg*4 + r;
        int f = f0w + nt*16 + lr;
        float va = acc[nt][r];
        *(__bf16*)(IB + swz512(e2, f*2)) = (__bf16)fmaxf(va, 0.f);
      }
  }
  __syncthreads();

  {
    const int o0 = w*32;
    f32x4 z = {0.f,0.f,0.f,0.f};
    f32x4 acc[2] = {z,z};
    #pragma unroll
    for (int k16=0;k16<16;++k16){
      bf16x8 a = *(const bf16x8*)(IB + swz512(lr, k16*64 + lg*16));
      #pragma unroll
      for (int nt=0;nt<2;++nt){
        bf16x8 b = *(const bf16x8*)(wob + (long)(o0+nt*16+lr)*512 + k16*32 + lg*8);
        acc[nt] = MFMA(a, b, acc[nt]);
      }
    }
    #pragma unroll
    for (int nt=0;nt<2;++nt)
      #pragma unroll
      for (int r=0;r<4;++r)
        XO[lg*4+r][o0+nt*16+lr] = acc[nt][r];
  }
  __syncthreads();

  float xn[8];
  {
    #pragma unroll
    for (int i=0;i<8;++i) xn[i] = x1[i] + XO[e][s*8+i];
    float* xp = x + (long)(n0+e)*DD + s*8;
    *(float4*)xp = *(float4*)&xn[0];
    *(float4*)(xp+4) = *(float4*)&xn[4];
    bf16x8 hb;
    #pragma unroll
    for (int i=0;i<8;++i) hb[i] = (__bf16)xn[i];
    *(bf16x8*)(xb + (long)(n0+e)*DD + s*8) = hb;
  }

  if constexpr (FUSE_LNQ){
    // re-zero agg/denom for the next layer's k_edge (own rows only; read above is done)
    {
      float4 z4 = {0.f,0.f,0.f,0.f};
      float* ap = (float*)agg + (long)n0*DD + t*8;
      *(float4*)ap = z4; *(float4*)(ap+4) = z4;
      if (t < NT*HH) ((float*)denom)[n0*HH + t] = 0.f;
    }
    // next-layer LN on xn (still in registers)
    {
      float sm = 0.f;
      #pragma unroll
      for (int i=0;i<8;++i) sm += xn[i];
      sm += __shfl_xor(sm,1); sm += __shfl_xor(sm,2);
      sm += __shfl_xor(sm,4); sm += __shfl_xor(sm,8);
      float mu = sm*(1.f/DD);
      float sq = 0.f;
      #pragma unroll
      for (int i=0;i<8;++i){ float d = xn[i]-mu; sq += d*d; }
      sq += __shfl_xor(sq,1); sq += __shfl_xor(sq,2);
      sq += __shfl_xor(sq,4); sq += __shfl_xor(sq,8);
      float rstd = rsqrtf(sq*(1.f/DD) + EPS);
      float4 w0 = *(const float4*)(nlnw + s*8), w1 = *(const float4*)(nlnw + s*8 + 4);
      float4 b0 = *(const float4*)(nlnb + s*8), b1 = *(const float4*)(nlnb + s*8 + 4);
      float wv[8] = {w0.x,w0.y,w0.z,w0.w,w1.x,w1.y,w1.z,w1.w};
      float bv[8] = {b0.x,b0.y,b0.z,b0.w,b1.x,b1.y,b1.z,b1.w};
      bf16x8 hb, hr;
      #pragma unroll
      for (int i=0;i<8;++i){
        hb[i] = (__bf16)((xn[i]-mu)*rstd*wv[i] + bv[i]);
        hr[i] = (__bf16)xn[i];
      }
      *(bf16x8*)(AB + swz128(e, s*16)) = hb;             // AB := HB (dead after wi GEMM)
      *(bf16x8*)(IB + swz128(e, s*16)) = hr;             // IB[0:4K] := HR (dead after wo GEMM)
    }
    __syncthreads();
    // q projection (K=128) from AB
    {
      const int o0 = w*32;
      f32x4 z = {0.f,0.f,0.f,0.f};
      f32x4 acc[2] = {z,z};
      #pragma unroll
      for (int k4=0;k4<4;++k4){
        bf16x8 a = *(const bf16x8*)(AB + swz128(lr, k4*64 + lg*16));
        #pragma unroll
        for (int nt=0;nt<2;++nt){
          bf16x8 b = *(const bf16x8*)(nqwb + (long)(o0+nt*16+lr)*128 + k4*32 + lg*8);
          acc[nt] = MFMA(a, b, acc[nt]);
        }
      }
      #pragma unroll
      for (int nt=0;nt<2;++nt)
        #pragma unroll
        for (int r=0;r<4;++r)
          q[(long)(n0 + lg*4 + r)*DD + o0 + nt*16 + lr] = acc[nt][r];
    }
    // XA (512 out, K=128) from IB(HR)
    {
      const int f0w = w*128;
      f32x4 z = {0.f,0.f,0.f,0.f};
      f32x4 acc[8] = {z,z,z,z,z,z,z,z};
      #pragma unroll
      for (int k4=0;k4<4;++k4){
        bf16x8 a = *(const bf16x8*)(IB + swz128(lr, k4*64 + lg*16));
        #pragma unroll
        for (int nt=0;nt<8;++nt){
          bf16x8 b = *(const bf16x8*)(na1b + (long)(f0w+nt*16+lr)*128 + k4*32 + lg*8);
          acc[nt] = MFMA(a, b, acc[nt]);
        }
      }
      #pragma unroll
      for (int nt=0;nt<8;++nt)
        #pragma unroll
        for (int r=0;r<4;++r){
          __hip_bfloat16 h = __float2bfloat16(acc[nt][r]);
          XAb[(long)(n0+lg*4+r)*FFF + f0w+nt*16+lr] = *(ushort*)&h;
        }
    }
  }
}

extern "C" void kernel_launch(void* const* d_in, const int* in_sizes, int n_in,
                              void* d_out, int out_size, void* d_ws, size_t ws_size,
                              hipStream_t stream) {
  const int* node_ids   = (const int*)d_in[0];
  const int* edge_index = (const int*)d_in[1];
  const int* edge_ids   = (const int*)d_in[2];
  const float* node_emb = (const float*)d_in[3];
  const float* edge_emb = (const float*)d_in[4];
  const float* ln_w   = (const float*)d_in[5];
  const float* ln_b   = (const float*)d_in[6];
  const float* q_w    = (const float*)d_in[7];
  const float* relA_w = (const float*)d_in[8];
  const float* relA_b = (const float*)d_in[9];
  const float* relB_w = (const float*)d_in[10];
  const float* relB_b = (const float*)d_in[11];
  const float* relG_w = (const float*)d_in[12];
  const float* relG_b = (const float*)d_in[13];
  const float* k_w    = (const float*)d_in[14];
  const float* v_w    = (const float*)d_in[15];
  const float* o_w    = (const float*)d_in[16];
  const float* ff_ln_w= (const float*)d_in[17];
  const float* ff_ln_b= (const float*)d_in[18];
  const float* wi_w   = (const float*)d_in[19];
  const float* wo_w   = (const float*)d_in[20];
  const int* src = edge_index;        // edge_index[0] = j (kv side)
  const int* dst = edge_index + EE;   // edge_index[1] = i (query side)

  float* ws = (float*)d_ws;
  float* x   = ws;  ws += (long)NN*DD;
  float* q   = ws;  ws += (long)NN*DD;
  float* denom = ws; ws += NN*HH;
  float* agg   = ws; ws += (long)NN*DD;
  float* EKf   = ws; ws += (long)LL*RELV*DD;
  int* hist   = (int*)ws; ws += NN;
  int* perm   = (int*)ws; ws += EE;
  ushort* xb  = (ushort*)ws; ws += (long)NN*DD/2;
  ushort* XAb = (ushort*)ws; ws += (long)NN*FFF/2;
  ushort* EAb = (ushort*)ws; ws += (long)LL*RELV*FFF/2;
  ushort* A1b = (ushort*)ws; ws += (long)LL*FFF*DD/2;
  ushort* Gwb = (ushort*)ws; ws += (long)LL*DD*FFF/2;
  ushort* Bwb = (ushort*)ws; ws += (long)LL*DD*FFF/2;
  ushort* Kwb = (ushort*)ws; ws += (long)LL*DD*DD/2;
  ushort* Vwb = (ushort*)ws; ws += (long)LL*DD*DD/2;
  ushort* Qwb = (ushort*)ws; ws += (long)LL*DD*DD/2;
  ushort* Owb = (ushort*)ws; ws += (long)LL*DD*DD/2;
  ushort* Wib = (ushort*)ws; ws += (long)LL*FFF*DD/2;
  ushort* Wob = (ushort*)ws; ws += (long)LL*DD*FFF/2;

  hipMemsetAsync(hist, 0, NN*sizeof(int), stream);
  k_gx<<<NN/2, 256, 0, stream>>>(node_ids, node_emb, x, xb, dst, hist);
  k_scan<<<1, 256, 0, stream>>>(hist, hist);   // in-place: hist becomes cursor
  k_scatter<<<(EE+255)/256, 256, 0, stream>>>(dst, hist, perm);
  k_prep2<<<512, 256, 0, stream>>>(relG_w, relB_w, k_w, v_w, relA_w,
                                   q_w, o_w, wi_w, wo_w,
                                   Gwb, Bwb, Kwb, Vwb, A1b, Qwb, Owb, Wib, Wob);
  k_ea2<<<2*RELV, 256, 0, stream>>>(edge_emb, relA_w, relA_b, k_w, EAb, EKf);

  // layer 0 front-end
  k_lnq_xa<<<NN/NT, 256, 0, stream>>>(x, ln_w, ln_b, Qwb, A1b, q, XAb, agg, denom);
  for (int l=0; l<LL; ++l){
    k_edge<<<EE/BM, 256, 0, stream>>>(xb, XAb, EAb + (long)l*RELV*FFF, EKf + (long)l*RELV*DD,
        q, src, dst, edge_ids, perm,
        Gwb + (long)l*DD*FFF,  relG_b + (long)l*DD,
        Bwb + (long)l*DD*FFF,  relB_b + (long)l*DD,
        Kwb + (long)l*DD*DD,   Vwb + (long)l*DD*DD,
        agg, denom);
    if (l < LL-1){
      k_node<true><<<NN/NT, 256, 0, stream>>>(agg, denom, Owb + (long)l*DD*DD,
          ff_ln_w + l*DD, ff_ln_b + l*DD,
          Wib + (long)l*FFF*DD, Wob + (long)l*DD*FFF, x, xb,
          ln_w + (l+1)*DD, ln_b + (l+1)*DD,
          Qwb + (long)(l+1)*DD*DD, A1b + (long)(l+1)*FFF*DD, q, XAb);
    } else {
      k_node<false><<<NN/NT, 256, 0, stream>>>(agg, denom, Owb + (long)l*DD*DD,
          ff_ln_w + l*DD, ff_ln_b + l*DD,
          Wib + (long)l*FFF*DD, Wob + (long)l*DD*FFF, x, xb,
          nullptr, nullptr, nullptr, nullptr, nullptr, nullptr);
    }
  }
  hipMemcpyAsync(d_out, x, (size_t)NN*DD*sizeof(float), hipMemcpyDeviceToDevice, stream);
}

// Round 14
// 411.340 us; speedup vs baseline: 1.2147x; 1.0234x over previous
//
#include <hip/hip_runtime.h>
#include <hip/hip_bf16.h>

#define NN 10000
#define EE 160000
#define DD 128
#define HH 4
#define CC 32
#define FFF 512
#define LL 2
#define RELV 100
#define EPS 1e-6f
#define GATE_BIAS 3.0f
#define BM 32
#define NT 16

typedef __bf16 bf16x8 __attribute__((ext_vector_type(8)));
typedef float f32x4 __attribute__((ext_vector_type(4)));
typedef float f32x16 __attribute__((ext_vector_type(16)));

#define MFMA(a,b,c)   __builtin_amdgcn_mfma_f32_16x16x32_bf16((a),(b),(c),0,0,0)
#define MFMA32(a,b,c) __builtin_amdgcn_mfma_f32_32x32x16_bf16((a),(b),(c),0,0,0)

__device__ __forceinline__ int swzK(int e, int b){ return e*256 + (b ^ ((e&7)<<4)); }   // [R][128] bf16
__device__ __forceinline__ int swz128(int e, int b){ return e*256 + (b ^ ((e&7)<<4)); } // [16][128] bf16
__device__ __forceinline__ int swz512(int e, int b){ return e*1024 + (b ^ ((e&7)<<4)); }// [16][512] bf16

// 256-thr blocks (2 nodes each) + edge-histogram fused in (hist pre-zeroed via memset)
__global__ __launch_bounds__(256) void k_gx(
    const int* __restrict__ node_ids, const float* __restrict__ node_emb,
    float* __restrict__ x, ushort* __restrict__ xb,
    const int* __restrict__ dst, int* __restrict__ hist){
  int b = blockIdx.x, t = threadIdx.x;
  int n = b*2 + (t>>7);
  int c = t & 127;
  float v = node_emb[(long)node_ids[n]*DD + c];
  x[(long)n*DD + c] = v;
  __hip_bfloat16 h = __float2bfloat16(v);
  xb[(long)n*DD + c] = *(ushort*)&h;
  if (t < 32){
    int e = b*32 + t;
    atomicAdd(&hist[dst[e]], 1);
  }
}

// W[?][instride] fp32 -> MFMA32 fragment order bf16 (device helper)
__device__ __forceinline__ void wprep_one(
    const float* __restrict__ in, ushort* __restrict__ out, int tid, int IN, int instride){
  int lane = tid & 63;
  int grp  = tid >> 6;
  int nkb  = IN >> 4;
  int kb   = grp % nkb;
  int cb   = grp / nkb;
  int col  = cb*32 + (lane & 31);
  int k0   = kb*16 + (lane >> 5)*8;
  const float* p = in + (long)col*instride + k0;
  bf16x8 h;
  #pragma unroll
  for (int j=0;j<8;++j) h[j] = (__bf16)p[j];
  *(bf16x8*)(out + (long)tid*8) = h;
}

// ALL weight prep in ONE launch (both layers' wprep + A1 subcast + the 4 plain casts).
__global__ __launch_bounds__(256) void k_prep2(
    const float* __restrict__ relG_w, const float* __restrict__ relB_w,
    const float* __restrict__ k_w, const float* __restrict__ v_w,
    const float* __restrict__ relA_w,
    const float* __restrict__ q_w, const float* __restrict__ o_w,
    const float* __restrict__ wi_w, const float* __restrict__ wo_w,
    ushort* __restrict__ Gwb, ushort* __restrict__ Bwb,
    ushort* __restrict__ Kwb, ushort* __restrict__ Vwb, ushort* __restrict__ A1b,
    ushort* __restrict__ Qwb, ushort* __restrict__ Owb,
    ushort* __restrict__ Wib, ushort* __restrict__ Wob){
  const int bid = blockIdx.x;
  const int l   = bid >> 8;
  const int tidl = (bid & 255)*256 + threadIdx.x;
  const long gid = (long)bid*256 + threadIdx.x;
  if (tidl < DD*FFF/8){
    wprep_one(relG_w + (long)l*DD*FFF, Gwb + (long)l*DD*FFF, tidl, FFF, FFF);
    wprep_one(relB_w + (long)l*DD*FFF, Bwb + (long)l*DD*FFF, tidl, FFF, FFF);
  }
  if (tidl < DD*DD/8){
    wprep_one(k_w + (long)l*DD*256, Kwb + (long)l*DD*DD, tidl, DD, 256);
    wprep_one(v_w + (long)l*DD*DD,  Vwb + (long)l*DD*DD, tidl, DD, DD);
  }
  {
    int o = tidl / DD, i = tidl % DD;
    __hip_bfloat16 h = __float2bfloat16(relA_w[(long)l*FFF*256 + (long)o*256 + i]);
    A1b[(long)l*FFF*DD + tidl] = *(ushort*)&h;
  }
  if (gid < (long)LL*DD*DD){
    __hip_bfloat16 h1 = __float2bfloat16(q_w[gid]); Qwb[gid] = *(ushort*)&h1;
    __hip_bfloat16 h2 = __float2bfloat16(o_w[gid]); Owb[gid] = *(ushort*)&h2;
  }
  {
    __hip_bfloat16 h3 = __float2bfloat16(wi_w[gid]); Wib[gid] = *(ushort*)&h3;
    __hip_bfloat16 h4 = __float2bfloat16(wo_w[gid]); Wob[gid] = *(ushort*)&h4;
  }
}

// both layers' per-relation precompute in one launch (grid 2*RELV).
__global__ __launch_bounds__(256) void k_ea2(
    const float* __restrict__ edge_emb, const float* __restrict__ relA_w,
    const float* __restrict__ relA_b, const float* __restrict__ k_w,
    ushort* __restrict__ EA2b, float* __restrict__ EKf){
  int l = blockIdx.x / RELV, rel = blockIdx.x % RELV, t = threadIdx.x;
  const float* Aw = relA_w + (long)l*FFF*256;
  const float* Ab = relA_b + (long)l*FFF;
  const float* Kw = k_w + (long)l*DD*256;
  ushort* EAo = EA2b + (long)l*RELV*FFF;
  float* EKo  = EKf + (long)l*RELV*DD;
  __shared__ float emb[128];
  if (t < 128) emb[t] = edge_emb[(long)rel*DD + t];
  __syncthreads();
  for (int f=t; f<FFF; f+=256){
    const float* wr = Aw + (long)f*256 + 128;
    float s = Ab[f];
    for (int i=0;i<128;++i) s += emb[i]*wr[i];
    __hip_bfloat16 h = __float2bfloat16(s);
    EAo[(long)rel*FFF + f] = *(ushort*)&h;
  }
  if (t < 128){
    const float* wr = Kw + (long)t*256 + 128;
    float s = 0.f;
    for (int i=0;i<128;++i) s += emb[i]*wr[i];
    EKo[(long)rel*DD + t] = s;
  }
}

// exclusive prefix of hist[NN] -> cursor[NN]; single block, 256 threads
__global__ __launch_bounds__(256) void k_scan(const int* __restrict__ hist, int* __restrict__ cursor){
  __shared__ int tsum[256];
  const int t = threadIdx.x;
  const int PER = (NN + 255) / 256;   // 40
  const int base = t*PER;
  int s = 0;
  for (int i=0;i<PER;++i){ int idx = base+i; if (idx < NN) s += hist[idx]; }
  tsum[t] = s;
  __syncthreads();
  if (t == 0){
    int run = 0;
    for (int i=0;i<256;++i){ int v = tsum[i]; tsum[i] = run; run += v; }
  }
  __syncthreads();
  int run = tsum[t];
  for (int i=0;i<PER;++i){
    int idx = base+i;
    if (idx < NN){ int v = hist[idx]; cursor[idx] = run; run += v; }
  }
}
__global__ __launch_bounds__(256) void k_scatter(const int* __restrict__ dst,
    int* __restrict__ cursor, int* __restrict__ perm){
  int e = blockIdx.x*256 + threadIdx.x;
  if (e < EE){
    int p = atomicAdd(&cursor[dst[e]], 1);
    perm[p] = e;
  }
}

// fused LN+q-proj AND XA = x@Aw1^T; also zeroes agg/denom. (layer 0 only; later layers fused in k_node)
__global__ __launch_bounds__(256) void k_lnq_xa(
    const float* __restrict__ x, const float* __restrict__ lnw, const float* __restrict__ lnb,
    const ushort* __restrict__ qwb, const ushort* __restrict__ a1b,
    float* __restrict__ q, ushort* __restrict__ XAb,
    float* __restrict__ agg, float* __restrict__ denom){
  __shared__ __align__(16) unsigned char HB[NT*256];    // LN'd x (bf16)
  __shared__ __align__(16) unsigned char HR[NT*256];    // raw x (bf16)
  const int n0 = blockIdx.x*NT;
  const int t = threadIdx.x;
  const int e = t>>4, s = t&15;
  const int w = t>>6, l = t&63, lr = l&15, lg = l>>4;
  {
    float4 z4 = {0.f,0.f,0.f,0.f};
    float* ap = agg + (long)n0*DD + t*8;
    *(float4*)ap = z4; *(float4*)(ap+4) = z4;
    if (t < NT*HH) denom[n0*HH + t] = 0.f;
  }
  {
    const float* xp = x + (long)(n0+e)*DD + s*8;
    float xv[8];
    *(float4*)&xv[0] = *(const float4*)xp;
    *(float4*)&xv[4] = *(const float4*)(xp+4);
    float sm = 0.f;
    #pragma unroll
    for (int i=0;i<8;++i) sm += xv[i];
    sm += __shfl_xor(sm,1); sm += __shfl_xor(sm,2);
    sm += __shfl_xor(sm,4); sm += __shfl_xor(sm,8);
    float mu = sm*(1.f/DD);
    float sq = 0.f;
    #pragma unroll
    for (int i=0;i<8;++i){ float d = xv[i]-mu; sq += d*d; }
    sq += __shfl_xor(sq,1); sq += __shfl_xor(sq,2);
    sq += __shfl_xor(sq,4); sq += __shfl_xor(sq,8);
    float rstd = rsqrtf(sq*(1.f/DD) + EPS);
    float4 w0 = *(const float4*)(lnw + s*8), w1 = *(const float4*)(lnw + s*8 + 4);
    float4 b0 = *(const float4*)(lnb + s*8), b1 = *(const float4*)(lnb + s*8 + 4);
    float wv[8] = {w0.x,w0.y,w0.z,w0.w,w1.x,w1.y,w1.z,w1.w};
    float bv[8] = {b0.x,b0.y,b0.z,b0.w,b1.x,b1.y,b1.z,b1.w};
    bf16x8 hb, hr;
    #pragma unroll
    for (int i=0;i<8;++i){
      hb[i] = (__bf16)((xv[i]-mu)*rstd*wv[i] + bv[i]);
      hr[i] = (__bf16)xv[i];
    }
    *(bf16x8*)(HB + swz128(e, s*16)) = hb;
    *(bf16x8*)(HR + swz128(e, s*16)) = hr;
  }
  __syncthreads();
  // q projection (K=128) from HB
  {
    const int o0 = w*32;
    f32x4 z = {0.f,0.f,0.f,0.f};
    f32x4 acc[2] = {z,z};
    #pragma unroll
    for (int k4=0;k4<4;++k4){
      bf16x8 a = *(const bf16x8*)(HB + swz128(lr, k4*64 + lg*16));
      #pragma unroll
      for (int nt=0;nt<2;++nt){
        bf16x8 b = *(const bf16x8*)(qwb + (long)(o0+nt*16+lr)*128 + k4*32 + lg*8);
        acc[nt] = MFMA(a, b, acc[nt]);
      }
    }
    #pragma unroll
    for (int nt=0;nt<2;++nt)
      #pragma unroll
      for (int r=0;r<4;++r)
        q[(long)(n0 + lg*4 + r)*DD + o0 + nt*16 + lr] = acc[nt][r];
  }
  // XA (512 out, K=128) from HR
  {
    const int f0w = w*128;
    f32x4 z = {0.f,0.f,0.f,0.f};
    f32x4 acc[8] = {z,z,z,z,z,z,z,z};
    #pragma unroll
    for (int k4=0;k4<4;++k4){
      bf16x8 a = *(const bf16x8*)(HR + swz128(lr, k4*64 + lg*16));
      #pragma unroll
      for (int nt=0;nt<8;++nt){
        bf16x8 b = *(const bf16x8*)(a1b + (long)(f0w+nt*16+lr)*128 + k4*32 + lg*8);
        acc[nt] = MFMA(a, b, acc[nt]);
      }
    }
    #pragma unroll
    for (int nt=0;nt<8;++nt)
      #pragma unroll
      for (int r=0;r<4;++r){
        __hip_bfloat16 h = __float2bfloat16(acc[nt][r]);
        XAb[(long)(n0+lg*4+r)*FFF + f0w+nt*16+lr] = *(ushort*)&h;
      }
  }
}

// --- fused edge kernel (dst-sorted) ---
// v15 = v13's proven k_edge (133us): BM=32, 256 thr, 4x128-col chunks, INTB double-buffer,
// in-register blend + scatter tail, exact XCD swizzle. (v14's 256-col chunks regressed: the
// shared INTB's mid-GEMM barrier re-serialized what the dbuf avoided.)
__global__ __launch_bounds__(256,4) void k_edge(
    const ushort* __restrict__ xb, const ushort* __restrict__ XAb,
    const ushort* __restrict__ EAb, const float* __restrict__ EKf,
    const float* __restrict__ q,
    const int* __restrict__ src, const int* __restrict__ dst, const int* __restrict__ eids,
    const int* __restrict__ perm,
    const ushort* __restrict__ Gwb, const float* __restrict__ Gb,
    const ushort* __restrict__ Bwb, const float* __restrict__ Bb,
    const ushort* __restrict__ Kwb, const ushort* __restrict__ Vwb,
    float* __restrict__ agg, float* __restrict__ denom)
{
  __shared__ __align__(16) unsigned char KVB[BM*256];      // 8KB kv2 bf16 [32][128] swz
  __shared__ __align__(16) unsigned char INTB[2][BM*256];  // 16KB celu chunk dbuf
  __shared__ int srcl[BM], dstl[BM], eidl[BM];

  // exact XCD swizzle: nwg = 5000, divisible by 8
  int nb;
  {
    const int cpx = (EE/BM) >> 3;     // 625
    nb = (blockIdx.x & 7)*cpx + (blockIdx.x >> 3);
  }
  const int e0 = nb * BM;
  const int t  = threadIdx.x;
  const int w  = t >> 6;
  const int l  = t & 63;
  const int c32 = l & 31;
  const int hi  = l >> 5;
  const int C = w;               // head / col-quarter (4 waves)
  const int oc = C*32 + c32;

  if (t < BM){
    int pe = perm[e0+t];
    srcl[t] = src[pe]; dstl[t] = dst[pe]; eidl[t] = eids[pe];
  }
  __syncthreads();

  // stage kv_j = xb[src] into KVB (32 edges x 16 uint4 = 512 over 256 thr)
  {
    const uint4* xbu = (const uint4*)xb;
    #pragma unroll
    for (int it=0; it<2; ++it){
      int g = it*256 + t;
      int e = g >> 4, qq = g & 15;
      *(uint4*)(KVB + swzK(e, qq*16)) = xbu[(long)srcl[e]*16 + qq];
    }
  }

  f32x16 gbG, gbB;
  {
    float bg = Gb[oc] + GATE_BIAS;
    float bb = Bb[oc];
    #pragma unroll
    for (int i=0;i<16;++i){ gbG[i] = bg; gbB[i] = bb; }
  }

  // prologue: issue chunk-0 gather (32 edges x 128 cols = 512 bf16x8 over 256 thr)
  bf16x8 xa8[2], ea8[2];
  #pragma unroll
  for (int it=0; it<2; ++it){
    int g = it*256 + t;
    int e = g >> 4, c8 = g & 15;
    xa8[it] = *(const bf16x8*)(XAb + (long)srcl[e]*FFF + c8*8);
    ea8[it] = *(const bf16x8*)(EAb + (long)eidl[e]*FFF + c8*8);
  }

  // 4 chunks of 128 FF-cols; INTB double-buffered: ONE barrier per chunk.
  #pragma unroll
  for (int ch=0; ch<4; ++ch){
    bf16x8 o[2];
    #pragma unroll
    for (int it=0; it<2; ++it){
      #pragma unroll
      for (int j=0;j<8;++j){
        float s = (float)xa8[it][j] + (float)ea8[it][j];
        o[it][j] = (__bf16)((s > 0.f) ? s : (__expf(s) - 1.f));
      }
    }
    unsigned char* INTp = INTB[ch & 1];
    #pragma unroll
    for (int it=0; it<2; ++it){
      int g = it*256 + t;
      int e = g >> 4, c8 = g & 15;
      *(bf16x8*)(INTp + swzK(e, c8*16)) = o[it];
    }
    __syncthreads();   // INT[p] visible; GEMM(ch-2) readers finished >=1 sync ago
    if (ch < 3){
      #pragma unroll
      for (int it=0; it<2; ++it){
        int g = it*256 + t;
        int e = g >> 4, c8 = g & 15;
        xa8[it] = *(const bf16x8*)(XAb + (long)srcl[e]*FFF + (ch+1)*128 + c8*8);
        ea8[it] = *(const bf16x8*)(EAb + (long)eidl[e]*FFF + (ch+1)*128 + c8*8);
      }
    }
    // gate GEMM: rows 0..31, cols 32C.., K=128
    {
      const ushort* Wg = Gwb + ((long)(C*32 + ch*8)*64 + l)*8;
      bf16x8 wf[8];
      #pragma unroll
      for (int i=0;i<8;++i) wf[i] = *(const bf16x8*)(Wg + (long)i*512);
      #pragma unroll
      for (int i=0;i<8;++i){
        bf16x8 a = *(const bf16x8*)(INTp + swzK(c32, i*32 + hi*16));
        gbG = MFMA32(a, wf[i], gbG);
      }
    }
    // badd GEMM
    {
      const ushort* Wb = Bwb + ((long)(C*32 + ch*8)*64 + l)*8;
      bf16x8 wf[8];
      #pragma unroll
      for (int i=0;i<8;++i) wf[i] = *(const bf16x8*)(Wb + (long)i*512);
      #pragma unroll
      for (int i=0;i<8;++i){
        bf16x8 a = *(const bf16x8*)(INTp + swzK(c32, i*32 + hi*16));
        gbB = MFMA32(a, wf[i], gbB);
      }
    }
  }

  // in-register blend: kv2 = badd + sigmoid(gate)*(kv - badd), write back to KVB
  #pragma unroll
  for (int r=0;r<16;++r){
    int row = (r&3) + 8*(r>>2) + 4*hi;
    float g  = 1.f/(1.f + __expf(-gbG[r]));
    float kv = (float)*(const __bf16*)(KVB + swzK(row, oc*2));
    float k2 = gbB[r] + g*(kv - gbB[r]);
    *(__bf16*)(KVB + swzK(row, oc*2)) = (__bf16)k2;
  }
  __syncthreads();   // kv2 ready in KVB

  // K and V GEMMs: wave C computes K[0..32][32C..] and V[0..32][32C..], K=128
  f32x16 ka, va;
  #pragma unroll
  for (int i=0;i<16;++i){ ka[i] = 0.f; va[i] = 0.f; }
  {
    const ushort* Wk = Kwb + ((long)(C*8)*64 + l)*8;
    bf16x8 wf[8];
    #pragma unroll
    for (int i=0;i<8;++i) wf[i] = *(const bf16x8*)(Wk + (long)i*512);
    #pragma unroll
    for (int i=0;i<8;++i){
      bf16x8 a = *(const bf16x8*)(KVB + swzK(c32, i*32 + hi*16));
      ka = MFMA32(a, wf[i], ka);
    }
  }
  {
    const ushort* Wv = Vwb + ((long)(C*8)*64 + l)*8;
    bf16x8 wf[8];
    #pragma unroll
    for (int i=0;i<8;++i) wf[i] = *(const bf16x8*)(Wv + (long)i*512);
    #pragma unroll
    for (int i=0;i<8;++i){
      bf16x8 a = *(const bf16x8*)(KVB + swzK(c32, i*32 + hi*16));
      va = MFMA32(a, wf[i], va);
    }
  }
  // no barrier needed: nothing writes LDS after this point.

  // fused score + exp + weighted in-register segment scatter.
  // Thread owns rows {8q+4hi+j : q=0..3, j=0..3}: 4 runs of 4 CONSECUTIVE sorted rows.
  #pragma unroll
  for (int qq=0; qq<4; ++qq){
    const int base = 8*qq + 4*hi;
    float ex[4];
    #pragma unroll
    for (int j=0;j<4;++j){
      int r = qq*4 + j;
      int gr = base + j;
      float kv = ka[r] + EKf[(long)eidl[gr]*DD + oc];
      float p = kv * q[(long)dstl[gr]*DD + oc];
      p += __shfl_xor(p, 1); p += __shfl_xor(p, 2);
      p += __shfl_xor(p, 4); p += __shfl_xor(p, 8);
      p += __shfl_xor(p, 16);
      ex[j] = __expf(p);          // all 32 lanes of the half-wave hold the row's score
    }
    // agg scatter: merge consecutive rows sharing dst (branch is half-wave-uniform)
    {
      float acc = va[qq*4]*ex[0];
      int cur = dstl[base];
      #pragma unroll
      for (int j=1;j<4;++j){
        int dn = dstl[base+j];
        if (dn != cur){
          atomicAdd(&agg[(long)cur*DD + oc], acc);
          acc = 0.f; cur = dn;
        }
        acc += va[qq*4+j]*ex[j];
      }
      atomicAdd(&agg[(long)cur*DD + oc], acc);
    }
    // denom scatter: one lane per half-wave
    if (c32 == 0){
      float da = ex[0];
      int cur = dstl[base];
      #pragma unroll
      for (int j=1;j<4;++j){
        int dn = dstl[base+j];
        if (dn != cur){
          atomicAdd(&denom[cur*HH + C], da);
          da = 0.f; cur = dn;
        }
        da += ex[j];
      }
      atomicAdd(&denom[cur*HH + C], da);
    }
  }
}

// fused: x1 = x + (agg/denom)@o_w^T;  x = x1 + relu(LN(x1)@wi^T)@wo^T;  emits x, xb.
// FUSE_LNQ tail runs the NEXT layer's LN + q-proj + XA-proj on xn in registers.
template<bool FUSE_LNQ>
__global__ __launch_bounds__(256) void k_node(
    const float* __restrict__ agg, const float* __restrict__ denom,
    const ushort* __restrict__ owb,
    const float* __restrict__ lnw, const float* __restrict__ lnb,
    const ushort* __restrict__ wib, const ushort* __restrict__ wob,
    float* __restrict__ x, ushort* __restrict__ xb,
    const float* __restrict__ nlnw, const float* __restrict__ nlnb,
    const ushort* __restrict__ nqwb, const ushort* __restrict__ na1b,
    float* __restrict__ q, ushort* __restrict__ XAb){
  __shared__ __align__(16) unsigned char AB[NT*256];
  __shared__ __align__(16) unsigned char IB[NT*1024];
  __shared__ __align__(16) float XO[NT][132];
  const int n0 = blockIdx.x*NT;
  const int t = threadIdx.x;
  const int e = t>>4, s = t&15;
  const int w = t>>6, l = t&63, lr = l&15, lg = l>>4;

  {
    const float* ap = agg + (long)(n0+e)*DD + s*8;
    float av[8];
    *(float4*)&av[0] = *(const float4*)ap;
    *(float4*)&av[4] = *(const float4*)(ap+4);
    float dinv = 1.f / denom[(n0+e)*HH + (s>>2)];
    bf16x8 hb;
    #pragma unroll
    for (int i=0;i<8;++i) hb[i] = (__bf16)(av[i]*dinv);
    *(bf16x8*)(AB + swz128(e, s*16)) = hb;
  }
  __syncthreads();

  {
    const int o0 = w*32;
    f32x4 z = {0.f,0.f,0.f,0.f};
    f32x4 acc[2] = {z,z};
    #pragma unroll
    for (int k4=0;k4<4;++k4){
      bf16x8 a = *(const bf16x8*)(AB + swz128(lr, k4*64 + lg*16));
      #pragma unroll
      for (int nt=0;nt<2;++nt){
        bf16x8 b = *(const bf16x8*)(owb + (long)(o0+nt*16+lr)*128 + k4*32 + lg*8);
        acc[nt] = MFMA(a, b, acc[nt]);
      }
    }
    #pragma unroll
    for (int nt=0;nt<2;++nt)
      #pragma unroll
      for (int r=0;r<4;++r)
        XO[lg*4+r][o0+nt*16+lr] = acc[nt][r];
  }
  __syncthreads();

  float x1[8];
  {
    const float* xp = x + (long)(n0+e)*DD + s*8;
    float xv[8];
    *(float4*)&xv[0] = *(const float4*)xp;
    *(float4*)&xv[4] = *(const float4*)(xp+4);
    #pragma unroll
    for (int i=0;i<8;++i) x1[i] = xv[i] + XO[e][s*8+i];
    float sm = 0.f;
    #pragma unroll
    for (int i=0;i<8;++i) sm += x1[i];
    sm += __shfl_xor(sm,1); sm += __shfl_xor(sm,2);
    sm += __shfl_xor(sm,4); sm += __shfl_xor(sm,8);
    float mu = sm*(1.f/DD);
    float sq = 0.f;
    #pragma unroll
    for (int i=0;i<8;++i){ float d = x1[i]-mu; sq += d*d; }
    sq += __shfl_xor(sq,1); sq += __shfl_xor(sq,2);
    sq += __shfl_xor(sq,4); sq += __shfl_xor(sq,8);
    float rstd = rsqrtf(sq*(1.f/DD) + EPS);
    float4 w0 = *(const float4*)(lnw + s*8), w1 = *(const float4*)(lnw + s*8 + 4);
    float4 b0 = *(const float4*)(lnb + s*8), b1 = *(const float4*)(lnb + s*8 + 4);
    float wv[8] = {w0.x,w0.y,w0.z,w0.w,w1.x,w1.y,w1.z,w1.w};
    float bv[8] = {b0.x,b0.y,b0.z,b0.w,b1.x,b1.y,b1.z,b1.w};
    bf16x8 hb;
    #pragma unroll
    for (int i=0;i<8;++i) hb[i] = (__bf16)((x1[i]-mu)*rstd*wv[i] + bv[i]);
    __syncthreads();
    *(bf16x8*)(AB + swz128(e, s*16)) = hb;
  }
  __syncthreads();

  {
    const int f0w = w*128;
    f32x4 z = {0.f,0.f,0.f,0.f};
    f32x4 acc[8] = {z,z,z,z,z,z,z,z};
    #pragma unroll
    for (int k4=0;k4<4;++k4){
      bf16x8 a = *(const bf16x8*)(AB + swz128(lr, k4*64 + lg*16));
      #pragma unroll
      for (int nt=0;nt<8;++nt){
        bf16x8 b = *(const bf16x8*)(wib + (long)(f0w+nt*16+lr)*128 + k4*32 + lg*8);
        acc[nt] = MFMA(a, b, acc[nt]);
      }
    }
    #pragma unroll
    for (int nt=0;nt<8;++nt)
      #pragma unroll
      for (int r=0;r<4;++r){
        int e2 = lg*4 + r;
        int f = f0w + nt*16 + lr;
        float va = acc[nt][r];
        *(__bf16*)(IB + swz512(e2, f*2)) = (__bf16)fmaxf(va, 0.f);
      }
  }
  __syncthreads();

  {
    const int o0 = w*32;
    f32x4 z = {0.f,0.f,0.f,0.f};
    f32x4 acc[2] = {z,z};
    #pragma unroll
    for (int k16=0;k16<16;++k16){
      bf16x8 a = *(const bf16x8*)(IB + swz512(lr, k16*64 + lg*16));
      #pragma unroll
      for (int nt=0;nt<2;++nt){
        bf16x8 b = *(const bf16x8*)(wob + (long)(o0+nt*16+lr)*512 + k16*32 + lg*8);
        acc[nt] = MFMA(a, b, acc[nt]);
      }
    }
    #pragma unroll
    for (int nt=0;nt<2;++nt)
      #pragma unroll
      for (int r=0;r<4;++r)
        XO[lg*4+r][o0+nt*16+lr] = acc[nt][r];
  }
  __syncthreads();

  float xn[8];
  {
    #pragma unroll
    for (int i=0;i<8;++i) xn[i] = x1[i] + XO[e][s*8+i];
    float* xp = x + (long)(n0+e)*DD + s*8;
    *(float4*)xp = *(float4*)&xn[0];
    *(float4*)(xp+4) = *(float4*)&xn[4];
    bf16x8 hb;
    #pragma unroll
    for (int i=0;i<8;++i) hb[i] = (__bf16)xn[i];
    *(bf16x8*)(xb + (long)(n0+e)*DD + s*8) = hb;
  }

  if constexpr (FUSE_LNQ){
    // re-zero agg/denom for the next layer's k_edge (own rows only; read above is done)
    {
      float4 z4 = {0.f,0.f,0.f,0.f};
      float* ap = (float*)agg + (long)n0*DD + t*8;
      *(float4*)ap = z4; *(float4*)(ap+4) = z4;
      if (t < NT*HH) ((float*)denom)[n0*HH + t] = 0.f;
    }
    // next-layer LN on xn (still in registers)
    {
      float sm = 0.f;
      #pragma unroll
      for (int i=0;i<8;++i) sm += xn[i];
      sm += __shfl_xor(sm,1); sm += __shfl_xor(sm,2);
      sm += __shfl_xor(sm,4); sm += __shfl_xor(sm,8);
      float mu = sm*(1.f/DD);
      float sq = 0.f;
      #pragma unroll
      for (int i=0;i<8;++i){ float d = xn[i]-mu; sq += d*d; }
      sq += __shfl_xor(sq,1); sq += __shfl_xor(sq,2);
      sq += __shfl_xor(sq,4); sq += __shfl_xor(sq,8);
      float rstd = rsqrtf(sq*(1.f/DD) + EPS);
      float4 w0 = *(const float4*)(nlnw + s*8), w1 = *(const float4*)(nlnw + s*8 + 4);
      float4 b0 = *(const float4*)(nlnb + s*8), b1 = *(const float4*)(nlnb + s*8 + 4);
      float wv[8] = {w0.x,w0.y,w0.z,w0.w,w1.x,w1.y,w1.z,w1.w};
      float bv[8] = {b0.x,b0.y,b0.z,b0.w,b1.x,b1.y,b1.z,b1.w};
      bf16x8 hb, hr;
      #pragma unroll
      for (int i=0;i<8;++i){
        hb[i] = (__bf16)((xn[i]-mu)*rstd*wv[i] + bv[i]);
        hr[i] = (__bf16)xn[i];
      }
      *(bf16x8*)(AB + swz128(e, s*16)) = hb;             // AB := HB (dead after wi GEMM)
      *(bf16x8*)(IB + swz128(e, s*16)) = hr;             // IB[0:4K] := HR (dead after wo GEMM)
    }
    __syncthreads();
    // q projection (K=128) from AB
    {
      const int o0 = w*32;
      f32x4 z = {0.f,0.f,0.f,0.f};
      f32x4 acc[2] = {z,z};
      #pragma unroll
      for (int k4=0;k4<4;++k4){
        bf16x8 a = *(const bf16x8*)(AB + swz128(lr, k4*64 + lg*16));
        #pragma unroll
        for (int nt=0;nt<2;++nt){
          bf16x8 b = *(const bf16x8*)(nqwb + (long)(o0+nt*16+lr)*128 + k4*32 + lg*8);
          acc[nt] = MFMA(a, b, acc[nt]);
        }
      }
      #pragma unroll
      for (int nt=0;nt<2;++nt)
        #pragma unroll
        for (int r=0;r<4;++r)
          q[(long)(n0 + lg*4 + r)*DD + o0 + nt*16 + lr] = acc[nt][r];
    }
    // XA (512 out, K=128) from IB(HR)
    {
      const int f0w = w*128;
      f32x4 z = {0.f,0.f,0.f,0.f};
      f32x4 acc[8] = {z,z,z,z,z,z,z,z};
      #pragma unroll
      for (int k4=0;k4<4;++k4){
        bf16x8 a = *(const bf16x8*)(IB + swz128(lr, k4*64 + lg*16));
        #pragma unroll
        for (int nt=0;nt<8;++nt){
          bf16x8 b = *(const bf16x8*)(na1b + (long)(f0w+nt*16+lr)*128 + k4*32 + lg*8);
          acc[nt] = MFMA(a, b, acc[nt]);
        }
      }
      #pragma unroll
      for (int nt=0;nt<8;++nt)
        #pragma unroll
        for (int r=0;r<4;++r){
          __hip_bfloat16 h = __float2bfloat16(acc[nt][r]);
          XAb[(long)(n0+lg*4+r)*FFF + f0w+nt*16+lr] = *(ushort*)&h;
        }
    }
  }
}

extern "C" void kernel_launch(void* const* d_in, const int* in_sizes, int n_in,
                              void* d_out, int out_size, void* d_ws, size_t ws_size,
                              hipStream_t stream) {
  const int* node_ids   = (const int*)d_in[0];
  const int* edge_index = (const int*)d_in[1];
  const int* edge_ids   = (const int*)d_in[2];
  const float* node_emb = (const float*)d_in[3];
  const float* edge_emb = (const float*)d_in[4];
  const float* ln_w   = (const float*)d_in[5];
  const float* ln_b   = (const float*)d_in[6];
  const float* q_w    = (const float*)d_in[7];
  const float* relA_w = (const float*)d_in[8];
  const float* relA_b = (const float*)d_in[9];
  const float* relB_w = (const float*)d_in[10];
  const float* relB_b = (const float*)d_in[11];
  const float* relG_w = (const float*)d_in[12];
  const float* relG_b = (const float*)d_in[13];
  const float* k_w    = (const float*)d_in[14];
  const float* v_w    = (const float*)d_in[15];
  const float* o_w    = (const float*)d_in[16];
  const float* ff_ln_w= (const float*)d_in[17];
  const float* ff_ln_b= (const float*)d_in[18];
  const float* wi_w   = (const float*)d_in[19];
  const float* wo_w   = (const float*)d_in[20];
  const int* src = edge_index;        // edge_index[0] = j (kv side)
  const int* dst = edge_index + EE;   // edge_index[1] = i (query side)

  float* ws = (float*)d_ws;
  float* x   = ws;  ws += (long)NN*DD;
  float* q   = ws;  ws += (long)NN*DD;
  float* denom = ws; ws += NN*HH;
  float* agg   = ws; ws += (long)NN*DD;
  float* EKf   = ws; ws += (long)LL*RELV*DD;
  int* hist   = (int*)ws; ws += NN;
  int* perm   = (int*)ws; ws += EE;
  ushort* xb  = (ushort*)ws; ws += (long)NN*DD/2;
  ushort* XAb = (ushort*)ws; ws += (long)NN*FFF/2;
  ushort* EAb = (ushort*)ws; ws += (long)LL*RELV*FFF/2;
  ushort* A1b = (ushort*)ws; ws += (long)LL*FFF*DD/2;
  ushort* Gwb = (ushort*)ws; ws += (long)LL*DD*FFF/2;
  ushort* Bwb = (ushort*)ws; ws += (long)LL*DD*FFF/2;
  ushort* Kwb = (ushort*)ws; ws += (long)LL*DD*DD/2;
  ushort* Vwb = (ushort*)ws; ws += (long)LL*DD*DD/2;
  ushort* Qwb = (ushort*)ws; ws += (long)LL*DD*DD/2;
  ushort* Owb = (ushort*)ws; ws += (long)LL*DD*DD/2;
  ushort* Wib = (ushort*)ws; ws += (long)LL*FFF*DD/2;
  ushort* Wob = (ushort*)ws; ws += (long)LL*DD*FFF/2;

  hipMemsetAsync(hist, 0, NN*sizeof(int), stream);
  k_gx<<<NN/2, 256, 0, stream>>>(node_ids, node_emb, x, xb, dst, hist);
  k_scan<<<1, 256, 0, stream>>>(hist, hist);   // in-place: hist becomes cursor
  k_scatter<<<(EE+255)/256, 256, 0, stream>>>(dst, hist, perm);
  k_prep2<<<512, 256, 0, stream>>>(relG_w, relB_w, k_w, v_w, relA_w,
                                   q_w, o_w, wi_w, wo_w,
                                   Gwb, Bwb, Kwb, Vwb, A1b, Qwb, Owb, Wib, Wob);
  k_ea2<<<2*RELV, 256, 0, stream>>>(edge_emb, relA_w, relA_b, k_w, EAb, EKf);

  // layer 0 front-end
  k_lnq_xa<<<NN/NT, 256, 0, stream>>>(x, ln_w, ln_b, Qwb, A1b, q, XAb, agg, denom);
  for (int l=0; l<LL; ++l){
    k_edge<<<EE/BM, 256, 0, stream>>>(xb, XAb, EAb + (long)l*RELV*FFF, EKf + (long)l*RELV*DD,
        q, src, dst, edge_ids, perm,
        Gwb + (long)l*DD*FFF,  relG_b + (long)l*DD,
        Bwb + (long)l*DD*FFF,  relB_b + (long)l*DD,
        Kwb + (long)l*DD*DD,   Vwb + (long)l*DD*DD,
        agg, denom);
    if (l < LL-1){
      k_node<true><<<NN/NT, 256, 0, stream>>>(agg, denom, Owb + (long)l*DD*DD,
          ff_ln_w + l*DD, ff_ln_b + l*DD,
          Wib + (long)l*FFF*DD, Wob + (long)l*DD*FFF, x, xb,
          ln_w + (l+1)*DD, ln_b + (l+1)*DD,
          Qwb + (long)(l+1)*DD*DD, A1b + (long)(l+1)*FFF*DD, q, XAb);
    } else {
      k_node<false><<<NN/NT, 256, 0, stream>>>(agg, denom, Owb + (long)l*DD*DD,
          ff_ln_w + l*DD, ff_ln_b + l*DD,
          Wib + (long)l*FFF*DD, Wob + (long)l*DD*FFF, x, xb,
          nullptr, nullptr, nullptr, nullptr, nullptr, nullptr);
    }
  }
  hipMemcpyAsync(d_out, x, (size_t)NN*DD*sizeof(float), hipMemcpyDeviceToDevice, stream);
}

// Round 15
// 403.166 us; speedup vs baseline: 1.2393x; 1.0203x over previous
//
#include <hip/hip_runtime.h>
#include <hip/hip_bf16.h>

#define NN 10000
#define EE 160000
#define DD 128
#define HH 4
#define CC 32
#define FFF 512
#define LL 2
#define RELV 100
#define EPS 1e-6f
#define GATE_BIAS 3.0f
#define BM 32
#define NT 16

typedef __bf16 bf16x8 __attribute__((ext_vector_type(8)));
typedef float f32x4 __attribute__((ext_vector_type(4)));
typedef float f32x16 __attribute__((ext_vector_type(16)));

#define MFMA(a,b,c)   __builtin_amdgcn_mfma_f32_16x16x32_bf16((a),(b),(c),0,0,0)
#define MFMA32(a,b,c) __builtin_amdgcn_mfma_f32_32x32x16_bf16((a),(b),(c),0,0,0)

__device__ __forceinline__ int swzK(int e, int b){ return e*256 + (b ^ ((e&7)<<4)); }   // [R][128] bf16
__device__ __forceinline__ int swz128(int e, int b){ return e*256 + (b ^ ((e&7)<<4)); } // [16][128] bf16
__device__ __forceinline__ int swz512(int e, int b){ return e*1024 + (b ^ ((e&7)<<4)); }// [16][512] bf16

// W[?][instride] fp32 -> MFMA32 fragment order bf16 (device helper)
__device__ __forceinline__ void wprep_one(
    const float* __restrict__ in, ushort* __restrict__ out, int tid, int IN, int instride){
  int lane = tid & 63;
  int grp  = tid >> 6;
  int nkb  = IN >> 4;
  int kb   = grp % nkb;
  int cb   = grp / nkb;
  int col  = cb*32 + (lane & 31);
  int k0   = kb*16 + (lane >> 5)*8;
  const float* p = in + (long)col*instride + k0;
  bf16x8 h;
  #pragma unroll
  for (int j=0;j<8;++j) h[j] = (__bf16)p[j];
  *(bf16x8*)(out + (long)tid*8) = h;
}

// ALL weight prep in ONE launch (both layers' wprep + A1 subcast + the 4 plain casts).
__global__ __launch_bounds__(256) void k_prep2(
    const float* __restrict__ relG_w, const float* __restrict__ relB_w,
    const float* __restrict__ k_w, const float* __restrict__ v_w,
    const float* __restrict__ relA_w,
    const float* __restrict__ q_w, const float* __restrict__ o_w,
    const float* __restrict__ wi_w, const float* __restrict__ wo_w,
    ushort* __restrict__ Gwb, ushort* __restrict__ Bwb,
    ushort* __restrict__ Kwb, ushort* __restrict__ Vwb, ushort* __restrict__ A1b,
    ushort* __restrict__ Qwb, ushort* __restrict__ Owb,
    ushort* __restrict__ Wib, ushort* __restrict__ Wob){
  const int bid = blockIdx.x;
  const int l   = bid >> 8;
  const int tidl = (bid & 255)*256 + threadIdx.x;
  const long gid = (long)bid*256 + threadIdx.x;
  if (tidl < DD*FFF/8){
    wprep_one(relG_w + (long)l*DD*FFF, Gwb + (long)l*DD*FFF, tidl, FFF, FFF);
    wprep_one(relB_w + (long)l*DD*FFF, Bwb + (long)l*DD*FFF, tidl, FFF, FFF);
  }
  if (tidl < DD*DD/8){
    wprep_one(k_w + (long)l*DD*256, Kwb + (long)l*DD*DD, tidl, DD, 256);
    wprep_one(v_w + (long)l*DD*DD,  Vwb + (long)l*DD*DD, tidl, DD, DD);
  }
  {
    int o = tidl / DD, i = tidl % DD;
    __hip_bfloat16 h = __float2bfloat16(relA_w[(long)l*FFF*256 + (long)o*256 + i]);
    A1b[(long)l*FFF*DD + tidl] = *(ushort*)&h;
  }
  if (gid < (long)LL*DD*DD){
    __hip_bfloat16 h1 = __float2bfloat16(q_w[gid]); Qwb[gid] = *(ushort*)&h1;
    __hip_bfloat16 h2 = __float2bfloat16(o_w[gid]); Owb[gid] = *(ushort*)&h2;
  }
  {
    __hip_bfloat16 h3 = __float2bfloat16(wi_w[gid]); Wib[gid] = *(ushort*)&h3;
    __hip_bfloat16 h4 = __float2bfloat16(wo_w[gid]); Wob[gid] = *(ushort*)&h4;
  }
}

// both layers' per-relation precompute in one launch (grid 2*RELV).
__global__ __launch_bounds__(256) void k_ea2(
    const float* __restrict__ edge_emb, const float* __restrict__ relA_w,
    const float* __restrict__ relA_b, const float* __restrict__ k_w,
    ushort* __restrict__ EA2b, float* __restrict__ EKf){
  int l = blockIdx.x / RELV, rel = blockIdx.x % RELV, t = threadIdx.x;
  const float* Aw = relA_w + (long)l*FFF*256;
  const float* Ab = relA_b + (long)l*FFF;
  const float* Kw = k_w + (long)l*DD*256;
  ushort* EAo = EA2b + (long)l*RELV*FFF;
  float* EKo  = EKf + (long)l*RELV*DD;
  __shared__ float emb[128];
  if (t < 128) emb[t] = edge_emb[(long)rel*DD + t];
  __syncthreads();
  for (int f=t; f<FFF; f+=256){
    const float* wr = Aw + (long)f*256 + 128;
    float s = Ab[f];
    for (int i=0;i<128;++i) s += emb[i]*wr[i];
    __hip_bfloat16 h = __float2bfloat16(s);
    EAo[(long)rel*FFF + f] = *(ushort*)&h;
  }
  if (t < 128){
    const float* wr = Kw + (long)t*256 + 128;
    float s = 0.f;
    for (int i=0;i<128;++i) s += emb[i]*wr[i];
    EKo[(long)rel*DD + t] = s;
  }
}

// exclusive prefix of hist[NN] -> cursor[NN]; single block, 256 threads. shfl-based wave scan.
__global__ __launch_bounds__(256) void k_scan(const int* __restrict__ hist, int* __restrict__ cursor){
  __shared__ int wsum[4];
  const int t = threadIdx.x;
  const int PER = (NN + 255) / 256;   // 40
  const int base = t*PER;
  int s = 0;
  for (int i=0;i<PER;++i){ int idx = base+i; if (idx < NN) s += hist[idx]; }
  // inclusive scan within wave (64 lanes)
  int inc = s;
  #pragma unroll
  for (int off=1; off<64; off<<=1){
    int v = __shfl_up(inc, off);
    if ((t & 63) >= off) inc += v;
  }
  if ((t & 63) == 63) wsum[t >> 6] = inc;
  __syncthreads();
  int woff = 0;
  {
    int w = t >> 6;
    for (int i=0;i<w;++i) woff += wsum[i];
  }
  int run = woff + inc - s;   // exclusive base for this thread's range
  for (int i=0;i<PER;++i){
    int idx = base+i;
    if (idx < NN){ int v = hist[idx]; cursor[idx] = run; run += v; }
  }
}
__global__ __launch_bounds__(256) void k_scatter(const int* __restrict__ dst,
    int* __restrict__ cursor, int* __restrict__ perm){
  int e = blockIdx.x*256 + threadIdx.x;
  if (e < EE){
    int p = atomicAdd(&cursor[dst[e]], 1);
    perm[p] = e;
  }
}

// v16 front-end: node-emb gather + x/xb emit + edge histogram + LN + q-proj + XA-proj,
// all in one 625-block launch (replaces k_gx + layer-0 k_lnq_xa; x never re-read).
__global__ __launch_bounds__(256) void k_front(
    const int* __restrict__ node_ids, const float* __restrict__ node_emb,
    const int* __restrict__ dst, int* __restrict__ hist,
    const float* __restrict__ lnw, const float* __restrict__ lnb,
    const ushort* __restrict__ qwb, const ushort* __restrict__ a1b,
    float* __restrict__ x, ushort* __restrict__ xb,
    float* __restrict__ q, ushort* __restrict__ XAb,
    float* __restrict__ agg, float* __restrict__ denom){
  __shared__ __align__(16) unsigned char HB[NT*256];    // LN'd x (bf16)
  __shared__ __align__(16) unsigned char HR[NT*256];    // raw x (bf16)
  const int n0 = blockIdx.x*NT;
  const int t = threadIdx.x;
  const int e = t>>4, s = t&15;
  const int w = t>>6, l = t&63, lr = l&15, lg = l>>4;
  // edge histogram: this block owns edges [blockIdx*256, +256) (EE/625 == 256 exactly)
  {
    int eg = blockIdx.x*256 + t;
    atomicAdd(&hist[dst[eg]], 1);
  }
  // zero agg/denom rows n0..n0+16
  {
    float4 z4 = {0.f,0.f,0.f,0.f};
    float* ap = agg + (long)n0*DD + t*8;
    *(float4*)ap = z4; *(float4*)(ap+4) = z4;
    if (t < NT*HH) denom[n0*HH + t] = 0.f;
  }
  {
    const float* xp = node_emb + (long)node_ids[n0+e]*DD + s*8;
    float xv[8];
    *(float4*)&xv[0] = *(const float4*)xp;
    *(float4*)&xv[4] = *(const float4*)(xp+4);
    // emit x (fp32) and xb (bf16)
    {
      float* xo = x + (long)(n0+e)*DD + s*8;
      *(float4*)xo = *(float4*)&xv[0];
      *(float4*)(xo+4) = *(float4*)&xv[4];
    }
    float sm = 0.f;
    #pragma unroll
    for (int i=0;i<8;++i) sm += xv[i];
    sm += __shfl_xor(sm,1); sm += __shfl_xor(sm,2);
    sm += __shfl_xor(sm,4); sm += __shfl_xor(sm,8);
    float mu = sm*(1.f/DD);
    float sq = 0.f;
    #pragma unroll
    for (int i=0;i<8;++i){ float d = xv[i]-mu; sq += d*d; }
    sq += __shfl_xor(sq,1); sq += __shfl_xor(sq,2);
    sq += __shfl_xor(sq,4); sq += __shfl_xor(sq,8);
    float rstd = rsqrtf(sq*(1.f/DD) + EPS);
    float4 w0 = *(const float4*)(lnw + s*8), w1 = *(const float4*)(lnw + s*8 + 4);
    float4 b0 = *(const float4*)(lnb + s*8), b1 = *(const float4*)(lnb + s*8 + 4);
    float wv[8] = {w0.x,w0.y,w0.z,w0.w,w1.x,w1.y,w1.z,w1.w};
    float bv[8] = {b0.x,b0.y,b0.z,b0.w,b1.x,b1.y,b1.z,b1.w};
    bf16x8 hb, hr;
    #pragma unroll
    for (int i=0;i<8;++i){
      hb[i] = (__bf16)((xv[i]-mu)*rstd*wv[i] + bv[i]);
      hr[i] = (__bf16)xv[i];
    }
    *(bf16x8*)(HB + swz128(e, s*16)) = hb;
    *(bf16x8*)(HR + swz128(e, s*16)) = hr;
    *(bf16x8*)(xb + (long)(n0+e)*DD + s*8) = hr;
  }
  __syncthreads();
  // q projection (K=128) from HB
  {
    const int o0 = w*32;
    f32x4 z = {0.f,0.f,0.f,0.f};
    f32x4 acc[2] = {z,z};
    #pragma unroll
    for (int k4=0;k4<4;++k4){
      bf16x8 a = *(const bf16x8*)(HB + swz128(lr, k4*64 + lg*16));
      #pragma unroll
      for (int nt=0;nt<2;++nt){
        bf16x8 b = *(const bf16x8*)(qwb + (long)(o0+nt*16+lr)*128 + k4*32 + lg*8);
        acc[nt] = MFMA(a, b, acc[nt]);
      }
    }
    #pragma unroll
    for (int nt=0;nt<2;++nt)
      #pragma unroll
      for (int r=0;r<4;++r)
        q[(long)(n0 + lg*4 + r)*DD + o0 + nt*16 + lr] = acc[nt][r];
  }
  // XA (512 out, K=128) from HR
  {
    const int f0w = w*128;
    f32x4 z = {0.f,0.f,0.f,0.f};
    f32x4 acc[8] = {z,z,z,z,z,z,z,z};
    #pragma unroll
    for (int k4=0;k4<4;++k4){
      bf16x8 a = *(const bf16x8*)(HR + swz128(lr, k4*64 + lg*16));
      #pragma unroll
      for (int nt=0;nt<8;++nt){
        bf16x8 b = *(const bf16x8*)(a1b + (long)(f0w+nt*16+lr)*128 + k4*32 + lg*8);
        acc[nt] = MFMA(a, b, acc[nt]);
      }
    }
    #pragma unroll
    for (int nt=0;nt<8;++nt)
      #pragma unroll
      for (int r=0;r<4;++r){
        __hip_bfloat16 h = __float2bfloat16(acc[nt][r]);
        XAb[(long)(n0+lg*4+r)*FFF + f0w+nt*16+lr] = *(ushort*)&h;
      }
  }
}

// --- fused edge kernel (dst-sorted) --- v13/v15 proven body (133us).
__global__ __launch_bounds__(256,4) void k_edge(
    const ushort* __restrict__ xb, const ushort* __restrict__ XAb,
    const ushort* __restrict__ EAb, const float* __restrict__ EKf,
    const float* __restrict__ q,
    const int* __restrict__ src, const int* __restrict__ dst, const int* __restrict__ eids,
    const int* __restrict__ perm,
    const ushort* __restrict__ Gwb, const float* __restrict__ Gb,
    const ushort* __restrict__ Bwb, const float* __restrict__ Bb,
    const ushort* __restrict__ Kwb, const ushort* __restrict__ Vwb,
    float* __restrict__ agg, float* __restrict__ denom)
{
  __shared__ __align__(16) unsigned char KVB[BM*256];      // 8KB kv2 bf16 [32][128] swz
  __shared__ __align__(16) unsigned char INTB[2][BM*256];  // 16KB celu chunk dbuf
  __shared__ int srcl[BM], dstl[BM], eidl[BM];

  // exact XCD swizzle: nwg = 5000, divisible by 8
  int nb;
  {
    const int cpx = (EE/BM) >> 3;     // 625
    nb = (blockIdx.x & 7)*cpx + (blockIdx.x >> 3);
  }
  const int e0 = nb * BM;
  const int t  = threadIdx.x;
  const int w  = t >> 6;
  const int l  = t & 63;
  const int c32 = l & 31;
  const int hi  = l >> 5;
  const int C = w;               // head / col-quarter (4 waves)
  const int oc = C*32 + c32;

  if (t < BM){
    int pe = perm[e0+t];
    srcl[t] = src[pe]; dstl[t] = dst[pe]; eidl[t] = eids[pe];
  }
  __syncthreads();

  // stage kv_j = xb[src] into KVB (32 edges x 16 uint4 = 512 over 256 thr)
  {
    const uint4* xbu = (const uint4*)xb;
    #pragma unroll
    for (int it=0; it<2; ++it){
      int g = it*256 + t;
      int e = g >> 4, qq = g & 15;
      *(uint4*)(KVB + swzK(e, qq*16)) = xbu[(long)srcl[e]*16 + qq];
    }
  }

  f32x16 gbG, gbB;
  {
    float bg = Gb[oc] + GATE_BIAS;
    float bb = Bb[oc];
    #pragma unroll
    for (int i=0;i<16;++i){ gbG[i] = bg; gbB[i] = bb; }
  }

  // prologue: issue chunk-0 gather (32 edges x 128 cols = 512 bf16x8 over 256 thr)
  bf16x8 xa8[2], ea8[2];
  #pragma unroll
  for (int it=0; it<2; ++it){
    int g = it*256 + t;
    int e = g >> 4, c8 = g & 15;
    xa8[it] = *(const bf16x8*)(XAb + (long)srcl[e]*FFF + c8*8);
    ea8[it] = *(const bf16x8*)(EAb + (long)eidl[e]*FFF + c8*8);
  }

  // 4 chunks of 128 FF-cols; INTB double-buffered: ONE barrier per chunk.
  #pragma unroll
  for (int ch=0; ch<4; ++ch){
    bf16x8 o[2];
    #pragma unroll
    for (int it=0; it<2; ++it){
      #pragma unroll
      for (int j=0;j<8;++j){
        float s = (float)xa8[it][j] + (float)ea8[it][j];
        o[it][j] = (__bf16)((s > 0.f) ? s : (__expf(s) - 1.f));
      }
    }
    unsigned char* INTp = INTB[ch & 1];
    #pragma unroll
    for (int it=0; it<2; ++it){
      int g = it*256 + t;
      int e = g >> 4, c8 = g & 15;
      *(bf16x8*)(INTp + swzK(e, c8*16)) = o[it];
    }
    __syncthreads();   // INT[p] visible; GEMM(ch-2) readers finished >=1 sync ago
    if (ch < 3){
      #pragma unroll
      for (int it=0; it<2; ++it){
        int g = it*256 + t;
        int e = g >> 4, c8 = g & 15;
        xa8[it] = *(const bf16x8*)(XAb + (long)srcl[e]*FFF + (ch+1)*128 + c8*8);
        ea8[it] = *(const bf16x8*)(EAb + (long)eidl[e]*FFF + (ch+1)*128 + c8*8);
      }
    }
    // gate GEMM: rows 0..31, cols 32C.., K=128
    {
      const ushort* Wg = Gwb + ((long)(C*32 + ch*8)*64 + l)*8;
      bf16x8 wf[8];
      #pragma unroll
      for (int i=0;i<8;++i) wf[i] = *(const bf16x8*)(Wg + (long)i*512);
      #pragma unroll
      for (int i=0;i<8;++i){
        bf16x8 a = *(const bf16x8*)(INTp + swzK(c32, i*32 + hi*16));
        gbG = MFMA32(a, wf[i], gbG);
      }
    }
    // badd GEMM
    {
      const ushort* Wb = Bwb + ((long)(C*32 + ch*8)*64 + l)*8;
      bf16x8 wf[8];
      #pragma unroll
      for (int i=0;i<8;++i) wf[i] = *(const bf16x8*)(Wb + (long)i*512);
      #pragma unroll
      for (int i=0;i<8;++i){
        bf16x8 a = *(const bf16x8*)(INTp + swzK(c32, i*32 + hi*16));
        gbB = MFMA32(a, wf[i], gbB);
      }
    }
  }

  // in-register blend: kv2 = badd + sigmoid(gate)*(kv - badd), write back to KVB
  #pragma unroll
  for (int r=0;r<16;++r){
    int row = (r&3) + 8*(r>>2) + 4*hi;
    float g  = 1.f/(1.f + __expf(-gbG[r]));
    float kv = (float)*(const __bf16*)(KVB + swzK(row, oc*2));
    float k2 = gbB[r] + g*(kv - gbB[r]);
    *(__bf16*)(KVB + swzK(row, oc*2)) = (__bf16)k2;
  }
  __syncthreads();   // kv2 ready in KVB

  // K and V GEMMs: wave C computes K[0..32][32C..] and V[0..32][32C..], K=128
  f32x16 ka, va;
  #pragma unroll
  for (int i=0;i<16;++i){ ka[i] = 0.f; va[i] = 0.f; }
  {
    const ushort* Wk = Kwb + ((long)(C*8)*64 + l)*8;
    bf16x8 wf[8];
    #pragma unroll
    for (int i=0;i<8;++i) wf[i] = *(const bf16x8*)(Wk + (long)i*512);
    #pragma unroll
    for (int i=0;i<8;++i){
      bf16x8 a = *(const bf16x8*)(KVB + swzK(c32, i*32 + hi*16));
      ka = MFMA32(a, wf[i], ka);
    }
  }
  {
    const ushort* Wv = Vwb + ((long)(C*8)*64 + l)*8;
    bf16x8 wf[8];
    #pragma unroll
    for (int i=0;i<8;++i) wf[i] = *(const bf16x8*)(Wv + (long)i*512);
    #pragma unroll
    for (int i=0;i<8;++i){
      bf16x8 a = *(const bf16x8*)(KVB + swzK(c32, i*32 + hi*16));
      va = MFMA32(a, wf[i], va);
    }
  }
  // no barrier needed: nothing writes LDS after this point.

  // fused score + exp + weighted in-register segment scatter.
  #pragma unroll
  for (int qq=0; qq<4; ++qq){
    const int base = 8*qq + 4*hi;
    float ex[4];
    #pragma unroll
    for (int j=0;j<4;++j){
      int r = qq*4 + j;
      int gr = base + j;
      float kv = ka[r] + EKf[(long)eidl[gr]*DD + oc];
      float p = kv * q[(long)dstl[gr]*DD + oc];
      p += __shfl_xor(p, 1); p += __shfl_xor(p, 2);
      p += __shfl_xor(p, 4); p += __shfl_xor(p, 8);
      p += __shfl_xor(p, 16);
      ex[j] = __expf(p);
    }
    {
      float acc = va[qq*4]*ex[0];
      int cur = dstl[base];
      #pragma unroll
      for (int j=1;j<4;++j){
        int dn = dstl[base+j];
        if (dn != cur){
          atomicAdd(&agg[(long)cur*DD + oc], acc);
          acc = 0.f; cur = dn;
        }
        acc += va[qq*4+j]*ex[j];
      }
      atomicAdd(&agg[(long)cur*DD + oc], acc);
    }
    if (c32 == 0){
      float da = ex[0];
      int cur = dstl[base];
      #pragma unroll
      for (int j=1;j<4;++j){
        int dn = dstl[base+j];
        if (dn != cur){
          atomicAdd(&denom[cur*HH + C], da);
          da = 0.f; cur = dn;
        }
        da += ex[j];
      }
      atomicAdd(&denom[cur*HH + C], da);
    }
  }
}

// fused: x1 = x + (agg/denom)@o_w^T;  x = x1 + relu(LN(x1)@wi^T)@wo^T.
// FUSE_LNQ: writes x/xb and runs next layer's LN+q+XA.  !FUSE_LNQ: writes xout (d_out) only.
template<bool FUSE_LNQ>
__global__ __launch_bounds__(256) void k_node(
    const float* __restrict__ agg, const float* __restrict__ denom,
    const ushort* __restrict__ owb,
    const float* __restrict__ lnw, const float* __restrict__ lnb,
    const ushort* __restrict__ wib, const ushort* __restrict__ wob,
    float* __restrict__ x, ushort* __restrict__ xb, float* __restrict__ xout,
    const float* __restrict__ nlnw, const float* __restrict__ nlnb,
    const ushort* __restrict__ nqwb, const ushort* __restrict__ na1b,
    float* __restrict__ q, ushort* __restrict__ XAb){
  __shared__ __align__(16) unsigned char AB[NT*256];
  __shared__ __align__(16) unsigned char IB[NT*1024];
  __shared__ __align__(16) float XO[NT][132];
  const int n0 = blockIdx.x*NT;
  const int t = threadIdx.x;
  const int e = t>>4, s = t&15;
  const int w = t>>6, l = t&63, lr = l&15, lg = l>>4;

  {
    const float* ap = agg + (long)(n0+e)*DD + s*8;
    float av[8];
    *(float4*)&av[0] = *(const float4*)ap;
    *(float4*)&av[4] = *(const float4*)(ap+4);
    float dinv = 1.f / denom[(n0+e)*HH + (s>>2)];
    bf16x8 hb;
    #pragma unroll
    for (int i=0;i<8;++i) hb[i] = (__bf16)(av[i]*dinv);
    *(bf16x8*)(AB + swz128(e, s*16)) = hb;
  }
  __syncthreads();

  {
    const int o0 = w*32;
    f32x4 z = {0.f,0.f,0.f,0.f};
    f32x4 acc[2] = {z,z};
    #pragma unroll
    for (int k4=0;k4<4;++k4){
      bf16x8 a = *(const bf16x8*)(AB + swz128(lr, k4*64 + lg*16));
      #pragma unroll
      for (int nt=0;nt<2;++nt){
        bf16x8 b = *(const bf16x8*)(owb + (long)(o0+nt*16+lr)*128 + k4*32 + lg*8);
        acc[nt] = MFMA(a, b, acc[nt]);
      }
    }
    #pragma unroll
    for (int nt=0;nt<2;++nt)
      #pragma unroll
      for (int r=0;r<4;++r)
        XO[lg*4+r][o0+nt*16+lr] = acc[nt][r];
  }
  __syncthreads();

  float x1[8];
  {
    const float* xp = x + (long)(n0+e)*DD + s*8;
    float xv[8];
    *(float4*)&xv[0] = *(const float4*)xp;
    *(float4*)&xv[4] = *(const float4*)(xp+4);
    #pragma unroll
    for (int i=0;i<8;++i) x1[i] = xv[i] + XO[e][s*8+i];
    float sm = 0.f;
    #pragma unroll
    for (int i=0;i<8;++i) sm += x1[i];
    sm += __shfl_xor(sm,1); sm += __shfl_xor(sm,2);
    sm += __shfl_xor(sm,4); sm += __shfl_xor(sm,8);
    float mu = sm*(1.f/DD);
    float sq = 0.f;
    #pragma unroll
    for (int i=0;i<8;++i){ float d = x1[i]-mu; sq += d*d; }
    sq += __shfl_xor(sq,1); sq += __shfl_xor(sq,2);
    sq += __shfl_xor(sq,4); sq += __shfl_xor(sq,8);
    float rstd = rsqrtf(sq*(1.f/DD) + EPS);
    float4 w0 = *(const float4*)(lnw + s*8), w1 = *(const float4*)(lnw + s*8 + 4);
    float4 b0 = *(const float4*)(lnb + s*8), b1 = *(const float4*)(lnb + s*8 + 4);
    float wv[8] = {w0.x,w0.y,w0.z,w0.w,w1.x,w1.y,w1.z,w1.w};
    float bv[8] = {b0.x,b0.y,b0.z,b0.w,b1.x,b1.y,b1.z,b1.w};
    bf16x8 hb;
    #pragma unroll
    for (int i=0;i<8;++i) hb[i] = (__bf16)((x1[i]-mu)*rstd*wv[i] + bv[i]);
    __syncthreads();
    *(bf16x8*)(AB + swz128(e, s*16)) = hb;
  }
  __syncthreads();

  {
    const int f0w = w*128;
    f32x4 z = {0.f,0.f,0.f,0.f};
    f32x4 acc[8] = {z,z,z,z,z,z,z,z};
    #pragma unroll
    for (int k4=0;k4<4;++k4){
      bf16x8 a = *(const bf16x8*)(AB + swz128(lr, k4*64 + lg*16));
      #pragma unroll
      for (int nt=0;nt<8;++nt){
        bf16x8 b = *(const bf16x8*)(wib + (long)(f0w+nt*16+lr)*128 + k4*32 + lg*8);
        acc[nt] = MFMA(a, b, acc[nt]);
      }
    }
    #pragma unroll
    for (int nt=0;nt<8;++nt)
      #pragma unroll
      for (int r=0;r<4;++r){
        int e2 = lg*4 + r;
        int f = f0w + nt*16 + lr;
        float va = acc[nt][r];
        *(__bf16*)(IB + swz512(e2, f*2)) = (__bf16)fmaxf(va, 0.f);
      }
  }
  __syncthreads();

  {
    const int o0 = w*32;
    f32x4 z = {0.f,0.f,0.f,0.f};
    f32x4 acc[2] = {z,z};
    #pragma unroll
    for (int k16=0;k16<16;++k16){
      bf16x8 a = *(const bf16x8*)(IB + swz512(lr, k16*64 + lg*16));
      #pragma unroll
      for (int nt=0;nt<2;++nt){
        bf16x8 b = *(const bf16x8*)(wob + (long)(o0+nt*16+lr)*512 + k16*32 + lg*8);
        acc[nt] = MFMA(a, b, acc[nt]);
      }
    }
    #pragma unroll
    for (int nt=0;nt<2;++nt)
      #pragma unroll
      for (int r=0;r<4;++r)
        XO[lg*4+r][o0+nt*16+lr] = acc[nt][r];
  }
  __syncthreads();

  float xn[8];
  #pragma unroll
  for (int i=0;i<8;++i) xn[i] = x1[i] + XO[e][s*8+i];

  if constexpr (!FUSE_LNQ){
    // final layer: write output directly (fp32), skip x/xb stores
    float* xp = xout + (long)(n0+e)*DD + s*8;
    *(float4*)xp = *(float4*)&xn[0];
    *(float4*)(xp+4) = *(float4*)&xn[4];
  } else {
    {
      float* xp = x + (long)(n0+e)*DD + s*8;
      *(float4*)xp = *(float4*)&xn[0];
      *(float4*)(xp+4) = *(float4*)&xn[4];
      bf16x8 hb;
      #pragma unroll
      for (int i=0;i<8;++i) hb[i] = (__bf16)xn[i];
      *(bf16x8*)(xb + (long)(n0+e)*DD + s*8) = hb;
    }
    // re-zero agg/denom for the next layer's k_edge
    {
      float4 z4 = {0.f,0.f,0.f,0.f};
      float* ap = (float*)agg + (long)n0*DD + t*8;
      *(float4*)ap = z4; *(float4*)(ap+4) = z4;
      if (t < NT*HH) ((float*)denom)[n0*HH + t] = 0.f;
    }
    // next-layer LN on xn (still in registers)
    {
      float sm = 0.f;
      #pragma unroll
      for (int i=0;i<8;++i) sm += xn[i];
      sm += __shfl_xor(sm,1); sm += __shfl_xor(sm,2);
      sm += __shfl_xor(sm,4); sm += __shfl_xor(sm,8);
      float mu = sm*(1.f/DD);
      float sq = 0.f;
      #pragma unroll
      for (int i=0;i<8;++i){ float d = xn[i]-mu; sq += d*d; }
      sq += __shfl_xor(sq,1); sq += __shfl_xor(sq,2);
      sq += __shfl_xor(sq,4); sq += __shfl_xor(sq,8);
      float rstd = rsqrtf(sq*(1.f/DD) + EPS);
      float4 w0 = *(const float4*)(nlnw + s*8), w1 = *(const float4*)(nlnw + s*8 + 4);
      float4 b0 = *(const float4*)(nlnb + s*8), b1 = *(const float4*)(nlnb + s*8 + 4);
      float wv[8] = {w0.x,w0.y,w0.z,w0.w,w1.x,w1.y,w1.z,w1.w};
      float bv[8] = {b0.x,b0.y,b0.z,b0.w,b1.x,b1.y,b1.z,b1.w};
      bf16x8 hb, hr;
      #pragma unroll
      for (int i=0;i<8;++i){
        hb[i] = (__bf16)((xn[i]-mu)*rstd*wv[i] + bv[i]);
        hr[i] = (__bf16)xn[i];
      }
      *(bf16x8*)(AB + swz128(e, s*16)) = hb;             // AB := HB (dead after wi GEMM)
      *(bf16x8*)(IB + swz128(e, s*16)) = hr;             // IB[0:4K] := HR (dead after wo GEMM)
    }
    __syncthreads();
    // q projection (K=128) from AB
    {
      const int o0 = w*32;
      f32x4 z = {0.f,0.f,0.f,0.f};
      f32x4 acc[2] = {z,z};
      #pragma unroll
      for (int k4=0;k4<4;++k4){
        bf16x8 a = *(const bf16x8*)(AB + swz128(lr, k4*64 + lg*16));
        #pragma unroll
        for (int nt=0;nt<2;++nt){
          bf16x8 b = *(const bf16x8*)(nqwb + (long)(o0+nt*16+lr)*128 + k4*32 + lg*8);
          acc[nt] = MFMA(a, b, acc[nt]);
        }
      }
      #pragma unroll
      for (int nt=0;nt<2;++nt)
        #pragma unroll
        for (int r=0;r<4;++r)
          q[(long)(n0 + lg*4 + r)*DD + o0 + nt*16 + lr] = acc[nt][r];
    }
    // XA (512 out, K=128) from IB(HR)
    {
      const int f0w = w*128;
      f32x4 z = {0.f,0.f,0.f,0.f};
      f32x4 acc[8] = {z,z,z,z,z,z,z,z};
      #pragma unroll
      for (int k4=0;k4<4;++k4){
        bf16x8 a = *(const bf16x8*)(IB + swz128(lr, k4*64 + lg*16));
        #pragma unroll
        for (int nt=0;nt<8;++nt){
          bf16x8 b = *(const bf16x8*)(na1b + (long)(f0w+nt*16+lr)*128 + k4*32 + lg*8);
          acc[nt] = MFMA(a, b, acc[nt]);
        }
      }
      #pragma unroll
      for (int nt=0;nt<8;++nt)
        #pragma unroll
        for (int r=0;r<4;++r){
          __hip_bfloat16 h = __float2bfloat16(acc[nt][r]);
          XAb[(long)(n0+lg*4+r)*FFF + f0w+nt*16+lr] = *(ushort*)&h;
        }
    }
  }
}

extern "C" void kernel_launch(void* const* d_in, const int* in_sizes, int n_in,
                              void* d_out, int out_size, void* d_ws, size_t ws_size,
                              hipStream_t stream) {
  const int* node_ids   = (const int*)d_in[0];
  const int* edge_index = (const int*)d_in[1];
  const int* edge_ids   = (const int*)d_in[2];
  const float* node_emb = (const float*)d_in[3];
  const float* edge_emb = (const float*)d_in[4];
  const float* ln_w   = (const float*)d_in[5];
  const float* ln_b   = (const float*)d_in[6];
  const float* q_w    = (const float*)d_in[7];
  const float* relA_w = (const float*)d_in[8];
  const float* relA_b = (const float*)d_in[9];
  const float* relB_w = (const float*)d_in[10];
  const float* relB_b = (const float*)d_in[11];
  const float* relG_w = (const float*)d_in[12];
  const float* relG_b = (const float*)d_in[13];
  const float* k_w    = (const float*)d_in[14];
  const float* v_w    = (const float*)d_in[15];
  const float* o_w    = (const float*)d_in[16];
  const float* ff_ln_w= (const float*)d_in[17];
  const float* ff_ln_b= (const float*)d_in[18];
  const float* wi_w   = (const float*)d_in[19];
  const float* wo_w   = (const float*)d_in[20];
  const int* src = edge_index;        // edge_index[0] = j (kv side)
  const int* dst = edge_index + EE;   // edge_index[1] = i (query side)

  float* ws = (float*)d_ws;
  float* x   = ws;  ws += (long)NN*DD;
  float* q   = ws;  ws += (long)NN*DD;
  float* denom = ws; ws += NN*HH;
  float* agg   = ws; ws += (long)NN*DD;
  float* EKf   = ws; ws += (long)LL*RELV*DD;
  int* hist   = (int*)ws; ws += NN;
  int* perm   = (int*)ws; ws += EE;
  ushort* xb  = (ushort*)ws; ws += (long)NN*DD/2;
  ushort* XAb = (ushort*)ws; ws += (long)NN*FFF/2;
  ushort* EAb = (ushort*)ws; ws += (long)LL*RELV*FFF/2;
  ushort* A1b = (ushort*)ws; ws += (long)LL*FFF*DD/2;
  ushort* Gwb = (ushort*)ws; ws += (long)LL*DD*FFF/2;
  ushort* Bwb = (ushort*)ws; ws += (long)LL*DD*FFF/2;
  ushort* Kwb = (ushort*)ws; ws += (long)LL*DD*DD/2;
  ushort* Vwb = (ushort*)ws; ws += (long)LL*DD*DD/2;
  ushort* Qwb = (ushort*)ws; ws += (long)LL*DD*DD/2;
  ushort* Owb = (ushort*)ws; ws += (long)LL*DD*DD/2;
  ushort* Wib = (ushort*)ws; ws += (long)LL*FFF*DD/2;
  ushort* Wob = (ushort*)ws; ws += (long)LL*DD*FFF/2;

  hipMemsetAsync(hist, 0, NN*sizeof(int), stream);
  k_prep2<<<512, 256, 0, stream>>>(relG_w, relB_w, k_w, v_w, relA_w,
                                   q_w, o_w, wi_w, wo_w,
                                   Gwb, Bwb, Kwb, Vwb, A1b, Qwb, Owb, Wib, Wob);
  k_ea2<<<2*RELV, 256, 0, stream>>>(edge_emb, relA_w, relA_b, k_w, EAb, EKf);
  // fused front-end: emb gather + x/xb + hist + LN + q + XA (layer 0), zeroes agg/denom
  k_front<<<NN/NT, 256, 0, stream>>>(node_ids, node_emb, dst, hist,
      ln_w, ln_b, Qwb, A1b, x, xb, q, XAb, agg, denom);
  k_scan<<<1, 256, 0, stream>>>(hist, hist);   // in-place: hist becomes cursor
  k_scatter<<<(EE+255)/256, 256, 0, stream>>>(dst, hist, perm);

  for (int l=0; l<LL; ++l){
    k_edge<<<EE/BM, 256, 0, stream>>>(xb, XAb, EAb + (long)l*RELV*FFF, EKf + (long)l*RELV*DD,
        q, src, dst, edge_ids, perm,
        Gwb + (long)l*DD*FFF,  relG_b + (long)l*DD,
        Bwb + (long)l*DD*FFF,  relB_b + (long)l*DD,
        Kwb + (long)l*DD*DD,   Vwb + (long)l*DD*DD,
        agg, denom);
    if (l < LL-1){
      k_node<true><<<NN/NT, 256, 0, stream>>>(agg, denom, Owb + (long)l*DD*DD,
          ff_ln_w + l*DD, ff_ln_b + l*DD,
          Wib + (long)l*FFF*DD, Wob + (long)l*DD*FFF, x, xb, x,
          ln_w + (l+1)*DD, ln_b + (l+1)*DD,
          Qwb + (long)(l+1)*DD*DD, A1b + (long)(l+1)*FFF*DD, q, XAb);
    } else {
      k_node<false><<<NN/NT, 256, 0, stream>>>(agg, denom, Owb + (long)l*DD*DD,
          ff_ln_w + l*DD, ff_ln_b + l*DD,
          Wib + (long)l*FFF*DD, Wob + (long)l*DD*FFF, x, xb, (float*)d_out,
          nullptr, nullptr, nullptr, nullptr, nullptr, nullptr);
    }
  }
}